// Round 7
// baseline (3058.250 us; speedup 1.0000x reference)
//
#include <hip/hip_runtime.h>
#include <hip/hip_bf16.h>

// Problem constants
#define BQ    8192
#define FIN   12288
#define SUN   4096
#define HIDN  1024
#define XW    2048
#define H1N   28
#define H2N   14
#define NWAY  5
#define BN_EPS 1e-5f
#define LEAKS 0.001f

typedef __bf16 bf16x8 __attribute__((ext_vector_type(8)));
typedef float  f32x4  __attribute__((ext_vector_type(4)));
typedef unsigned short ushort8 __attribute__((ext_vector_type(8)));

__device__ __forceinline__ unsigned short f2bf(float f) {
    unsigned u = __float_as_uint(f);
    unsigned r = u + 0x7fffu + ((u >> 16) & 1u);   // RNE
    return (unsigned short)(r >> 16);
}

__device__ __forceinline__ ushort8 cvt8(const float4 a, const float4 b) {
    union { __bf16 h[8]; ushort8 u; } r;
    r.h[0] = (__bf16)a.x; r.h[1] = (__bf16)a.y;
    r.h[2] = (__bf16)a.z; r.h[3] = (__bf16)a.w;
    r.h[4] = (__bf16)b.x; r.h[5] = (__bf16)b.y;
    r.h[6] = (__bf16)b.z; r.h[7] = (__bf16)b.w;
    return r.u;
}

#define TO_LDS(p) ((__attribute__((address_space(3))) void*)(p))
#define TO_GLB(p) ((const __attribute__((address_space(1))) void*)(p))

// ---------------------------------------------------------------------------
__global__ __launch_bounds__(256) void cvt_bf16(
    const float* __restrict__ in, unsigned short* __restrict__ out, long long n8)
{
    const long long idx = (long long)blockIdx.x * 256 + threadIdx.x;
    const long long stride = (long long)gridDim.x * 256;
    for (long long i = idx; i < n8; i += stride) {
        const float4 a = ((const float4*)in)[2 * i];
        const float4 b = ((const float4*)in)[2 * i + 1];
        ((ushort8*)out)[i] = cvt8(a, b);
    }
}

// ---------------------------------------------------------------------------
__global__ __launch_bounds__(256) void transpose_cvt(
    const float* __restrict__ in, unsigned short* __restrict__ out,
    int R, int Cc, const int* __restrict__ dom)
{
    if (dom) in += (size_t)(*dom) * (size_t)R * (size_t)Cc;
    __shared__ float tile[64][65];
    const int t  = threadIdx.x;
    const int tr = t >> 4;
    const int tc = t & 15;
    const int c0 = blockIdx.x * 64;
    const int r0 = blockIdx.y * 64;

    #pragma unroll
    for (int q = 0; q < 4; ++q) {
        const int r = r0 + tr + q * 16;
        const float4 v = *(const float4*)&in[(size_t)r * Cc + c0 + tc * 4];
        tile[tc*4+0][tr + q*16] = v.x;
        tile[tc*4+1][tr + q*16] = v.y;
        tile[tc*4+2][tr + q*16] = v.z;
        tile[tc*4+3][tr + q*16] = v.w;
    }
    __syncthreads();
    #pragma unroll
    for (int q = 0; q < 4; ++q) {
        const int c = c0 + tr + q * 16;
        ushort4 o;
        o.x = f2bf(tile[tr + q*16][tc*4+0]);
        o.y = f2bf(tile[tr + q*16][tc*4+1]);
        o.z = f2bf(tile[tr + q*16][tc*4+2]);
        o.w = f2bf(tile[tr + q*16][tc*4+3]);
        *(ushort4*)&out[(size_t)c * R + r0 + tc * 4] = o;
    }
}

// ---------------------------------------------------------------------------
// m97-structure bf16 MFMA GEMM (128x128, 2-barrier) — fp32-A fallback only.
// ---------------------------------------------------------------------------
template<bool A_F32, bool OUT_F32, int ACT>
__global__ __launch_bounds__(256) void gemm_mfma(
    const void* __restrict__ Ap, const unsigned short* __restrict__ Bt,
    const float* __restrict__ bias, void* __restrict__ Cp,
    int M, int N, int K, int ldc, int cc0,
    const int* __restrict__ dom, int biasStride)
{
    __shared__ alignas(16) unsigned short As[128 * 32];
    __shared__ alignas(16) unsigned short Bs[128 * 32];

    const int nbx = N >> 7;
    int wg = blockIdx.x;
    const int nwg = gridDim.x;
    if ((nwg & 7) == 0) {
        const int cpx = nwg >> 3;
        wg = (wg & 7) * cpx + (wg >> 3);
    }
    const int bx = wg % nbx, by = wg / nbx;
    const int row0 = by << 7, col0 = bx << 7;

    const int t  = threadIdx.x;
    const int w  = t >> 6;
    const int l  = t & 63;
    const int wr = w >> 1, wc = w & 1;
    const int lr = l & 15, lk = l >> 4;
    const int rsw = (lr >> 1) & 3;

    f32x4 acc[4][4];
    #pragma unroll
    for (int i = 0; i < 4; ++i)
        #pragma unroll
        for (int j = 0; j < 4; ++j)
            acc[i][j] = (f32x4)(0.f);

    const int srow = l >> 2;
    const int skb  = (((l & 3) ^ ((l >> 3) & 3)) * 16);
    const float* Af = (const float*)Ap;
    const unsigned short* Ab = (const unsigned short*)Ap;

    for (int k0 = 0; k0 < K; k0 += 32) {
        __syncthreads();

        #pragma unroll
        for (int c = 0; c < 2; ++c) {
            const int inst = w * 2 + c;
            const int row  = inst * 16 + srow;
            const char* src = (const char*)Bt +
                (((size_t)(col0 + row) * K + k0) * 2 + skb);
            char* dst = (char*)Bs + inst * 1024;
            __builtin_amdgcn_global_load_lds(TO_GLB(src), TO_LDS(dst), 16, 0, 0);
        }
        if (!A_F32) {
            #pragma unroll
            for (int c = 0; c < 2; ++c) {
                const int inst = w * 2 + c;
                const int row  = inst * 16 + srow;
                const char* src = (const char*)Ab +
                    (((size_t)(row0 + row) * K + k0) * 2 + skb);
                char* dst = (char*)As + inst * 1024;
                __builtin_amdgcn_global_load_lds(TO_GLB(src), TO_LDS(dst), 16, 0, 0);
            }
        } else {
            #pragma unroll
            for (int c = 0; c < 2; ++c) {
                const int ci  = t + 256 * c;
                const int row = ci >> 2;
                const int ko  = (((ci & 3) ^ ((ci >> 3) & 3)) * 8);
                const float* s = Af + (size_t)(row0 + row) * K + k0 + ko;
                const float4 v0 = *(const float4*)s;
                const float4 v1 = *(const float4*)(s + 4);
                *(ushort8*)&As[ci * 8] = cvt8(v0, v1);
            }
        }
        __syncthreads();

        bf16x8 af[4], bfv[4];
        #pragma unroll
        for (int i = 0; i < 4; ++i)
            af[i]  = *(const bf16x8*)&As[(wr*64 + i*16 + lr) * 32 + (lk ^ rsw) * 8];
        #pragma unroll
        for (int j = 0; j < 4; ++j)
            bfv[j] = *(const bf16x8*)&Bs[(wc*64 + j*16 + lr) * 32 + (lk ^ rsw) * 8];
        #pragma unroll
        for (int i = 0; i < 4; ++i)
            #pragma unroll
            for (int j = 0; j < 4; ++j)
                acc[i][j] = __builtin_amdgcn_mfma_f32_16x16x32_bf16(
                    af[i], bfv[j], acc[i][j], 0, 0, 0);
    }

    if (dom) bias += (*dom) * biasStride;
    const int colb = col0 + wc * 64 + lr;
    const int rowb = row0 + wr * 64 + lk * 4;
    float bj[4];
    #pragma unroll
    for (int j = 0; j < 4; ++j) bj[j] = bias[colb + j * 16];

    #pragma unroll
    for (int i = 0; i < 4; ++i) {
        #pragma unroll
        for (int r = 0; r < 4; ++r) {
            const size_t row = rowb + i * 16 + r;
            #pragma unroll
            for (int j = 0; j < 4; ++j) {
                float x = acc[i][j][r] + bj[j];
                if (ACT == 1)      x = fmaxf(x, 0.f);
                else if (ACT == 2) x = (x > 0.f) ? x : LEAKS * x;
                const size_t idx = row * (size_t)ldc + cc0 + colb + j * 16;
                if (OUT_F32) ((float*)Cp)[idx] = x;
                else         ((unsigned short*)Cp)[idx] = f2bf(x);
            }
        }
    }
}

// ---------------------------------------------------------------------------
// gemm256v2: 256x256 tile, BK=64, 8 waves, DOUBLE-buffered LDS (128 KiB),
// bulk stage at tile top (full-tile latency cover), tile-end vmcnt(0)+barrier,
// 4 quadrant phases, T2 swizzle for 128B rows, T5 setprio.
// PHASED=true adds m201-style per-phase s_barrier/lgkmcnt(0) choreography.
// LDS layout per matrix: [row][64] bf16 (128 B rows); logical k-granule g
// (8 elems) of row r lives at phys granule g ^ (r&7).
// Race ledger: stage(t+1)->buf[(t+1)&1] issued after the tile-(t-1)-end
// barrier (that buffer's last readers retired before it); drained by the
// tile-t-end vmcnt(0)+barrier before tile t+1 reads it.
// ---------------------------------------------------------------------------
template<bool PHASED>
__global__ __launch_bounds__(512, 2) void gemm256v2(
    const unsigned short* __restrict__ A, const unsigned short* __restrict__ Bt,
    const float* __restrict__ bias, unsigned short* __restrict__ C,
    int M, int N, int K)
{
    __shared__ alignas(16) unsigned short As[2][256 * 64];  // 64 KiB
    __shared__ alignas(16) unsigned short Bs[2][256 * 64];  // 64 KiB

    const int nbx = N >> 8;
    int wg = blockIdx.x;
    const int nwg = gridDim.x;
    if ((nwg & 7) == 0) {
        const int cpx = nwg >> 3;
        wg = (wg & 7) * cpx + (wg >> 3);
    }
    const int bx = wg % nbx, by = wg / nbx;
    const int row0 = by << 8, col0 = bx << 8;

    const int t  = threadIdx.x;
    const int w  = t >> 6, l = t & 63;
    const int wr = w >> 2, wc = w & 3;        // 2M x 4N waves, 128x64 each
    const int lr = l & 15, lk = l >> 4;

    f32x4 acc[8][4];
    #pragma unroll
    for (int i = 0; i < 8; ++i)
        #pragma unroll
        for (int j = 0; j < 4; ++j)
            acc[i][j] = (f32x4)(0.f);

    const int NT = K >> 6;

    // 8 loads/thread/tile: A 32KB + B 32KB; chunk = h*1024 + s*512 + t.
    #define STAGEV2(tile_)  do {                                              \
        const int k0_ = (tile_) << 6;                                         \
        const int b_  = (tile_) & 1;                                          \
        _Pragma("unroll")                                                     \
        for (int h_ = 0; h_ < 2; ++h_)                                        \
        _Pragma("unroll")                                                     \
        for (int s_ = 0; s_ < 2; ++s_) {                                      \
            const int ch_  = h_ * 1024 + s_ * 512 + t;                        \
            const int row_ = ch_ >> 3;                                        \
            const int g_   = (ch_ & 7) ^ (row_ & 7);                          \
            __builtin_amdgcn_global_load_lds(                                 \
                TO_GLB(A + (size_t)(row0 + row_) * K + k0_ + g_ * 8),         \
                TO_LDS((char*)&As[b_][0] + ch_ * 16), 16, 0, 0);              \
            __builtin_amdgcn_global_load_lds(                                 \
                TO_GLB(Bt + (size_t)(col0 + row_) * K + k0_ + g_ * 8),        \
                TO_LDS((char*)&Bs[b_][0] + ch_ * 16), 16, 0, 0);              \
        }                                                                     \
    } while (0)

    // prologue
    STAGEV2(0);
    asm volatile("s_waitcnt vmcnt(0)" ::: "memory");
    __builtin_amdgcn_sched_barrier(0);
    __builtin_amdgcn_s_barrier();
    __builtin_amdgcn_sched_barrier(0);

    for (int tt = 0; tt < NT; ++tt) {
        const int b = tt & 1;
        if (tt + 1 < NT) STAGEV2(tt + 1);
        __builtin_amdgcn_sched_barrier(0);     // stage issue stays at tile top

        #pragma unroll
        for (int ph = 0; ph < 4; ++ph) {
            const int qi = ph >> 1, qj = ph & 1;

            bf16x8 av[2][4], bv[2][2];
            #pragma unroll
            for (int ks = 0; ks < 2; ++ks)
                #pragma unroll
                for (int i = 0; i < 4; ++i) {
                    const int row = wr * 128 + qi * 64 + i * 16 + lr;
                    av[ks][i] = *(const bf16x8*)
                        &As[b][row * 64 + (((ks * 4 + lk) ^ (row & 7)) << 3)];
                }
            #pragma unroll
            for (int ks = 0; ks < 2; ++ks)
                #pragma unroll
                for (int j = 0; j < 2; ++j) {
                    const int row = wc * 64 + qj * 32 + j * 16 + lr;
                    bv[ks][j] = *(const bf16x8*)
                        &Bs[b][row * 64 + (((ks * 4 + lk) ^ (row & 7)) << 3)];
                }

            if (PHASED) {
                __builtin_amdgcn_s_barrier();
                asm volatile("s_waitcnt lgkmcnt(0)" ::: "memory");
                __builtin_amdgcn_sched_barrier(0);
            }
            __builtin_amdgcn_s_setprio(1);
            #pragma unroll
            for (int ks = 0; ks < 2; ++ks)
                #pragma unroll
                for (int j = 0; j < 2; ++j)
                    #pragma unroll
                    for (int i = 0; i < 4; ++i)
                        acc[qi*4+i][qj*2+j] = __builtin_amdgcn_mfma_f32_16x16x32_bf16(
                            av[ks][i], bv[ks][j], acc[qi*4+i][qj*2+j], 0, 0, 0);
            __builtin_amdgcn_s_setprio(0);
            if (PHASED) __builtin_amdgcn_s_barrier();
        }

        if (tt + 1 < NT) {
            asm volatile("s_waitcnt vmcnt(0)" ::: "memory");
            __builtin_amdgcn_sched_barrier(0);
            __builtin_amdgcn_s_barrier();
            __builtin_amdgcn_sched_barrier(0);
        }
    }
    #undef STAGEV2

    const int colb = col0 + wc * 64 + lr;
    const int rowb = row0 + wr * 128 + lk * 4;
    float bj[4];
    #pragma unroll
    for (int j = 0; j < 4; ++j) bj[j] = bias[colb + j * 16];

    #pragma unroll
    for (int i = 0; i < 8; ++i) {
        #pragma unroll
        for (int r = 0; r < 4; ++r) {
            const size_t row = rowb + i * 16 + r;
            #pragma unroll
            for (int j = 0; j < 4; ++j) {
                float x = fmaxf(acc[i][j][r] + bj[j], 0.f);
                C[row * (size_t)N + colb + j * 16] = f2bf(x);
            }
        }
    }
}

// ---------------------------------------------------------------------------
// gemm128: proven pipeline (counted vmcnt(4), triple buffer, distance-2,
// T2 swizzle) at 128x128 / 4 waves / 48 KiB. For narrow-N GEMMs 6/7.
// ---------------------------------------------------------------------------
template<bool OUT_F32, int ACT>
__global__ __launch_bounds__(256, 2) void gemm128(
    const unsigned short* __restrict__ A, const unsigned short* __restrict__ Bt,
    const float* __restrict__ bias, void* __restrict__ Cp,
    int M, int N, int K, int ldc, int cc0,
    const int* __restrict__ dom, int biasStride)
{
    __shared__ alignas(16) unsigned short lds[3][2][128 * 32];  // 48 KiB

    const int nbx = N >> 7;
    int wg = blockIdx.x;
    const int nwg = gridDim.x;
    if ((nwg & 7) == 0) {
        const int cpx = nwg >> 3;
        wg = (wg & 7) * cpx + (wg >> 3);
    }
    const int bx = wg % nbx, by = wg / nbx;
    const int row0 = by << 7, col0 = bx << 7;

    const int t  = threadIdx.x;
    const int w  = t >> 6, l = t & 63;
    const int wr = w >> 1, wc = w & 1;
    const int lr = l & 15, lk = l >> 4;
    const int rsw = (lr >> 1) & 3;
    const int srow = l >> 2;
    const int skel = ((l & 3) ^ ((l >> 3) & 3)) * 8;

    f32x4 acc[4][4];
    #pragma unroll
    for (int i = 0; i < 4; ++i)
        #pragma unroll
        for (int j = 0; j < 4; ++j)
            acc[i][j] = (f32x4)(0.f);

    const int NT = K >> 5;

    #define STAGE128(tile_)  do {                                            \
        const int k0_  = (tile_) << 5;                                       \
        const int buf_ = (tile_) % 3;                                        \
        _Pragma("unroll")                                                    \
        for (int s_ = 0; s_ < 2; ++s_) {                                     \
            const int c_   = w * 2 + s_;                                     \
            const int row_ = c_ * 16 + srow;                                 \
            __builtin_amdgcn_global_load_lds(                                \
                TO_GLB(A + (size_t)(row0 + row_) * K + k0_ + skel),          \
                TO_LDS((char*)&lds[buf_][0][0] + c_ * 1024), 16, 0, 0);      \
            __builtin_amdgcn_global_load_lds(                                \
                TO_GLB(Bt + (size_t)(col0 + row_) * K + k0_ + skel),         \
                TO_LDS((char*)&lds[buf_][1][0] + c_ * 1024), 16, 0, 0);      \
        }                                                                    \
    } while (0)

    STAGE128(0);
    if (NT > 1) {
        STAGE128(1);
        asm volatile("s_waitcnt vmcnt(4)" ::: "memory");
    } else {
        asm volatile("s_waitcnt vmcnt(0)" ::: "memory");
    }
    __builtin_amdgcn_sched_barrier(0);
    __builtin_amdgcn_s_barrier();
    __builtin_amdgcn_sched_barrier(0);

    for (int tt = 0; tt < NT; ++tt) {
        const int buf = tt % 3;
        if (tt + 2 < NT) STAGE128(tt + 2);
        __builtin_amdgcn_sched_barrier(0);

        bf16x8 af[4], bfv[4];
        #pragma unroll
        for (int i = 0; i < 4; ++i)
            af[i]  = *(const bf16x8*)&lds[buf][0][(wr*64 + i*16 + lr) * 32 + (lk ^ rsw) * 8];
        #pragma unroll
        for (int j = 0; j < 4; ++j)
            bfv[j] = *(const bf16x8*)&lds[buf][1][(wc*64 + j*16 + lr) * 32 + (lk ^ rsw) * 8];

        #pragma unroll
        for (int j = 0; j < 4; ++j)
            #pragma unroll
            for (int i = 0; i < 4; ++i)
                acc[i][j] = __builtin_amdgcn_mfma_f32_16x16x32_bf16(
                    af[i], bfv[j], acc[i][j], 0, 0, 0);

        if (tt + 1 < NT) {
            if (tt + 2 < NT) asm volatile("s_waitcnt vmcnt(4)" ::: "memory");
            else             asm volatile("s_waitcnt vmcnt(0)" ::: "memory");
            __builtin_amdgcn_sched_barrier(0);
            __builtin_amdgcn_s_barrier();
            __builtin_amdgcn_sched_barrier(0);
        }
    }
    #undef STAGE128

    if (dom) bias += (*dom) * biasStride;
    const int colb = col0 + wc * 64 + lr;
    const int rowb = row0 + wr * 64 + lk * 4;
    float bj[4];
    #pragma unroll
    for (int j = 0; j < 4; ++j) bj[j] = bias[colb + j * 16];

    #pragma unroll
    for (int i = 0; i < 4; ++i) {
        #pragma unroll
        for (int r = 0; r < 4; ++r) {
            const size_t row = rowb + i * 16 + r;
            #pragma unroll
            for (int j = 0; j < 4; ++j) {
                float x = acc[i][j][r] + bj[j];
                if (ACT == 1)      x = fmaxf(x, 0.f);
                else if (ACT == 2) x = (x > 0.f) ? x : LEAKS * x;
                const size_t idx = row * (size_t)ldc + cc0 + colb + j * 16;
                if (OUT_F32) ((float*)Cp)[idx] = x;
                else         ((unsigned short*)Cp)[idx] = f2bf(x);
            }
        }
    }
}

// ---------------------------------------------------------------------------
// BatchNorm stats + heads — unchanged (proven).
// ---------------------------------------------------------------------------
__global__ __launch_bounds__(256) void bn_stats_a(
    const float* __restrict__ X, float* __restrict__ psum, float* __restrict__ pss)
{
    const int c  = blockIdx.x * 256 + threadIdx.x;
    const int rb = blockIdx.y;
    float s = 0.f, ss = 0.f;
    const int r0 = rb * 256;
    for (int r = r0; r < r0 + 256; ++r) {
        float v = X[(size_t)r * XW + c];
        s += v; ss = fmaf(v, v, ss);
    }
    psum[rb * XW + c] = s;
    pss [rb * XW + c] = ss;
}

__global__ __launch_bounds__(256) void bn_stats_b(
    const float* __restrict__ psum, const float* __restrict__ pss,
    const float* __restrict__ gamma, const float* __restrict__ beta,
    float* __restrict__ scale, float* __restrict__ shift)
{
    const int c = blockIdx.x * 256 + threadIdx.x;
    float s = 0.f, ss = 0.f;
    for (int rb = 0; rb < 32; ++rb) { s += psum[rb * XW + c]; ss += pss[rb * XW + c]; }
    const float inv = 1.f / (float)BQ;
    const float mean = s * inv;
    const float var  = ss * inv - mean * mean;
    const float sc = gamma[c] * rsqrtf(var + BN_EPS);
    scale[c] = sc;
    shift[c] = beta[c] - mean * sc;
}

__global__ __launch_bounds__(256) void head_kernel(
    const float* __restrict__ X, const float* __restrict__ scale,
    const float* __restrict__ shift, const int* __restrict__ tt,
    const float* __restrict__ Wh1, const float* __restrict__ bh1,
    const float* __restrict__ Wh2, const float* __restrict__ bh2,
    const float* __restrict__ Wh3, const float* __restrict__ bh3,
    float* __restrict__ out)
{
    __shared__ float xs[4][XW];
    __shared__ float y1[4][H1N];
    __shared__ float y2[4][H2N + 2];

    const int t = threadIdx.x;
    const int w = t >> 6;
    const int l = t & 63;
    const int s = blockIdx.x * 4 + w;
    const int d = tt[s];

    #pragma unroll 4
    for (int i = 0; i < XW / 64; ++i) {
        const int c = i * 64 + l;
        xs[w][c] = fmaf(X[(size_t)s * XW + c], scale[c], shift[c]);
    }
    __syncthreads();

    if (l < H1N) {
        const float* W1 = Wh1 + (size_t)d * XW * H1N;
        float acc = bh1[d * H1N + l];
        #pragma unroll 8
        for (int c = 0; c < XW; ++c)
            acc = fmaf(xs[w][c], W1[c * H1N + l], acc);
        y1[w][l] = fmaxf(acc, 0.f);
    }
    __syncthreads();

    if (l < H2N) {
        const float* W2 = Wh2 + (size_t)d * H1N * H2N;
        float acc = bh2[d * H2N + l];
        #pragma unroll
        for (int c = 0; c < H1N; ++c)
            acc = fmaf(y1[w][c], W2[c * H2N + l], acc);
        y2[w][l] = fmaxf(acc, 0.f);
    }
    __syncthreads();

    if (l < NWAY) {
        const float* W3 = Wh3 + (size_t)d * H2N * NWAY;
        float acc = bh3[d * NWAY + l];
        #pragma unroll
        for (int c = 0; c < H2N; ++c)
            acc = fmaf(y2[w][c], W3[c * NWAY + l], acc);
        out[(size_t)s * NWAY + l] = acc;
    }
}

// ---------------------------------------------------------------------------
extern "C" void kernel_launch(void* const* d_in, const int* in_sizes, int n_in,
                              void* d_out, int out_size, void* d_ws, size_t ws_size,
                              hipStream_t stream)
{
    const float* x_s   = (const float*)d_in[0];
    const float* x_p   = (const float*)d_in[1];
    const int*   tt    = (const int*)  d_in[2];
    const int*   dom   = (const int*)  d_in[3];
    const float* W_in  = (const float*)d_in[4];
    const float* b_in  = (const float*)d_in[5];
    const float* W_hid = (const float*)d_in[6];
    const float* b_hid = (const float*)d_in[7];
    const float* W_out = (const float*)d_in[8];
    const float* b_out = (const float*)d_in[9];
    const float* Wp    = (const float*)d_in[10];
    const float* bp    = (const float*)d_in[11];
    const float* gamma = (const float*)d_in[12];
    const float* beta  = (const float*)d_in[13];
    const float* Wh1   = (const float*)d_in[14];
    const float* bh1   = (const float*)d_in[15];
    const float* Wh2   = (const float*)d_in[16];
    const float* bh2   = (const float*)d_in[17];
    const float* Wh3   = (const float*)d_in[18];
    const float* bh3   = (const float*)d_in[19];
    float* out = (float*)d_out;

    const dim3 blk(256);
    char* w = (char*)d_ws;

    const size_t FAST_NEED = 470810624ull;

    if (ws_size >= FAST_NEED) {
        unsigned short* xb    = (unsigned short*)w;                    // 192M
        unsigned short* WinT  = (unsigned short*)(w + 201326592);      // 96M region
        unsigned short* WoutT = (unsigned short*)(w + 201326592);      //  8M
        unsigned short* WpT   = (unsigned short*)(w + 209715200);      // 24M
        unsigned short* actA  = (unsigned short*)(w + 301989888);      // 64M
        unsigned short* actB  = (unsigned short*)(w + 369098752);      // 64M
        float*          X     = (float*)(w + 369098752);               // aliases actB
        unsigned short* WhidT = (unsigned short*)(w + 436207616);      // 32M
        float*          psum  = (float*)(w + 469762048);
        float*          pss   = psum + 32 * XW;
        float*          scale = pss  + 32 * XW;
        float*          shift = scale + XW;

        cvt_bf16<<<dim3(2048), blk, 0, stream>>>(x_s, xb, (long long)BQ * FIN / 8);
        transpose_cvt<<<dim3(SUN/64,  FIN/64), blk, 0, stream>>>(W_in,  WinT,  FIN, SUN,  nullptr);
        transpose_cvt<<<dim3(SUN/64,  SUN/64), blk, 0, stream>>>(W_hid, WhidT, SUN, SUN,  nullptr);

        // GEMM1 (v2, compiler-scheduled phases)
        gemm256v2<false><<<dim3(512), dim3(512), 0, stream>>>(xb, WinT, b_in, actA, BQ, SUN, FIN);

        transpose_cvt<<<dim3(HIDN/64, SUN/64), blk, 0, stream>>>(W_out, WoutT, SUN, HIDN, nullptr);
        transpose_cvt<<<dim3(HIDN/64, FIN/64), blk, 0, stream>>>(Wp,    WpT,   FIN, HIDN, dom);
        cvt_bf16<<<dim3(2048), blk, 0, stream>>>(x_p, xb, (long long)BQ * FIN / 8);

        // hidden layers: A/B experiment — false,true,false,true
        gemm256v2<false><<<dim3(512), dim3(512), 0, stream>>>(actA, WhidT, b_hid, actB, BQ, SUN, SUN);
        gemm256v2<true ><<<dim3(512), dim3(512), 0, stream>>>(actB, WhidT, b_hid, actA, BQ, SUN, SUN);
        gemm256v2<false><<<dim3(512), dim3(512), 0, stream>>>(actA, WhidT, b_hid, actB, BQ, SUN, SUN);
        gemm256v2<true ><<<dim3(512), dim3(512), 0, stream>>>(actB, WhidT, b_hid, actA, BQ, SUN, SUN);

        gemm128<true,1><<<dim3(512), blk, 0, stream>>>(
            actA, WoutT, b_out, X, BQ, HIDN, SUN, XW, 0, nullptr, 0);
        gemm128<true,2><<<dim3(512), blk, 0, stream>>>(
            xb, WpT, bp, X, BQ, HIDN, FIN, XW, HIDN, dom, HIDN);

        bn_stats_a<<<dim3(XW/256, 32), blk, 0, stream>>>(X, psum, pss);
        bn_stats_b<<<dim3(XW/256),     blk, 0, stream>>>(psum, pss, gamma, beta, scale, shift);
        head_kernel<<<dim3(BQ/4), blk, 0, stream>>>(X, scale, shift, tt,
                                                    Wh1, bh1, Wh2, bh2, Wh3, bh3, out);
        return;
    }

    // ---------------- fallback: 256 MiB path ----------------
    unsigned short* actA  = (unsigned short*)w;
    unsigned short* actB  = (unsigned short*)(w + 67108864);
    float*          X     = (float*)(w + 67108864);
    unsigned short* WinT  = (unsigned short*)(w + 134217728);
    unsigned short* WoutT = (unsigned short*)(w + 134217728);
    unsigned short* WpT   = (unsigned short*)(w + 142606336);
    float*          psum  = (float*)(w + 167772160);
    float*          pss   = psum + 32 * XW;
    float*          scale = pss  + 32 * XW;
    float*          shift = scale + XW;
    unsigned short* WhidT = (unsigned short*)(w + 234881024);

    transpose_cvt<<<dim3(SUN/64,  FIN/64), blk, 0, stream>>>(W_in,  WinT,  FIN, SUN,  nullptr);
    transpose_cvt<<<dim3(SUN/64,  SUN/64), blk, 0, stream>>>(W_hid, WhidT, SUN, SUN,  nullptr);

    gemm_mfma<true,false,1><<<dim3(2048), blk, 0, stream>>>(
        x_s, WinT, b_in, actA, BQ, SUN, FIN, SUN, 0, nullptr, 0);

    transpose_cvt<<<dim3(HIDN/64, SUN/64), blk, 0, stream>>>(W_out, WoutT, SUN, HIDN, nullptr);
    transpose_cvt<<<dim3(HIDN/64, FIN/64), blk, 0, stream>>>(Wp,    WpT,   FIN, HIDN, dom);

    gemm256v2<false><<<dim3(512), dim3(512), 0, stream>>>(actA, WhidT, b_hid, actB, BQ, SUN, SUN);
    gemm256v2<false><<<dim3(512), dim3(512), 0, stream>>>(actB, WhidT, b_hid, actA, BQ, SUN, SUN);
    gemm256v2<false><<<dim3(512), dim3(512), 0, stream>>>(actA, WhidT, b_hid, actB, BQ, SUN, SUN);
    gemm256v2<false><<<dim3(512), dim3(512), 0, stream>>>(actB, WhidT, b_hid, actA, BQ, SUN, SUN);

    gemm128<true,1><<<dim3(512), blk, 0, stream>>>(
        actA, WoutT, b_out, X, BQ, HIDN, SUN, XW, 0, nullptr, 0);
    gemm_mfma<true,true,2><<<dim3(512), blk, 0, stream>>>(
        x_p, WpT, bp, X, BQ, HIDN, FIN, XW, HIDN, dom, HIDN);

    bn_stats_a<<<dim3(XW/256, 32), blk, 0, stream>>>(X, psum, pss);
    bn_stats_b<<<dim3(XW/256),     blk, 0, stream>>>(psum, pss, gamma, beta, scale, shift);
    head_kernel<<<dim3(BQ/4), blk, 0, stream>>>(X, scale, shift, tt,
                                                Wh1, bh1, Wh2, bh2, Wh3, bh3, out);
}

// Round 8
// 2558.915 us; speedup vs baseline: 1.1951x; 1.1951x over previous
//
#include <hip/hip_runtime.h>
#include <hip/hip_bf16.h>

// Problem constants
#define BQ    8192
#define FIN   12288
#define SUN   4096
#define HIDN  1024
#define XW    2048
#define H1N   28
#define H2N   14
#define NWAY  5
#define BN_EPS 1e-5f
#define LEAKS 0.001f

typedef __bf16 bf16x8 __attribute__((ext_vector_type(8)));
typedef float  f32x4  __attribute__((ext_vector_type(4)));
typedef unsigned short ushort8 __attribute__((ext_vector_type(8)));

__device__ __forceinline__ unsigned short f2bf(float f) {
    unsigned u = __float_as_uint(f);
    unsigned r = u + 0x7fffu + ((u >> 16) & 1u);   // RNE
    return (unsigned short)(r >> 16);
}

__device__ __forceinline__ ushort8 cvt8(const float4 a, const float4 b) {
    union { __bf16 h[8]; ushort8 u; } r;
    r.h[0] = (__bf16)a.x; r.h[1] = (__bf16)a.y;
    r.h[2] = (__bf16)a.z; r.h[3] = (__bf16)a.w;
    r.h[4] = (__bf16)b.x; r.h[5] = (__bf16)b.y;
    r.h[6] = (__bf16)b.z; r.h[7] = (__bf16)b.w;
    return r.u;
}

#define TO_LDS(p) ((__attribute__((address_space(3))) void*)(p))
#define TO_GLB(p) ((const __attribute__((address_space(1))) void*)(p))

// LDS tile layout (v1/d): row-major [row][32] bf16 (64 B rows). T2 XOR-swizzle:
// logical k-granule lk of row r at phys granule lk ^ ((r>>1)&3); staged via
// linear dest + pre-swizzled global source; reads XOR with (lr>>1)&3.

// ---------------------------------------------------------------------------
__global__ __launch_bounds__(256) void cvt_bf16(
    const float* __restrict__ in, unsigned short* __restrict__ out, long long n8)
{
    const long long idx = (long long)blockIdx.x * 256 + threadIdx.x;
    const long long stride = (long long)gridDim.x * 256;
    for (long long i = idx; i < n8; i += stride) {
        const float4 a = ((const float4*)in)[2 * i];
        const float4 b = ((const float4*)in)[2 * i + 1];
        ((ushort8*)out)[i] = cvt8(a, b);
    }
}

// ---------------------------------------------------------------------------
__global__ __launch_bounds__(256) void transpose_cvt(
    const float* __restrict__ in, unsigned short* __restrict__ out,
    int R, int Cc, const int* __restrict__ dom)
{
    if (dom) in += (size_t)(*dom) * (size_t)R * (size_t)Cc;
    __shared__ float tile[64][65];
    const int t  = threadIdx.x;
    const int tr = t >> 4;
    const int tc = t & 15;
    const int c0 = blockIdx.x * 64;
    const int r0 = blockIdx.y * 64;

    #pragma unroll
    for (int q = 0; q < 4; ++q) {
        const int r = r0 + tr + q * 16;
        const float4 v = *(const float4*)&in[(size_t)r * Cc + c0 + tc * 4];
        tile[tc*4+0][tr + q*16] = v.x;
        tile[tc*4+1][tr + q*16] = v.y;
        tile[tc*4+2][tr + q*16] = v.z;
        tile[tc*4+3][tr + q*16] = v.w;
    }
    __syncthreads();
    #pragma unroll
    for (int q = 0; q < 4; ++q) {
        const int c = c0 + tr + q * 16;
        ushort4 o;
        o.x = f2bf(tile[tr + q*16][tc*4+0]);
        o.y = f2bf(tile[tr + q*16][tc*4+1]);
        o.z = f2bf(tile[tr + q*16][tc*4+2]);
        o.w = f2bf(tile[tr + q*16][tc*4+3]);
        *(ushort4*)&out[(size_t)c * R + r0 + tc * 4] = o;
    }
}

// ---------------------------------------------------------------------------
// m97-structure bf16 MFMA GEMM (128x128, 2-barrier) — fp32-A fallback only.
// ---------------------------------------------------------------------------
template<bool A_F32, bool OUT_F32, int ACT>
__global__ __launch_bounds__(256) void gemm_mfma(
    const void* __restrict__ Ap, const unsigned short* __restrict__ Bt,
    const float* __restrict__ bias, void* __restrict__ Cp,
    int M, int N, int K, int ldc, int cc0,
    const int* __restrict__ dom, int biasStride)
{
    __shared__ alignas(16) unsigned short As[128 * 32];
    __shared__ alignas(16) unsigned short Bs[128 * 32];

    const int nbx = N >> 7;
    int wg = blockIdx.x;
    const int nwg = gridDim.x;
    if ((nwg & 7) == 0) {
        const int cpx = nwg >> 3;
        wg = (wg & 7) * cpx + (wg >> 3);
    }
    const int bx = wg % nbx, by = wg / nbx;
    const int row0 = by << 7, col0 = bx << 7;

    const int t  = threadIdx.x;
    const int w  = t >> 6;
    const int l  = t & 63;
    const int wr = w >> 1, wc = w & 1;
    const int lr = l & 15, lk = l >> 4;
    const int rsw = (lr >> 1) & 3;

    f32x4 acc[4][4];
    #pragma unroll
    for (int i = 0; i < 4; ++i)
        #pragma unroll
        for (int j = 0; j < 4; ++j)
            acc[i][j] = (f32x4)(0.f);

    const int srow = l >> 2;
    const int skb  = (((l & 3) ^ ((l >> 3) & 3)) * 16);
    const float* Af = (const float*)Ap;
    const unsigned short* Ab = (const unsigned short*)Ap;

    for (int k0 = 0; k0 < K; k0 += 32) {
        __syncthreads();

        #pragma unroll
        for (int c = 0; c < 2; ++c) {
            const int inst = w * 2 + c;
            const int row  = inst * 16 + srow;
            const char* src = (const char*)Bt +
                (((size_t)(col0 + row) * K + k0) * 2 + skb);
            char* dst = (char*)Bs + inst * 1024;
            __builtin_amdgcn_global_load_lds(TO_GLB(src), TO_LDS(dst), 16, 0, 0);
        }
        if (!A_F32) {
            #pragma unroll
            for (int c = 0; c < 2; ++c) {
                const int inst = w * 2 + c;
                const int row  = inst * 16 + srow;
                const char* src = (const char*)Ab +
                    (((size_t)(row0 + row) * K + k0) * 2 + skb);
                char* dst = (char*)As + inst * 1024;
                __builtin_amdgcn_global_load_lds(TO_GLB(src), TO_LDS(dst), 16, 0, 0);
            }
        } else {
            #pragma unroll
            for (int c = 0; c < 2; ++c) {
                const int ci  = t + 256 * c;
                const int row = ci >> 2;
                const int ko  = (((ci & 3) ^ ((ci >> 3) & 3)) * 8);
                const float* s = Af + (size_t)(row0 + row) * K + k0 + ko;
                const float4 v0 = *(const float4*)s;
                const float4 v1 = *(const float4*)(s + 4);
                *(ushort8*)&As[ci * 8] = cvt8(v0, v1);
            }
        }
        __syncthreads();

        bf16x8 af[4], bfv[4];
        #pragma unroll
        for (int i = 0; i < 4; ++i)
            af[i]  = *(const bf16x8*)&As[(wr*64 + i*16 + lr) * 32 + (lk ^ rsw) * 8];
        #pragma unroll
        for (int j = 0; j < 4; ++j)
            bfv[j] = *(const bf16x8*)&Bs[(wc*64 + j*16 + lr) * 32 + (lk ^ rsw) * 8];
        #pragma unroll
        for (int i = 0; i < 4; ++i)
            #pragma unroll
            for (int j = 0; j < 4; ++j)
                acc[i][j] = __builtin_amdgcn_mfma_f32_16x16x32_bf16(
                    af[i], bfv[j], acc[i][j], 0, 0, 0);
    }

    if (dom) bias += (*dom) * biasStride;
    const int colb = col0 + wc * 64 + lr;
    const int rowb = row0 + wr * 64 + lk * 4;
    float bj[4];
    #pragma unroll
    for (int j = 0; j < 4; ++j) bj[j] = bias[colb + j * 16];

    #pragma unroll
    for (int i = 0; i < 4; ++i) {
        #pragma unroll
        for (int r = 0; r < 4; ++r) {
            const size_t row = rowb + i * 16 + r;
            #pragma unroll
            for (int j = 0; j < 4; ++j) {
                float x = acc[i][j][r] + bj[j];
                if (ACT == 1)      x = fmaxf(x, 0.f);
                else if (ACT == 2) x = (x > 0.f) ? x : LEAKS * x;
                const size_t idx = row * (size_t)ldc + cc0 + colb + j * 16;
                if (OUT_F32) ((float*)Cp)[idx] = x;
                else         ((unsigned short*)Cp)[idx] = f2bf(x);
            }
        }
    }
}

// ---------------------------------------------------------------------------
// gemm256 (v1, PROVEN): 256x256, BK=32, 8 waves, TRIPLE-buffered (96 KiB),
// distance-2 prefetch, counted vmcnt(4), T2 swizzle, setprio.
// ---------------------------------------------------------------------------
__global__ __launch_bounds__(512, 2) void gemm256(
    const unsigned short* __restrict__ A, const unsigned short* __restrict__ Bt,
    const float* __restrict__ bias, unsigned short* __restrict__ C,
    int M, int N, int K)
{
    __shared__ alignas(16) unsigned short lds[3][2][256 * 32];  // 96 KiB

    const int nbx = N >> 8;
    int wg = blockIdx.x;
    const int nwg = gridDim.x;
    if ((nwg & 7) == 0) {
        const int cpx = nwg >> 3;
        wg = (wg & 7) * cpx + (wg >> 3);
    }
    const int bx = wg % nbx, by = wg / nbx;
    const int row0 = by << 8, col0 = bx << 8;

    const int t  = threadIdx.x;
    const int w  = t >> 6, l = t & 63;
    const int wr = w >> 2, wc = w & 3;
    const int lr = l & 15, lk = l >> 4;
    const int rsw = (lr >> 1) & 3;
    const int srow = l >> 2;
    const int skel = ((l & 3) ^ ((l >> 3) & 3)) * 8;

    f32x4 acc[8][4];
    #pragma unroll
    for (int i = 0; i < 8; ++i)
        #pragma unroll
        for (int j = 0; j < 4; ++j)
            acc[i][j] = (f32x4)(0.f);

    const int NT = K >> 5;

    #define STAGE256(tile_)  do {                                            \
        const int k0_  = (tile_) << 5;                                       \
        const int buf_ = (tile_) % 3;                                        \
        _Pragma("unroll")                                                    \
        for (int s_ = 0; s_ < 2; ++s_) {                                     \
            const int c_   = w * 2 + s_;                                     \
            const int row_ = c_ * 16 + srow;                                 \
            __builtin_amdgcn_global_load_lds(                                \
                TO_GLB(A + (size_t)(row0 + row_) * K + k0_ + skel),          \
                TO_LDS((char*)&lds[buf_][0][0] + c_ * 1024), 16, 0, 0);      \
            __builtin_amdgcn_global_load_lds(                                \
                TO_GLB(Bt + (size_t)(col0 + row_) * K + k0_ + skel),         \
                TO_LDS((char*)&lds[buf_][1][0] + c_ * 1024), 16, 0, 0);      \
        }                                                                    \
    } while (0)

    STAGE256(0);
    if (NT > 1) {
        STAGE256(1);
        asm volatile("s_waitcnt vmcnt(4)" ::: "memory");
    } else {
        asm volatile("s_waitcnt vmcnt(0)" ::: "memory");
    }
    __builtin_amdgcn_sched_barrier(0);
    __builtin_amdgcn_s_barrier();
    __builtin_amdgcn_sched_barrier(0);

    for (int tt = 0; tt < NT; ++tt) {
        const int buf = tt % 3;
        if (tt + 2 < NT) STAGE256(tt + 2);
        __builtin_amdgcn_sched_barrier(0);

        bf16x8 af[8], bfv[4];
        #pragma unroll
        for (int i = 0; i < 8; ++i)
            af[i]  = *(const bf16x8*)&lds[buf][0][(wr*128 + i*16 + lr) * 32 + (lk ^ rsw) * 8];
        #pragma unroll
        for (int j = 0; j < 4; ++j)
            bfv[j] = *(const bf16x8*)&lds[buf][1][(wc*64 + j*16 + lr) * 32 + (lk ^ rsw) * 8];

        __builtin_amdgcn_s_setprio(1);
        #pragma unroll
        for (int j = 0; j < 4; ++j)
            #pragma unroll
            for (int i = 0; i < 8; ++i)
                acc[i][j] = __builtin_amdgcn_mfma_f32_16x16x32_bf16(
                    af[i], bfv[j], acc[i][j], 0, 0, 0);
        __builtin_amdgcn_s_setprio(0);

        if (tt + 1 < NT) {
            if (tt + 2 < NT) asm volatile("s_waitcnt vmcnt(4)" ::: "memory");
            else             asm volatile("s_waitcnt vmcnt(0)" ::: "memory");
            __builtin_amdgcn_sched_barrier(0);
            __builtin_amdgcn_s_barrier();
            __builtin_amdgcn_sched_barrier(0);
        }
    }
    #undef STAGE256

    const int colb = col0 + wc * 64 + lr;
    const int rowb = row0 + wr * 128 + lk * 4;
    float bj[4];
    #pragma unroll
    for (int j = 0; j < 4; ++j) bj[j] = bias[colb + j * 16];

    #pragma unroll
    for (int i = 0; i < 8; ++i) {
        #pragma unroll
        for (int r = 0; r < 4; ++r) {
            const size_t row = rowb + i * 16 + r;
            #pragma unroll
            for (int j = 0; j < 4; ++j) {
                float x = fmaxf(acc[i][j][r] + bj[j], 0.f);
                C[row * (size_t)N + colb + j * 16] = f2bf(x);
            }
        }
    }
}

// ---------------------------------------------------------------------------
// gemm256d (EXPERIMENT): same geometry/swizzle as gemm256 but DOUBLE-buffered
// (64 KiB -> 2 blocks/CU). Drain vmcnt(0)+barrier per tile; the co-resident
// block hides the drain (cross-block overlap). A/B vs gemm256 on hidden GEMMs.
// Race ledger: tile t reads buf[t&1]; stage(t+1) targets buf[(t+1)&1] whose
// t-1 readers delivered to regs before their MFMAs, all preceding the
// end-of-(t-1) barrier (sched_barrier-fenced). vmcnt(0)+barrier at tile end
// publishes stage(t+1) to all waves before tile t+1 reads it.
// ---------------------------------------------------------------------------
__global__ __launch_bounds__(512, 2) void gemm256d(
    const unsigned short* __restrict__ A, const unsigned short* __restrict__ Bt,
    const float* __restrict__ bias, unsigned short* __restrict__ C,
    int M, int N, int K)
{
    __shared__ alignas(16) unsigned short lds[2][2][256 * 32];  // 64 KiB

    const int nbx = N >> 8;
    int wg = blockIdx.x;
    const int nwg = gridDim.x;
    if ((nwg & 7) == 0) {
        const int cpx = nwg >> 3;
        wg = (wg & 7) * cpx + (wg >> 3);
    }
    const int bx = wg % nbx, by = wg / nbx;
    const int row0 = by << 8, col0 = bx << 8;

    const int t  = threadIdx.x;
    const int w  = t >> 6, l = t & 63;
    const int wr = w >> 2, wc = w & 3;
    const int lr = l & 15, lk = l >> 4;
    const int rsw = (lr >> 1) & 3;
    const int srow = l >> 2;
    const int skel = ((l & 3) ^ ((l >> 3) & 3)) * 8;

    f32x4 acc[8][4];
    #pragma unroll
    for (int i = 0; i < 8; ++i)
        #pragma unroll
        for (int j = 0; j < 4; ++j)
            acc[i][j] = (f32x4)(0.f);

    const int NT = K >> 5;

    #define STAGE256D(tile_)  do {                                           \
        const int k0_  = (tile_) << 5;                                       \
        const int buf_ = (tile_) & 1;                                        \
        _Pragma("unroll")                                                    \
        for (int s_ = 0; s_ < 2; ++s_) {                                     \
            const int c_   = w * 2 + s_;                                     \
            const int row_ = c_ * 16 + srow;                                 \
            __builtin_amdgcn_global_load_lds(                                \
                TO_GLB(A + (size_t)(row0 + row_) * K + k0_ + skel),          \
                TO_LDS((char*)&lds[buf_][0][0] + c_ * 1024), 16, 0, 0);      \
            __builtin_amdgcn_global_load_lds(                                \
                TO_GLB(Bt + (size_t)(col0 + row_) * K + k0_ + skel),         \
                TO_LDS((char*)&lds[buf_][1][0] + c_ * 1024), 16, 0, 0);      \
        }                                                                    \
    } while (0)

    STAGE256D(0);
    asm volatile("s_waitcnt vmcnt(0)" ::: "memory");
    __builtin_amdgcn_sched_barrier(0);
    __builtin_amdgcn_s_barrier();
    __builtin_amdgcn_sched_barrier(0);

    for (int tt = 0; tt < NT; ++tt) {
        const int buf = tt & 1;
        if (tt + 1 < NT) STAGE256D(tt + 1);
        __builtin_amdgcn_sched_barrier(0);     // keep stage issue at tile top

        bf16x8 af[8], bfv[4];
        #pragma unroll
        for (int i = 0; i < 8; ++i)
            af[i]  = *(const bf16x8*)&lds[buf][0][(wr*128 + i*16 + lr) * 32 + (lk ^ rsw) * 8];
        #pragma unroll
        for (int j = 0; j < 4; ++j)
            bfv[j] = *(const bf16x8*)&lds[buf][1][(wc*64 + j*16 + lr) * 32 + (lk ^ rsw) * 8];

        __builtin_amdgcn_s_setprio(1);
        #pragma unroll
        for (int j = 0; j < 4; ++j)
            #pragma unroll
            for (int i = 0; i < 8; ++i)
                acc[i][j] = __builtin_amdgcn_mfma_f32_16x16x32_bf16(
                    af[i], bfv[j], acc[i][j], 0, 0, 0);
        __builtin_amdgcn_s_setprio(0);

        if (tt + 1 < NT) {
            asm volatile("s_waitcnt vmcnt(0)" ::: "memory");
            __builtin_amdgcn_sched_barrier(0);
            __builtin_amdgcn_s_barrier();
            __builtin_amdgcn_sched_barrier(0);
        }
    }
    #undef STAGE256D

    const int colb = col0 + wc * 64 + lr;
    const int rowb = row0 + wr * 128 + lk * 4;
    float bj[4];
    #pragma unroll
    for (int j = 0; j < 4; ++j) bj[j] = bias[colb + j * 16];

    #pragma unroll
    for (int i = 0; i < 8; ++i) {
        #pragma unroll
        for (int r = 0; r < 4; ++r) {
            const size_t row = rowb + i * 16 + r;
            #pragma unroll
            for (int j = 0; j < 4; ++j) {
                float x = fmaxf(acc[i][j][r] + bj[j], 0.f);
                C[row * (size_t)N + colb + j * 16] = f2bf(x);
            }
        }
    }
}

// ---------------------------------------------------------------------------
// gemm128: proven pipeline at 128x128 / 4 waves / 48 KiB. Narrow-N GEMMs 6/7.
// ---------------------------------------------------------------------------
template<bool OUT_F32, int ACT>
__global__ __launch_bounds__(256, 2) void gemm128(
    const unsigned short* __restrict__ A, const unsigned short* __restrict__ Bt,
    const float* __restrict__ bias, void* __restrict__ Cp,
    int M, int N, int K, int ldc, int cc0,
    const int* __restrict__ dom, int biasStride)
{
    __shared__ alignas(16) unsigned short lds[3][2][128 * 32];  // 48 KiB

    const int nbx = N >> 7;
    int wg = blockIdx.x;
    const int nwg = gridDim.x;
    if ((nwg & 7) == 0) {
        const int cpx = nwg >> 3;
        wg = (wg & 7) * cpx + (wg >> 3);
    }
    const int bx = wg % nbx, by = wg / nbx;
    const int row0 = by << 7, col0 = bx << 7;

    const int t  = threadIdx.x;
    const int w  = t >> 6, l = t & 63;
    const int wr = w >> 1, wc = w & 1;
    const int lr = l & 15, lk = l >> 4;
    const int rsw = (lr >> 1) & 3;
    const int srow = l >> 2;
    const int skel = ((l & 3) ^ ((l >> 3) & 3)) * 8;

    f32x4 acc[4][4];
    #pragma unroll
    for (int i = 0; i < 4; ++i)
        #pragma unroll
        for (int j = 0; j < 4; ++j)
            acc[i][j] = (f32x4)(0.f);

    const int NT = K >> 5;

    #define STAGE128(tile_)  do {                                            \
        const int k0_  = (tile_) << 5;                                       \
        const int buf_ = (tile_) % 3;                                        \
        _Pragma("unroll")                                                    \
        for (int s_ = 0; s_ < 2; ++s_) {                                     \
            const int c_   = w * 2 + s_;                                     \
            const int row_ = c_ * 16 + srow;                                 \
            __builtin_amdgcn_global_load_lds(                                \
                TO_GLB(A + (size_t)(row0 + row_) * K + k0_ + skel),          \
                TO_LDS((char*)&lds[buf_][0][0] + c_ * 1024), 16, 0, 0);      \
            __builtin_amdgcn_global_load_lds(                                \
                TO_GLB(Bt + (size_t)(col0 + row_) * K + k0_ + skel),         \
                TO_LDS((char*)&lds[buf_][1][0] + c_ * 1024), 16, 0, 0);      \
        }                                                                    \
    } while (0)

    STAGE128(0);
    if (NT > 1) {
        STAGE128(1);
        asm volatile("s_waitcnt vmcnt(4)" ::: "memory");
    } else {
        asm volatile("s_waitcnt vmcnt(0)" ::: "memory");
    }
    __builtin_amdgcn_sched_barrier(0);
    __builtin_amdgcn_s_barrier();
    __builtin_amdgcn_sched_barrier(0);

    for (int tt = 0; tt < NT; ++tt) {
        const int buf = tt % 3;
        if (tt + 2 < NT) STAGE128(tt + 2);
        __builtin_amdgcn_sched_barrier(0);

        bf16x8 af[4], bfv[4];
        #pragma unroll
        for (int i = 0; i < 4; ++i)
            af[i]  = *(const bf16x8*)&lds[buf][0][(wr*64 + i*16 + lr) * 32 + (lk ^ rsw) * 8];
        #pragma unroll
        for (int j = 0; j < 4; ++j)
            bfv[j] = *(const bf16x8*)&lds[buf][1][(wc*64 + j*16 + lr) * 32 + (lk ^ rsw) * 8];

        #pragma unroll
        for (int j = 0; j < 4; ++j)
            #pragma unroll
            for (int i = 0; i < 4; ++i)
                acc[i][j] = __builtin_amdgcn_mfma_f32_16x16x32_bf16(
                    af[i], bfv[j], acc[i][j], 0, 0, 0);

        if (tt + 1 < NT) {
            if (tt + 2 < NT) asm volatile("s_waitcnt vmcnt(4)" ::: "memory");
            else             asm volatile("s_waitcnt vmcnt(0)" ::: "memory");
            __builtin_amdgcn_sched_barrier(0);
            __builtin_amdgcn_s_barrier();
            __builtin_amdgcn_sched_barrier(0);
        }
    }
    #undef STAGE128

    if (dom) bias += (*dom) * biasStride;
    const int colb = col0 + wc * 64 + lr;
    const int rowb = row0 + wr * 64 + lk * 4;
    float bj[4];
    #pragma unroll
    for (int j = 0; j < 4; ++j) bj[j] = bias[colb + j * 16];

    #pragma unroll
    for (int i = 0; i < 4; ++i) {
        #pragma unroll
        for (int r = 0; r < 4; ++r) {
            const size_t row = rowb + i * 16 + r;
            #pragma unroll
            for (int j = 0; j < 4; ++j) {
                float x = acc[i][j][r] + bj[j];
                if (ACT == 1)      x = fmaxf(x, 0.f);
                else if (ACT == 2) x = (x > 0.f) ? x : LEAKS * x;
                const size_t idx = row * (size_t)ldc + cc0 + colb + j * 16;
                if (OUT_F32) ((float*)Cp)[idx] = x;
                else         ((unsigned short*)Cp)[idx] = f2bf(x);
            }
        }
    }
}

// ---------------------------------------------------------------------------
// BatchNorm stats + heads — unchanged (proven).
// ---------------------------------------------------------------------------
__global__ __launch_bounds__(256) void bn_stats_a(
    const float* __restrict__ X, float* __restrict__ psum, float* __restrict__ pss)
{
    const int c  = blockIdx.x * 256 + threadIdx.x;
    const int rb = blockIdx.y;
    float s = 0.f, ss = 0.f;
    const int r0 = rb * 256;
    for (int r = r0; r < r0 + 256; ++r) {
        float v = X[(size_t)r * XW + c];
        s += v; ss = fmaf(v, v, ss);
    }
    psum[rb * XW + c] = s;
    pss [rb * XW + c] = ss;
}

__global__ __launch_bounds__(256) void bn_stats_b(
    const float* __restrict__ psum, const float* __restrict__ pss,
    const float* __restrict__ gamma, const float* __restrict__ beta,
    float* __restrict__ scale, float* __restrict__ shift)
{
    const int c = blockIdx.x * 256 + threadIdx.x;
    float s = 0.f, ss = 0.f;
    for (int rb = 0; rb < 32; ++rb) { s += psum[rb * XW + c]; ss += pss[rb * XW + c]; }
    const float inv = 1.f / (float)BQ;
    const float mean = s * inv;
    const float var  = ss * inv - mean * mean;
    const float sc = gamma[c] * rsqrtf(var + BN_EPS);
    scale[c] = sc;
    shift[c] = beta[c] - mean * sc;
}

__global__ __launch_bounds__(256) void head_kernel(
    const float* __restrict__ X, const float* __restrict__ scale,
    const float* __restrict__ shift, const int* __restrict__ tt,
    const float* __restrict__ Wh1, const float* __restrict__ bh1,
    const float* __restrict__ Wh2, const float* __restrict__ bh2,
    const float* __restrict__ Wh3, const float* __restrict__ bh3,
    float* __restrict__ out)
{
    __shared__ float xs[4][XW];
    __shared__ float y1[4][H1N];
    __shared__ float y2[4][H2N + 2];

    const int t = threadIdx.x;
    const int w = t >> 6;
    const int l = t & 63;
    const int s = blockIdx.x * 4 + w;
    const int d = tt[s];

    #pragma unroll 4
    for (int i = 0; i < XW / 64; ++i) {
        const int c = i * 64 + l;
        xs[w][c] = fmaf(X[(size_t)s * XW + c], scale[c], shift[c]);
    }
    __syncthreads();

    if (l < H1N) {
        const float* W1 = Wh1 + (size_t)d * XW * H1N;
        float acc = bh1[d * H1N + l];
        #pragma unroll 8
        for (int c = 0; c < XW; ++c)
            acc = fmaf(xs[w][c], W1[c * H1N + l], acc);
        y1[w][l] = fmaxf(acc, 0.f);
    }
    __syncthreads();

    if (l < H2N) {
        const float* W2 = Wh2 + (size_t)d * H1N * H2N;
        float acc = bh2[d * H2N + l];
        #pragma unroll
        for (int c = 0; c < H1N; ++c)
            acc = fmaf(y1[w][c], W2[c * H2N + l], acc);
        y2[w][l] = fmaxf(acc, 0.f);
    }
    __syncthreads();

    if (l < NWAY) {
        const float* W3 = Wh3 + (size_t)d * H2N * NWAY;
        float acc = bh3[d * NWAY + l];
        #pragma unroll
        for (int c = 0; c < H2N; ++c)
            acc = fmaf(y2[w][c], W3[c * NWAY + l], acc);
        out[(size_t)s * NWAY + l] = acc;
    }
}

// ---------------------------------------------------------------------------
extern "C" void kernel_launch(void* const* d_in, const int* in_sizes, int n_in,
                              void* d_out, int out_size, void* d_ws, size_t ws_size,
                              hipStream_t stream)
{
    const float* x_s   = (const float*)d_in[0];
    const float* x_p   = (const float*)d_in[1];
    const int*   tt    = (const int*)  d_in[2];
    const int*   dom   = (const int*)  d_in[3];
    const float* W_in  = (const float*)d_in[4];
    const float* b_in  = (const float*)d_in[5];
    const float* W_hid = (const float*)d_in[6];
    const float* b_hid = (const float*)d_in[7];
    const float* W_out = (const float*)d_in[8];
    const float* b_out = (const float*)d_in[9];
    const float* Wp    = (const float*)d_in[10];
    const float* bp    = (const float*)d_in[11];
    const float* gamma = (const float*)d_in[12];
    const float* beta  = (const float*)d_in[13];
    const float* Wh1   = (const float*)d_in[14];
    const float* bh1   = (const float*)d_in[15];
    const float* Wh2   = (const float*)d_in[16];
    const float* bh2   = (const float*)d_in[17];
    const float* Wh3   = (const float*)d_in[18];
    const float* bh3   = (const float*)d_in[19];
    float* out = (float*)d_out;

    const dim3 blk(256);
    char* w = (char*)d_ws;

    const size_t FAST_NEED = 470810624ull;

    if (ws_size >= FAST_NEED) {
        unsigned short* xb    = (unsigned short*)w;                    // 192M
        unsigned short* WinT  = (unsigned short*)(w + 201326592);      // 96M region
        unsigned short* WoutT = (unsigned short*)(w + 201326592);      //  8M
        unsigned short* WpT   = (unsigned short*)(w + 209715200);      // 24M
        unsigned short* actA  = (unsigned short*)(w + 301989888);      // 64M
        unsigned short* actB  = (unsigned short*)(w + 369098752);      // 64M
        float*          X     = (float*)(w + 369098752);               // aliases actB
        unsigned short* WhidT = (unsigned short*)(w + 436207616);      // 32M
        float*          psum  = (float*)(w + 469762048);
        float*          pss   = psum + 32 * XW;
        float*          scale = pss  + 32 * XW;
        float*          shift = scale + XW;

        cvt_bf16<<<dim3(2048), blk, 0, stream>>>(x_s, xb, (long long)BQ * FIN / 8);
        transpose_cvt<<<dim3(SUN/64,  FIN/64), blk, 0, stream>>>(W_in,  WinT,  FIN, SUN,  nullptr);
        transpose_cvt<<<dim3(SUN/64,  SUN/64), blk, 0, stream>>>(W_hid, WhidT, SUN, SUN,  nullptr);

        // GEMM1 — proven v1
        gemm256<<<dim3(512), dim3(512), 0, stream>>>(xb, WinT, b_in, actA, BQ, SUN, FIN);

        transpose_cvt<<<dim3(HIDN/64, SUN/64), blk, 0, stream>>>(W_out, WoutT, SUN, HIDN, nullptr);
        transpose_cvt<<<dim3(HIDN/64, FIN/64), blk, 0, stream>>>(Wp,    WpT,   FIN, HIDN, dom);
        cvt_bf16<<<dim3(2048), blk, 0, stream>>>(x_p, xb, (long long)BQ * FIN / 8);

        // hidden layers A/B: d, v1, d, v1
        gemm256d<<<dim3(512), dim3(512), 0, stream>>>(actA, WhidT, b_hid, actB, BQ, SUN, SUN);
        gemm256 <<<dim3(512), dim3(512), 0, stream>>>(actB, WhidT, b_hid, actA, BQ, SUN, SUN);
        gemm256d<<<dim3(512), dim3(512), 0, stream>>>(actA, WhidT, b_hid, actB, BQ, SUN, SUN);
        gemm256 <<<dim3(512), dim3(512), 0, stream>>>(actB, WhidT, b_hid, actA, BQ, SUN, SUN);

        gemm128<true,1><<<dim3(512), blk, 0, stream>>>(
            actA, WoutT, b_out, X, BQ, HIDN, SUN, XW, 0, nullptr, 0);
        gemm128<true,2><<<dim3(512), blk, 0, stream>>>(
            xb, WpT, bp, X, BQ, HIDN, FIN, XW, HIDN, dom, HIDN);

        bn_stats_a<<<dim3(XW/256, 32), blk, 0, stream>>>(X, psum, pss);
        bn_stats_b<<<dim3(XW/256),     blk, 0, stream>>>(psum, pss, gamma, beta, scale, shift);
        head_kernel<<<dim3(BQ/4), blk, 0, stream>>>(X, scale, shift, tt,
                                                    Wh1, bh1, Wh2, bh2, Wh3, bh3, out);
        return;
    }

    // ---------------- fallback: 256 MiB path ----------------
    unsigned short* actA  = (unsigned short*)w;
    unsigned short* actB  = (unsigned short*)(w + 67108864);
    float*          X     = (float*)(w + 67108864);
    unsigned short* WinT  = (unsigned short*)(w + 134217728);
    unsigned short* WoutT = (unsigned short*)(w + 134217728);
    unsigned short* WpT   = (unsigned short*)(w + 142606336);
    float*          psum  = (float*)(w + 167772160);
    float*          pss   = psum + 32 * XW;
    float*          scale = pss  + 32 * XW;
    float*          shift = scale + XW;
    unsigned short* WhidT = (unsigned short*)(w + 234881024);

    transpose_cvt<<<dim3(SUN/64,  FIN/64), blk, 0, stream>>>(W_in,  WinT,  FIN, SUN,  nullptr);
    transpose_cvt<<<dim3(SUN/64,  SUN/64), blk, 0, stream>>>(W_hid, WhidT, SUN, SUN,  nullptr);

    gemm_mfma<true,false,1><<<dim3(2048), blk, 0, stream>>>(
        x_s, WinT, b_in, actA, BQ, SUN, FIN, SUN, 0, nullptr, 0);

    transpose_cvt<<<dim3(HIDN/64, SUN/64), blk, 0, stream>>>(W_out, WoutT, SUN, HIDN, nullptr);
    transpose_cvt<<<dim3(HIDN/64, FIN/64), blk, 0, stream>>>(Wp,    WpT,   FIN, HIDN, dom);

    gemm256<<<dim3(512), dim3(512), 0, stream>>>(actA, WhidT, b_hid, actB, BQ, SUN, SUN);
    gemm256<<<dim3(512), dim3(512), 0, stream>>>(actB, WhidT, b_hid, actA, BQ, SUN, SUN);
    gemm256<<<dim3(512), dim3(512), 0, stream>>>(actA, WhidT, b_hid, actB, BQ, SUN, SUN);
    gemm256<<<dim3(512), dim3(512), 0, stream>>>(actB, WhidT, b_hid, actA, BQ, SUN, SUN);

    gemm128<true,1><<<dim3(512), blk, 0, stream>>>(
        actA, WoutT, b_out, X, BQ, HIDN, SUN, XW, 0, nullptr, 0);
    gemm_mfma<true,true,2><<<dim3(512), blk, 0, stream>>>(
        x_p, WpT, bp, X, BQ, HIDN, FIN, XW, HIDN, dom, HIDN);

    bn_stats_a<<<dim3(XW/256, 32), blk, 0, stream>>>(X, psum, pss);
    bn_stats_b<<<dim3(XW/256),     blk, 0, stream>>>(psum, pss, gamma, beta, scale, shift);
    head_kernel<<<dim3(BQ/4), blk, 0, stream>>>(X, scale, shift, tt,
                                                Wh1, bh1, Wh2, bh2, Wh3, bh3, out);
}

// Round 10
// 2545.698 us; speedup vs baseline: 1.2013x; 1.0052x over previous
//
#include <hip/hip_runtime.h>
#include <hip/hip_bf16.h>

// Problem constants
#define BQ    8192
#define FIN   12288
#define SUN   4096
#define HIDN  1024
#define XW    2048
#define H1N   28
#define H2N   14
#define NWAY  5
#define BN_EPS 1e-5f
#define LEAKS 0.001f

typedef __bf16 bf16x8 __attribute__((ext_vector_type(8)));
typedef float  f32x4  __attribute__((ext_vector_type(4)));
typedef unsigned short ushort8 __attribute__((ext_vector_type(8)));

__device__ __forceinline__ unsigned short f2bf(float f) {
    unsigned u = __float_as_uint(f);
    unsigned r = u + 0x7fffu + ((u >> 16) & 1u);   // RNE
    return (unsigned short)(r >> 16);
}

__device__ __forceinline__ ushort8 cvt8(const float4 a, const float4 b) {
    union { __bf16 h[8]; ushort8 u; } r;
    r.h[0] = (__bf16)a.x; r.h[1] = (__bf16)a.y;
    r.h[2] = (__bf16)a.z; r.h[3] = (__bf16)a.w;
    r.h[4] = (__bf16)b.x; r.h[5] = (__bf16)b.y;
    r.h[6] = (__bf16)b.z; r.h[7] = (__bf16)b.w;
    return r.u;
}

#define TO_LDS(p) ((__attribute__((address_space(3))) void*)(p))
#define TO_GLB(p) ((const __attribute__((address_space(1))) void*)(p))

// LDS tile layout: row-major [row][32] bf16 (64 B rows). T2 XOR-swizzle:
// logical k-granule lk of row r at phys granule lk ^ ((r>>1)&3); staged via
// linear dest + pre-swizzled global source; reads XOR with (lr>>1)&3.

// ---------------------------------------------------------------------------
__global__ __launch_bounds__(256) void cvt_bf16(
    const float* __restrict__ in, unsigned short* __restrict__ out, long long n8)
{
    const long long idx = (long long)blockIdx.x * 256 + threadIdx.x;
    const long long stride = (long long)gridDim.x * 256;
    for (long long i = idx; i < n8; i += stride) {
        const float4 a = ((const float4*)in)[2 * i];
        const float4 b = ((const float4*)in)[2 * i + 1];
        ((ushort8*)out)[i] = cvt8(a, b);
    }
}

// ---------------------------------------------------------------------------
__global__ __launch_bounds__(256) void transpose_cvt(
    const float* __restrict__ in, unsigned short* __restrict__ out,
    int R, int Cc, const int* __restrict__ dom)
{
    if (dom) in += (size_t)(*dom) * (size_t)R * (size_t)Cc;
    __shared__ float tile[64][65];
    const int t  = threadIdx.x;
    const int tr = t >> 4;
    const int tc = t & 15;
    const int c0 = blockIdx.x * 64;
    const int r0 = blockIdx.y * 64;

    #pragma unroll
    for (int q = 0; q < 4; ++q) {
        const int r = r0 + tr + q * 16;
        const float4 v = *(const float4*)&in[(size_t)r * Cc + c0 + tc * 4];
        tile[tc*4+0][tr + q*16] = v.x;
        tile[tc*4+1][tr + q*16] = v.y;
        tile[tc*4+2][tr + q*16] = v.z;
        tile[tc*4+3][tr + q*16] = v.w;
    }
    __syncthreads();
    #pragma unroll
    for (int q = 0; q < 4; ++q) {
        const int c = c0 + tr + q * 16;
        ushort4 o;
        o.x = f2bf(tile[tr + q*16][tc*4+0]);
        o.y = f2bf(tile[tr + q*16][tc*4+1]);
        o.z = f2bf(tile[tr + q*16][tc*4+2]);
        o.w = f2bf(tile[tr + q*16][tc*4+3]);
        *(ushort4*)&out[(size_t)c * R + r0 + tc * 4] = o;
    }
}

// ---------------------------------------------------------------------------
// m97-structure bf16 MFMA GEMM (128x128, 2-barrier) — fp32-A fallback only.
// ---------------------------------------------------------------------------
template<bool A_F32, bool OUT_F32, int ACT>
__global__ __launch_bounds__(256) void gemm_mfma(
    const void* __restrict__ Ap, const unsigned short* __restrict__ Bt,
    const float* __restrict__ bias, void* __restrict__ Cp,
    int M, int N, int K, int ldc, int cc0,
    const int* __restrict__ dom, int biasStride)
{
    __shared__ alignas(16) unsigned short As[128 * 32];
    __shared__ alignas(16) unsigned short Bs[128 * 32];

    const int nbx = N >> 7;
    int wg = blockIdx.x;
    const int nwg = gridDim.x;
    if ((nwg & 7) == 0) {
        const int cpx = nwg >> 3;
        wg = (wg & 7) * cpx + (wg >> 3);
    }
    const int bx = wg % nbx, by = wg / nbx;
    const int row0 = by << 7, col0 = bx << 7;

    const int t  = threadIdx.x;
    const int w  = t >> 6;
    const int l  = t & 63;
    const int wr = w >> 1, wc = w & 1;
    const int lr = l & 15, lk = l >> 4;
    const int rsw = (lr >> 1) & 3;

    f32x4 acc[4][4];
    #pragma unroll
    for (int i = 0; i < 4; ++i)
        #pragma unroll
        for (int j = 0; j < 4; ++j)
            acc[i][j] = (f32x4)(0.f);

    const int srow = l >> 2;
    const int skb  = (((l & 3) ^ ((l >> 3) & 3)) * 16);
    const float* Af = (const float*)Ap;
    const unsigned short* Ab = (const unsigned short*)Ap;

    for (int k0 = 0; k0 < K; k0 += 32) {
        __syncthreads();

        #pragma unroll
        for (int c = 0; c < 2; ++c) {
            const int inst = w * 2 + c;
            const int row  = inst * 16 + srow;
            const char* src = (const char*)Bt +
                (((size_t)(col0 + row) * K + k0) * 2 + skb);
            char* dst = (char*)Bs + inst * 1024;
            __builtin_amdgcn_global_load_lds(TO_GLB(src), TO_LDS(dst), 16, 0, 0);
        }
        if (!A_F32) {
            #pragma unroll
            for (int c = 0; c < 2; ++c) {
                const int inst = w * 2 + c;
                const int row  = inst * 16 + srow;
                const char* src = (const char*)Ab +
                    (((size_t)(row0 + row) * K + k0) * 2 + skb);
                char* dst = (char*)As + inst * 1024;
                __builtin_amdgcn_global_load_lds(TO_GLB(src), TO_LDS(dst), 16, 0, 0);
            }
        } else {
            #pragma unroll
            for (int c = 0; c < 2; ++c) {
                const int ci  = t + 256 * c;
                const int row = ci >> 2;
                const int ko  = (((ci & 3) ^ ((ci >> 3) & 3)) * 8);
                const float* s = Af + (size_t)(row0 + row) * K + k0 + ko;
                const float4 v0 = *(const float4*)s;
                const float4 v1 = *(const float4*)(s + 4);
                *(ushort8*)&As[ci * 8] = cvt8(v0, v1);
            }
        }
        __syncthreads();

        bf16x8 af[4], bfv[4];
        #pragma unroll
        for (int i = 0; i < 4; ++i)
            af[i]  = *(const bf16x8*)&As[(wr*64 + i*16 + lr) * 32 + (lk ^ rsw) * 8];
        #pragma unroll
        for (int j = 0; j < 4; ++j)
            bfv[j] = *(const bf16x8*)&Bs[(wc*64 + j*16 + lr) * 32 + (lk ^ rsw) * 8];
        #pragma unroll
        for (int i = 0; i < 4; ++i)
            #pragma unroll
            for (int j = 0; j < 4; ++j)
                acc[i][j] = __builtin_amdgcn_mfma_f32_16x16x32_bf16(
                    af[i], bfv[j], acc[i][j], 0, 0, 0);
    }

    if (dom) bias += (*dom) * biasStride;
    const int colb = col0 + wc * 64 + lr;
    const int rowb = row0 + wr * 64 + lk * 4;
    float bj[4];
    #pragma unroll
    for (int j = 0; j < 4; ++j) bj[j] = bias[colb + j * 16];

    #pragma unroll
    for (int i = 0; i < 4; ++i) {
        #pragma unroll
        for (int r = 0; r < 4; ++r) {
            const size_t row = rowb + i * 16 + r;
            #pragma unroll
            for (int j = 0; j < 4; ++j) {
                float x = acc[i][j][r] + bj[j];
                if (ACT == 1)      x = fmaxf(x, 0.f);
                else if (ACT == 2) x = (x > 0.f) ? x : LEAKS * x;
                const size_t idx = row * (size_t)ldc + cc0 + colb + j * 16;
                if (OUT_F32) ((float*)Cp)[idx] = x;
                else         ((unsigned short*)Cp)[idx] = f2bf(x);
            }
        }
    }
}

// ---------------------------------------------------------------------------
// gemm256 (v1, PROVEN): 256x256, BK=32, 8 waves, TRIPLE-buffered (96 KiB),
// distance-2 prefetch, counted vmcnt(4), T2 swizzle, setprio.
// PHASES=true: compute split into 2 phases of 16 MFMA with per-phase
// {ds_read subtile -> s_barrier -> lgkmcnt(0) -> setprio -> MFMA}
// choreography (m201-style role diversity). Staging/wait structure identical;
// added barriers are inside a read-only region -> cannot race.
// ---------------------------------------------------------------------------
template<bool PHASES>
__global__ __launch_bounds__(512, 2) void gemm256(
    const unsigned short* __restrict__ A, const unsigned short* __restrict__ Bt,
    const float* __restrict__ bias, unsigned short* __restrict__ C,
    int M, int N, int K)
{
    __shared__ alignas(16) unsigned short lds[3][2][256 * 32];  // 96 KiB

    const int nbx = N >> 8;
    int wg = blockIdx.x;
    const int nwg = gridDim.x;
    if ((nwg & 7) == 0) {
        const int cpx = nwg >> 3;
        wg = (wg & 7) * cpx + (wg >> 3);
    }
    const int bx = wg % nbx, by = wg / nbx;
    const int row0 = by << 8, col0 = bx << 8;

    const int t  = threadIdx.x;
    const int w  = t >> 6, l = t & 63;
    const int wr = w >> 2, wc = w & 3;
    const int lr = l & 15, lk = l >> 4;
    const int rsw = (lr >> 1) & 3;
    const int srow = l >> 2;
    const int skel = ((l & 3) ^ ((l >> 3) & 3)) * 8;

    f32x4 acc[8][4];
    #pragma unroll
    for (int i = 0; i < 8; ++i)
        #pragma unroll
        for (int j = 0; j < 4; ++j)
            acc[i][j] = (f32x4)(0.f);

    const int NT = K >> 5;

    #define STAGE256(tile_)  do {                                            \
        const int k0_  = (tile_) << 5;                                       \
        const int buf_ = (tile_) % 3;                                        \
        _Pragma("unroll")                                                    \
        for (int s_ = 0; s_ < 2; ++s_) {                                     \
            const int c_   = w * 2 + s_;                                     \
            const int row_ = c_ * 16 + srow;                                 \
            __builtin_amdgcn_global_load_lds(                                \
                TO_GLB(A + (size_t)(row0 + row_) * K + k0_ + skel),          \
                TO_LDS((char*)&lds[buf_][0][0] + c_ * 1024), 16, 0, 0);      \
            __builtin_amdgcn_global_load_lds(                                \
                TO_GLB(Bt + (size_t)(col0 + row_) * K + k0_ + skel),         \
                TO_LDS((char*)&lds[buf_][1][0] + c_ * 1024), 16, 0, 0);      \
        }                                                                    \
    } while (0)

    STAGE256(0);
    if (NT > 1) {
        STAGE256(1);
        asm volatile("s_waitcnt vmcnt(4)" ::: "memory");
    } else {
        asm volatile("s_waitcnt vmcnt(0)" ::: "memory");
    }
    __builtin_amdgcn_sched_barrier(0);
    __builtin_amdgcn_s_barrier();
    __builtin_amdgcn_sched_barrier(0);

    for (int tt = 0; tt < NT; ++tt) {
        const int buf = tt % 3;
        if (tt + 2 < NT) STAGE256(tt + 2);
        __builtin_amdgcn_sched_barrier(0);

        if (!PHASES) {
            bf16x8 af[8], bfv[4];
            #pragma unroll
            for (int i = 0; i < 8; ++i)
                af[i]  = *(const bf16x8*)&lds[buf][0][(wr*128 + i*16 + lr) * 32 + (lk ^ rsw) * 8];
            #pragma unroll
            for (int j = 0; j < 4; ++j)
                bfv[j] = *(const bf16x8*)&lds[buf][1][(wc*64 + j*16 + lr) * 32 + (lk ^ rsw) * 8];

            __builtin_amdgcn_s_setprio(1);
            #pragma unroll
            for (int j = 0; j < 4; ++j)
                #pragma unroll
                for (int i = 0; i < 8; ++i)
                    acc[i][j] = __builtin_amdgcn_mfma_f32_16x16x32_bf16(
                        af[i], bfv[j], acc[i][j], 0, 0, 0);
            __builtin_amdgcn_s_setprio(0);
        } else {
            // phase 0: rows 0-63 of wave tile + all B fragments
            bf16x8 af0[4], bfv[4];
            #pragma unroll
            for (int i = 0; i < 4; ++i)
                af0[i] = *(const bf16x8*)&lds[buf][0][(wr*128 + i*16 + lr) * 32 + (lk ^ rsw) * 8];
            #pragma unroll
            for (int j = 0; j < 4; ++j)
                bfv[j] = *(const bf16x8*)&lds[buf][1][(wc*64 + j*16 + lr) * 32 + (lk ^ rsw) * 8];
            __builtin_amdgcn_s_barrier();
            asm volatile("s_waitcnt lgkmcnt(0)" ::: "memory");
            __builtin_amdgcn_sched_barrier(0);           // rule #18 fence
            __builtin_amdgcn_s_setprio(1);
            #pragma unroll
            for (int j = 0; j < 4; ++j)
                #pragma unroll
                for (int i = 0; i < 4; ++i)
                    acc[i][j] = __builtin_amdgcn_mfma_f32_16x16x32_bf16(
                        af0[i], bfv[j], acc[i][j], 0, 0, 0);
            __builtin_amdgcn_s_setprio(0);

            // phase 1: rows 64-127 of wave tile
            bf16x8 af1[4];
            #pragma unroll
            for (int i = 0; i < 4; ++i)
                af1[i] = *(const bf16x8*)&lds[buf][0][(wr*128 + (4+i)*16 + lr) * 32 + (lk ^ rsw) * 8];
            __builtin_amdgcn_s_barrier();
            asm volatile("s_waitcnt lgkmcnt(0)" ::: "memory");
            __builtin_amdgcn_sched_barrier(0);           // rule #18 fence
            __builtin_amdgcn_s_setprio(1);
            #pragma unroll
            for (int j = 0; j < 4; ++j)
                #pragma unroll
                for (int i = 0; i < 4; ++i)
                    acc[4+i][j] = __builtin_amdgcn_mfma_f32_16x16x32_bf16(
                        af1[i], bfv[j], acc[4+i][j], 0, 0, 0);
            __builtin_amdgcn_s_setprio(0);
        }

        if (tt + 1 < NT) {
            if (tt + 2 < NT) asm volatile("s_waitcnt vmcnt(4)" ::: "memory");
            else             asm volatile("s_waitcnt vmcnt(0)" ::: "memory");
            __builtin_amdgcn_sched_barrier(0);
            __builtin_amdgcn_s_barrier();
            __builtin_amdgcn_sched_barrier(0);
        }
    }
    #undef STAGE256

    const int colb = col0 + wc * 64 + lr;
    const int rowb = row0 + wr * 128 + lk * 4;
    float bj[4];
    #pragma unroll
    for (int j = 0; j < 4; ++j) bj[j] = bias[colb + j * 16];

    #pragma unroll
    for (int i = 0; i < 8; ++i) {
        #pragma unroll
        for (int r = 0; r < 4; ++r) {
            const size_t row = rowb + i * 16 + r;
            #pragma unroll
            for (int j = 0; j < 4; ++j) {
                float x = fmaxf(acc[i][j][r] + bj[j], 0.f);
                C[row * (size_t)N + colb + j * 16] = f2bf(x);
            }
        }
    }
}

// ---------------------------------------------------------------------------
// gemm128: proven pipeline at 128x128 / 4 waves / 48 KiB. Narrow-N GEMMs 6/7.
// ---------------------------------------------------------------------------
template<bool OUT_F32, int ACT>
__global__ __launch_bounds__(256, 2) void gemm128(
    const unsigned short* __restrict__ A, const unsigned short* __restrict__ Bt,
    const float* __restrict__ bias, void* __restrict__ Cp,
    int M, int N, int K, int ldc, int cc0,
    const int* __restrict__ dom, int biasStride)
{
    __shared__ alignas(16) unsigned short lds[3][2][128 * 32];  // 48 KiB

    const int nbx = N >> 7;
    int wg = blockIdx.x;
    const int nwg = gridDim.x;
    if ((nwg & 7) == 0) {
        const int cpx = nwg >> 3;
        wg = (wg & 7) * cpx + (wg >> 3);
    }
    const int bx = wg % nbx, by = wg / nbx;
    const int row0 = by << 7, col0 = bx << 7;

    const int t  = threadIdx.x;
    const int w  = t >> 6, l = t & 63;
    const int wr = w >> 1, wc = w & 1;
    const int lr = l & 15, lk = l >> 4;
    const int rsw = (lr >> 1) & 3;
    const int srow = l >> 2;
    const int skel = ((l & 3) ^ ((l >> 3) & 3)) * 8;

    f32x4 acc[4][4];
    #pragma unroll
    for (int i = 0; i < 4; ++i)
        #pragma unroll
        for (int j = 0; j < 4; ++j)
            acc[i][j] = (f32x4)(0.f);

    const int NT = K >> 5;

    #define STAGE128(tile_)  do {                                            \
        const int k0_  = (tile_) << 5;                                       \
        const int buf_ = (tile_) % 3;                                        \
        _Pragma("unroll")                                                    \
        for (int s_ = 0; s_ < 2; ++s_) {                                     \
            const int c_   = w * 2 + s_;                                     \
            const int row_ = c_ * 16 + srow;                                 \
            __builtin_amdgcn_global_load_lds(                                \
                TO_GLB(A + (size_t)(row0 + row_) * K + k0_ + skel),          \
                TO_LDS((char*)&lds[buf_][0][0] + c_ * 1024), 16, 0, 0);      \
            __builtin_amdgcn_global_load_lds(                                \
                TO_GLB(Bt + (size_t)(col0 + row_) * K + k0_ + skel),         \
                TO_LDS((char*)&lds[buf_][1][0] + c_ * 1024), 16, 0, 0);      \
        }                                                                    \
    } while (0)

    STAGE128(0);
    if (NT > 1) {
        STAGE128(1);
        asm volatile("s_waitcnt vmcnt(4)" ::: "memory");
    } else {
        asm volatile("s_waitcnt vmcnt(0)" ::: "memory");
    }
    __builtin_amdgcn_sched_barrier(0);
    __builtin_amdgcn_s_barrier();
    __builtin_amdgcn_sched_barrier(0);

    for (int tt = 0; tt < NT; ++tt) {
        const int buf = tt % 3;
        if (tt + 2 < NT) STAGE128(tt + 2);
        __builtin_amdgcn_sched_barrier(0);

        bf16x8 af[4], bfv[4];
        #pragma unroll
        for (int i = 0; i < 4; ++i)
            af[i]  = *(const bf16x8*)&lds[buf][0][(wr*64 + i*16 + lr) * 32 + (lk ^ rsw) * 8];
        #pragma unroll
        for (int j = 0; j < 4; ++j)
            bfv[j] = *(const bf16x8*)&lds[buf][1][(wc*64 + j*16 + lr) * 32 + (lk ^ rsw) * 8];

        #pragma unroll
        for (int j = 0; j < 4; ++j)
            #pragma unroll
            for (int i = 0; i < 4; ++i)
                acc[i][j] = __builtin_amdgcn_mfma_f32_16x16x32_bf16(
                    af[i], bfv[j], acc[i][j], 0, 0, 0);

        if (tt + 1 < NT) {
            if (tt + 2 < NT) asm volatile("s_waitcnt vmcnt(4)" ::: "memory");
            else             asm volatile("s_waitcnt vmcnt(0)" ::: "memory");
            __builtin_amdgcn_sched_barrier(0);
            __builtin_amdgcn_s_barrier();
            __builtin_amdgcn_sched_barrier(0);
        }
    }
    #undef STAGE128

    if (dom) bias += (*dom) * biasStride;
    const int colb = col0 + wc * 64 + lr;
    const int rowb = row0 + wr * 64 + lk * 4;
    float bj[4];
    #pragma unroll
    for (int j = 0; j < 4; ++j) bj[j] = bias[colb + j * 16];

    #pragma unroll
    for (int i = 0; i < 4; ++i) {
        #pragma unroll
        for (int r = 0; r < 4; ++r) {
            const size_t row = rowb + i * 16 + r;
            #pragma unroll
            for (int j = 0; j < 4; ++j) {
                float x = acc[i][j][r] + bj[j];
                if (ACT == 1)      x = fmaxf(x, 0.f);
                else if (ACT == 2) x = (x > 0.f) ? x : LEAKS * x;
                const size_t idx = row * (size_t)ldc + cc0 + colb + j * 16;
                if (OUT_F32) ((float*)Cp)[idx] = x;
                else         ((unsigned short*)Cp)[idx] = f2bf(x);
            }
        }
    }
}

// ---------------------------------------------------------------------------
// BatchNorm stats + heads — unchanged (proven; layer-3 index restored).
// ---------------------------------------------------------------------------
__global__ __launch_bounds__(256) void bn_stats_a(
    const float* __restrict__ X, float* __restrict__ psum, float* __restrict__ pss)
{
    const int c  = blockIdx.x * 256 + threadIdx.x;
    const int rb = blockIdx.y;
    float s = 0.f, ss = 0.f;
    const int r0 = rb * 256;
    for (int r = r0; r < r0 + 256; ++r) {
        float v = X[(size_t)r * XW + c];
        s += v; ss = fmaf(v, v, ss);
    }
    psum[rb * XW + c] = s;
    pss [rb * XW + c] = ss;
}

__global__ __launch_bounds__(256) void bn_stats_b(
    const float* __restrict__ psum, const float* __restrict__ pss,
    const float* __restrict__ gamma, const float* __restrict__ beta,
    float* __restrict__ scale, float* __restrict__ shift)
{
    const int c = blockIdx.x * 256 + threadIdx.x;
    float s = 0.f, ss = 0.f;
    for (int rb = 0; rb < 32; ++rb) { s += psum[rb * XW + c]; ss += pss[rb * XW + c]; }
    const float inv = 1.f / (float)BQ;
    const float mean = s * inv;
    const float var  = ss * inv - mean * mean;
    const float sc = gamma[c] * rsqrtf(var + BN_EPS);
    scale[c] = sc;
    shift[c] = beta[c] - mean * sc;
}

__global__ __launch_bounds__(256) void head_kernel(
    const float* __restrict__ X, const float* __restrict__ scale,
    const float* __restrict__ shift, const int* __restrict__ tt,
    const float* __restrict__ Wh1, const float* __restrict__ bh1,
    const float* __restrict__ Wh2, const float* __restrict__ bh2,
    const float* __restrict__ Wh3, const float* __restrict__ bh3,
    float* __restrict__ out)
{
    __shared__ float xs[4][XW];
    __shared__ float y1[4][H1N];
    __shared__ float y2[4][H2N + 2];

    const int t = threadIdx.x;
    const int w = t >> 6;
    const int l = t & 63;
    const int s = blockIdx.x * 4 + w;
    const int d = tt[s];

    #pragma unroll 4
    for (int i = 0; i < XW / 64; ++i) {
        const int c = i * 64 + l;
        xs[w][c] = fmaf(X[(size_t)s * XW + c], scale[c], shift[c]);
    }
    __syncthreads();

    if (l < H1N) {
        const float* W1 = Wh1 + (size_t)d * XW * H1N;
        float acc = bh1[d * H1N + l];
        #pragma unroll 8
        for (int c = 0; c < XW; ++c)
            acc = fmaf(xs[w][c], W1[c * H1N + l], acc);
        y1[w][l] = fmaxf(acc, 0.f);
    }
    __syncthreads();

    if (l < H2N) {
        const float* W2 = Wh2 + (size_t)d * H1N * H2N;
        float acc = bh2[d * H2N + l];
        #pragma unroll
        for (int c = 0; c < H1N; ++c)
            acc = fmaf(y1[w][c], W2[c * H2N + l], acc);
        y2[w][l] = fmaxf(acc, 0.f);
    }
    __syncthreads();

    if (l < NWAY) {
        const float* W3 = Wh3 + (size_t)d * H2N * NWAY;
        float acc = bh3[d * NWAY + l];
        #pragma unroll
        for (int c = 0; c < H2N; ++c)
            acc = fmaf(y2[w][c], W3[c * NWAY + l], acc);   // FIXED: c*NWAY+l
        out[(size_t)s * NWAY + l] = acc;
    }
}

// ---------------------------------------------------------------------------
extern "C" void kernel_launch(void* const* d_in, const int* in_sizes, int n_in,
                              void* d_out, int out_size, void* d_ws, size_t ws_size,
                              hipStream_t stream)
{
    const float* x_s   = (const float*)d_in[0];
    const float* x_p   = (const float*)d_in[1];
    const int*   tt    = (const int*)  d_in[2];
    const int*   dom   = (const int*)  d_in[3];
    const float* W_in  = (const float*)d_in[4];
    const float* b_in  = (const float*)d_in[5];
    const float* W_hid = (const float*)d_in[6];
    const float* b_hid = (const float*)d_in[7];
    const float* W_out = (const float*)d_in[8];
    const float* b_out = (const float*)d_in[9];
    const float* Wp    = (const float*)d_in[10];
    const float* bp    = (const float*)d_in[11];
    const float* gamma = (const float*)d_in[12];
    const float* beta  = (const float*)d_in[13];
    const float* Wh1   = (const float*)d_in[14];
    const float* bh1   = (const float*)d_in[15];
    const float* Wh2   = (const float*)d_in[16];
    const float* bh2   = (const float*)d_in[17];
    const float* Wh3   = (const float*)d_in[18];
    const float* bh3   = (const float*)d_in[19];
    float* out = (float*)d_out;

    const dim3 blk(256);
    char* w = (char*)d_ws;

    const size_t FAST_NEED = 470810624ull;

    if (ws_size >= FAST_NEED) {
        unsigned short* xb    = (unsigned short*)w;                    // 192M
        unsigned short* WinT  = (unsigned short*)(w + 201326592);      // 96M region
        unsigned short* WoutT = (unsigned short*)(w + 201326592);      //  8M
        unsigned short* WpT   = (unsigned short*)(w + 209715200);      // 24M
        unsigned short* actA  = (unsigned short*)(w + 301989888);      // 64M
        unsigned short* actB  = (unsigned short*)(w + 369098752);      // 64M
        float*          X     = (float*)(w + 369098752);               // aliases actB
        unsigned short* WhidT = (unsigned short*)(w + 436207616);      // 32M
        float*          psum  = (float*)(w + 469762048);
        float*          pss   = psum + 32 * XW;
        float*          scale = pss  + 32 * XW;
        float*          shift = scale + XW;

        cvt_bf16<<<dim3(2048), blk, 0, stream>>>(x_s, xb, (long long)BQ * FIN / 8);
        transpose_cvt<<<dim3(SUN/64,  FIN/64), blk, 0, stream>>>(W_in,  WinT,  FIN, SUN,  nullptr);
        transpose_cvt<<<dim3(SUN/64,  SUN/64), blk, 0, stream>>>(W_hid, WhidT, SUN, SUN,  nullptr);

        // GEMM1 — proven v1
        gemm256<false><<<dim3(512), dim3(512), 0, stream>>>(xb, WinT, b_in, actA, BQ, SUN, FIN);

        transpose_cvt<<<dim3(HIDN/64, SUN/64), blk, 0, stream>>>(W_out, WoutT, SUN, HIDN, nullptr);
        transpose_cvt<<<dim3(HIDN/64, FIN/64), blk, 0, stream>>>(Wp,    WpT,   FIN, HIDN, dom);
        cvt_bf16<<<dim3(2048), blk, 0, stream>>>(x_p, xb, (long long)BQ * FIN / 8);

        // hidden layers A/B: phased, v1, phased, v1
        gemm256<true ><<<dim3(512), dim3(512), 0, stream>>>(actA, WhidT, b_hid, actB, BQ, SUN, SUN);
        gemm256<false><<<dim3(512), dim3(512), 0, stream>>>(actB, WhidT, b_hid, actA, BQ, SUN, SUN);
        gemm256<true ><<<dim3(512), dim3(512), 0, stream>>>(actA, WhidT, b_hid, actB, BQ, SUN, SUN);
        gemm256<false><<<dim3(512), dim3(512), 0, stream>>>(actB, WhidT, b_hid, actA, BQ, SUN, SUN);

        gemm128<true,1><<<dim3(512), blk, 0, stream>>>(
            actA, WoutT, b_out, X, BQ, HIDN, SUN, XW, 0, nullptr, 0);
        gemm128<true,2><<<dim3(512), blk, 0, stream>>>(
            xb, WpT, bp, X, BQ, HIDN, FIN, XW, HIDN, dom, HIDN);

        bn_stats_a<<<dim3(XW/256, 32), blk, 0, stream>>>(X, psum, pss);
        bn_stats_b<<<dim3(XW/256),     blk, 0, stream>>>(psum, pss, gamma, beta, scale, shift);
        head_kernel<<<dim3(BQ/4), blk, 0, stream>>>(X, scale, shift, tt,
                                                    Wh1, bh1, Wh2, bh2, Wh3, bh3, out);
        return;
    }

    // ---------------- fallback: 256 MiB path ----------------
    unsigned short* actA  = (unsigned short*)w;
    unsigned short* actB  = (unsigned short*)(w + 67108864);
    float*          X     = (float*)(w + 67108864);
    unsigned short* WinT  = (unsigned short*)(w + 134217728);
    unsigned short* WoutT = (unsigned short*)(w + 134217728);
    unsigned short* WpT   = (unsigned short*)(w + 142606336);
    float*          psum  = (float*)(w + 167772160);
    float*          pss   = psum + 32 * XW;
    float*          scale = pss  + 32 * XW;
    float*          shift = scale + XW;
    unsigned short* WhidT = (unsigned short*)(w + 234881024);

    transpose_cvt<<<dim3(SUN/64,  FIN/64), blk, 0, stream>>>(W_in,  WinT,  FIN, SUN,  nullptr);
    transpose_cvt<<<dim3(SUN/64,  SUN/64), blk, 0, stream>>>(W_hid, WhidT, SUN, SUN,  nullptr);

    gemm_mfma<true,false,1><<<dim3(2048), blk, 0, stream>>>(
        x_s, WinT, b_in, actA, BQ, SUN, FIN, SUN, 0, nullptr, 0);

    transpose_cvt<<<dim3(HIDN/64, SUN/64), blk, 0, stream>>>(W_out, WoutT, SUN, HIDN, nullptr);
    transpose_cvt<<<dim3(HIDN/64, FIN/64), blk, 0, stream>>>(Wp,    WpT,   FIN, HIDN, dom);

    gemm256<false><<<dim3(512), dim3(512), 0, stream>>>(actA, WhidT, b_hid, actB, BQ, SUN, SUN);
    gemm256<false><<<dim3(512), dim3(512), 0, stream>>>(actB, WhidT, b_hid, actA, BQ, SUN, SUN);
    gemm256<false><<<dim3(512), dim3(512), 0, stream>>>(actA, WhidT, b_hid, actB, BQ, SUN, SUN);
    gemm256<false><<<dim3(512), dim3(512), 0, stream>>>(actB, WhidT, b_hid, actA, BQ, SUN, SUN);

    gemm128<true,1><<<dim3(512), blk, 0, stream>>>(
        actA, WoutT, b_out, X, BQ, HIDN, SUN, XW, 0, nullptr, 0);
    gemm_mfma<true,true,2><<<dim3(512), blk, 0, stream>>>(
        x_p, WpT, bp, X, BQ, HIDN, FIN, XW, HIDN, dom, HIDN);

    bn_stats_a<<<dim3(XW/256, 32), blk, 0, stream>>>(X, psum, pss);
    bn_stats_b<<<dim3(XW/256),     blk, 0, stream>>>(psum, pss, gamma, beta, scale, shift);
    head_kernel<<<dim3(BQ/4), blk, 0, stream>>>(X, scale, shift, tt,
                                                Wh1, bh1, Wh2, bh2, Wh3, bh3, out);
}

// Round 11
// 2486.661 us; speedup vs baseline: 1.2299x; 1.0237x over previous
//
#include <hip/hip_runtime.h>
#include <hip/hip_bf16.h>

// Problem constants
#define BQ    8192
#define FIN   12288
#define SUN   4096
#define HIDN  1024
#define XW    2048
#define H1N   28
#define H2N   14
#define NWAY  5
#define BN_EPS 1e-5f
#define LEAKS 0.001f

typedef __bf16 bf16x8 __attribute__((ext_vector_type(8)));
typedef float  f32x4  __attribute__((ext_vector_type(4)));
typedef unsigned short ushort8 __attribute__((ext_vector_type(8)));

__device__ __forceinline__ unsigned short f2bf(float f) {
    unsigned u = __float_as_uint(f);
    unsigned r = u + 0x7fffu + ((u >> 16) & 1u);   // RNE
    return (unsigned short)(r >> 16);
}

__device__ __forceinline__ ushort8 cvt8(const float4 a, const float4 b) {
    union { __bf16 h[8]; ushort8 u; } r;
    r.h[0] = (__bf16)a.x; r.h[1] = (__bf16)a.y;
    r.h[2] = (__bf16)a.z; r.h[3] = (__bf16)a.w;
    r.h[4] = (__bf16)b.x; r.h[5] = (__bf16)b.y;
    r.h[6] = (__bf16)b.z; r.h[7] = (__bf16)b.w;
    return r.u;
}

#define TO_LDS(p) ((__attribute__((address_space(3))) void*)(p))
#define TO_GLB(p) ((const __attribute__((address_space(1))) void*)(p))

// ---------------------------------------------------------------------------
__global__ __launch_bounds__(256) void cvt_bf16(
    const float* __restrict__ in, unsigned short* __restrict__ out, long long n8)
{
    const long long idx = (long long)blockIdx.x * 256 + threadIdx.x;
    const long long stride = (long long)gridDim.x * 256;
    for (long long i = idx; i < n8; i += stride) {
        const float4 a = ((const float4*)in)[2 * i];
        const float4 b = ((const float4*)in)[2 * i + 1];
        ((ushort8*)out)[i] = cvt8(a, b);
    }
}

// ---------------------------------------------------------------------------
__global__ __launch_bounds__(256) void transpose_cvt(
    const float* __restrict__ in, unsigned short* __restrict__ out,
    int R, int Cc, const int* __restrict__ dom)
{
    if (dom) in += (size_t)(*dom) * (size_t)R * (size_t)Cc;
    __shared__ float tile[64][65];
    const int t  = threadIdx.x;
    const int tr = t >> 4;
    const int tc = t & 15;
    const int c0 = blockIdx.x * 64;
    const int r0 = blockIdx.y * 64;

    #pragma unroll
    for (int q = 0; q < 4; ++q) {
        const int r = r0 + tr + q * 16;
        const float4 v = *(const float4*)&in[(size_t)r * Cc + c0 + tc * 4];
        tile[tc*4+0][tr + q*16] = v.x;
        tile[tc*4+1][tr + q*16] = v.y;
        tile[tc*4+2][tr + q*16] = v.z;
        tile[tc*4+3][tr + q*16] = v.w;
    }
    __syncthreads();
    #pragma unroll
    for (int q = 0; q < 4; ++q) {
        const int c = c0 + tr + q * 16;
        ushort4 o;
        o.x = f2bf(tile[tr + q*16][tc*4+0]);
        o.y = f2bf(tile[tr + q*16][tc*4+1]);
        o.z = f2bf(tile[tr + q*16][tc*4+2]);
        o.w = f2bf(tile[tr + q*16][tc*4+3]);
        *(ushort4*)&out[(size_t)c * R + r0 + tc * 4] = o;
    }
}

// ---------------------------------------------------------------------------
// m97-structure bf16 MFMA GEMM (128x128, 2-barrier) — fp32-A fallback only.
// ---------------------------------------------------------------------------
template<bool A_F32, bool OUT_F32, int ACT>
__global__ __launch_bounds__(256) void gemm_mfma(
    const void* __restrict__ Ap, const unsigned short* __restrict__ Bt,
    const float* __restrict__ bias, void* __restrict__ Cp,
    int M, int N, int K, int ldc, int cc0,
    const int* __restrict__ dom, int biasStride)
{
    __shared__ alignas(16) unsigned short As[128 * 32];
    __shared__ alignas(16) unsigned short Bs[128 * 32];

    const int nbx = N >> 7;
    int wg = blockIdx.x;
    const int nwg = gridDim.x;
    if ((nwg & 7) == 0) {
        const int cpx = nwg >> 3;
        wg = (wg & 7) * cpx + (wg >> 3);
    }
    const int bx = wg % nbx, by = wg / nbx;
    const int row0 = by << 7, col0 = bx << 7;

    const int t  = threadIdx.x;
    const int w  = t >> 6;
    const int l  = t & 63;
    const int wr = w >> 1, wc = w & 1;
    const int lr = l & 15, lk = l >> 4;
    const int rsw = (lr >> 1) & 3;

    f32x4 acc[4][4];
    #pragma unroll
    for (int i = 0; i < 4; ++i)
        #pragma unroll
        for (int j = 0; j < 4; ++j)
            acc[i][j] = (f32x4)(0.f);

    const int srow = l >> 2;
    const int skb  = (((l & 3) ^ ((l >> 3) & 3)) * 16);
    const float* Af = (const float*)Ap;
    const unsigned short* Ab = (const unsigned short*)Ap;

    for (int k0 = 0; k0 < K; k0 += 32) {
        __syncthreads();

        #pragma unroll
        for (int c = 0; c < 2; ++c) {
            const int inst = w * 2 + c;
            const int row  = inst * 16 + srow;
            const char* src = (const char*)Bt +
                (((size_t)(col0 + row) * K + k0) * 2 + skb);
            char* dst = (char*)Bs + inst * 1024;
            __builtin_amdgcn_global_load_lds(TO_GLB(src), TO_LDS(dst), 16, 0, 0);
        }
        if (!A_F32) {
            #pragma unroll
            for (int c = 0; c < 2; ++c) {
                const int inst = w * 2 + c;
                const int row  = inst * 16 + srow;
                const char* src = (const char*)Ab +
                    (((size_t)(row0 + row) * K + k0) * 2 + skb);
                char* dst = (char*)As + inst * 1024;
                __builtin_amdgcn_global_load_lds(TO_GLB(src), TO_LDS(dst), 16, 0, 0);
            }
        } else {
            #pragma unroll
            for (int c = 0; c < 2; ++c) {
                const int ci  = t + 256 * c;
                const int row = ci >> 2;
                const int ko  = (((ci & 3) ^ ((ci >> 3) & 3)) * 8);
                const float* s = Af + (size_t)(row0 + row) * K + k0 + ko;
                const float4 v0 = *(const float4*)s;
                const float4 v1 = *(const float4*)(s + 4);
                *(ushort8*)&As[ci * 8] = cvt8(v0, v1);
            }
        }
        __syncthreads();

        bf16x8 af[4], bfv[4];
        #pragma unroll
        for (int i = 0; i < 4; ++i)
            af[i]  = *(const bf16x8*)&As[(wr*64 + i*16 + lr) * 32 + (lk ^ rsw) * 8];
        #pragma unroll
        for (int j = 0; j < 4; ++j)
            bfv[j] = *(const bf16x8*)&Bs[(wc*64 + j*16 + lr) * 32 + (lk ^ rsw) * 8];
        #pragma unroll
        for (int i = 0; i < 4; ++i)
            #pragma unroll
            for (int j = 0; j < 4; ++j)
                acc[i][j] = __builtin_amdgcn_mfma_f32_16x16x32_bf16(
                    af[i], bfv[j], acc[i][j], 0, 0, 0);
    }

    if (dom) bias += (*dom) * biasStride;
    const int colb = col0 + wc * 64 + lr;
    const int rowb = row0 + wr * 64 + lk * 4;
    float bj[4];
    #pragma unroll
    for (int j = 0; j < 4; ++j) bj[j] = bias[colb + j * 16];

    #pragma unroll
    for (int i = 0; i < 4; ++i) {
        #pragma unroll
        for (int r = 0; r < 4; ++r) {
            const size_t row = rowb + i * 16 + r;
            #pragma unroll
            for (int j = 0; j < 4; ++j) {
                float x = acc[i][j][r] + bj[j];
                if (ACT == 1)      x = fmaxf(x, 0.f);
                else if (ACT == 2) x = (x > 0.f) ? x : LEAKS * x;
                const size_t idx = row * (size_t)ldc + cc0 + colb + j * 16;
                if (OUT_F32) ((float*)Cp)[idx] = x;
                else         ((unsigned short*)Cp)[idx] = f2bf(x);
            }
        }
    }
}

// ---------------------------------------------------------------------------
// gemm256 (v1, PROVEN): 256x256, BK=32, 8 waves, TRIPLE-buffered (96 KiB),
// distance-2 prefetch, counted vmcnt(4), T2 swizzle, setprio.
// ---------------------------------------------------------------------------
__global__ __launch_bounds__(512, 2) void gemm256(
    const unsigned short* __restrict__ A, const unsigned short* __restrict__ Bt,
    const float* __restrict__ bias, unsigned short* __restrict__ C,
    int M, int N, int K)
{
    __shared__ alignas(16) unsigned short lds[3][2][256 * 32];  // 96 KiB

    const int nbx = N >> 8;
    int wg = blockIdx.x;
    const int nwg = gridDim.x;
    if ((nwg & 7) == 0) {
        const int cpx = nwg >> 3;
        wg = (wg & 7) * cpx + (wg >> 3);
    }
    const int bx = wg % nbx, by = wg / nbx;
    const int row0 = by << 8, col0 = bx << 8;

    const int t  = threadIdx.x;
    const int w  = t >> 6, l = t & 63;
    const int wr = w >> 2, wc = w & 3;
    const int lr = l & 15, lk = l >> 4;
    const int rsw = (lr >> 1) & 3;
    const int srow = l >> 2;
    const int skel = ((l & 3) ^ ((l >> 3) & 3)) * 8;

    f32x4 acc[8][4];
    #pragma unroll
    for (int i = 0; i < 8; ++i)
        #pragma unroll
        for (int j = 0; j < 4; ++j)
            acc[i][j] = (f32x4)(0.f);

    const int NT = K >> 5;

    #define STAGE256(tile_)  do {                                            \
        const int k0_  = (tile_) << 5;                                       \
        const int buf_ = (tile_) % 3;                                        \
        _Pragma("unroll")                                                    \
        for (int s_ = 0; s_ < 2; ++s_) {                                     \
            const int c_   = w * 2 + s_;                                     \
            const int row_ = c_ * 16 + srow;                                 \
            __builtin_amdgcn_global_load_lds(                                \
                TO_GLB(A + (size_t)(row0 + row_) * K + k0_ + skel),          \
                TO_LDS((char*)&lds[buf_][0][0] + c_ * 1024), 16, 0, 0);      \
            __builtin_amdgcn_global_load_lds(                                \
                TO_GLB(Bt + (size_t)(col0 + row_) * K + k0_ + skel),         \
                TO_LDS((char*)&lds[buf_][1][0] + c_ * 1024), 16, 0, 0);      \
        }                                                                    \
    } while (0)

    STAGE256(0);
    if (NT > 1) {
        STAGE256(1);
        asm volatile("s_waitcnt vmcnt(4)" ::: "memory");
    } else {
        asm volatile("s_waitcnt vmcnt(0)" ::: "memory");
    }
    __builtin_amdgcn_sched_barrier(0);
    __builtin_amdgcn_s_barrier();
    __builtin_amdgcn_sched_barrier(0);

    for (int tt = 0; tt < NT; ++tt) {
        const int buf = tt % 3;
        if (tt + 2 < NT) STAGE256(tt + 2);
        __builtin_amdgcn_sched_barrier(0);

        bf16x8 af[8], bfv[4];
        #pragma unroll
        for (int i = 0; i < 8; ++i)
            af[i]  = *(const bf16x8*)&lds[buf][0][(wr*128 + i*16 + lr) * 32 + (lk ^ rsw) * 8];
        #pragma unroll
        for (int j = 0; j < 4; ++j)
            bfv[j] = *(const bf16x8*)&lds[buf][1][(wc*64 + j*16 + lr) * 32 + (lk ^ rsw) * 8];

        __builtin_amdgcn_s_setprio(1);
        #pragma unroll
        for (int j = 0; j < 4; ++j)
            #pragma unroll
            for (int i = 0; i < 8; ++i)
                acc[i][j] = __builtin_amdgcn_mfma_f32_16x16x32_bf16(
                    af[i], bfv[j], acc[i][j], 0, 0, 0);
        __builtin_amdgcn_s_setprio(0);

        if (tt + 1 < NT) {
            if (tt + 2 < NT) asm volatile("s_waitcnt vmcnt(4)" ::: "memory");
            else             asm volatile("s_waitcnt vmcnt(0)" ::: "memory");
            __builtin_amdgcn_sched_barrier(0);
            __builtin_amdgcn_s_barrier();
            __builtin_amdgcn_sched_barrier(0);
        }
    }
    #undef STAGE256

    const int colb = col0 + wc * 64 + lr;
    const int rowb = row0 + wr * 128 + lk * 4;
    float bj[4];
    #pragma unroll
    for (int j = 0; j < 4; ++j) bj[j] = bias[colb + j * 16];

    #pragma unroll
    for (int i = 0; i < 8; ++i) {
        #pragma unroll
        for (int r = 0; r < 4; ++r) {
            const size_t row = rowb + i * 16 + r;
            #pragma unroll
            for (int j = 0; j < 4; ++j) {
                float x = fmaxf(acc[i][j][r] + bj[j], 0.f);
                C[row * (size_t)N + colb + j * 16] = f2bf(x);
            }
        }
    }
}

// ---------------------------------------------------------------------------
// gemm256_8ph — faithful m201-style 8-phase schedule. BK=64, 2 K-tiles/iter,
// 8 waves (2Mx4N), LDS 128 KiB = [mat][dbuf][half][128x64] bf16.
// Wave bands interleave halves: wave wr covers A rows {wr*64..+63} in half0
// and {128+wr*64..+63} in half1 (qi selects half); wave wc covers B cols
// {wc*32..+31} half0 / {128+wc*32..+31} half1 (qj selects half).
// Per phase: {ds_reads (12/4/8/0, reg-reused) ; stage 1 half-tile (2 wave-
// uniform gload_lds) ; barrier ; lgkmcnt(0) ; setprio1 ; 16 MFMA ; setprio0 ;
// [vmcnt(4) at ph4/ph8 only] ; barrier}.
// RACE LEDGER (dbuf0=K-tile 2m phases1-4, dbuf1=2m+1 phases5-8):
//  deadness: b0.A0 after ph2, b0.B0 ph3, b0.A1/B1 ph4, b1.A0 ph6, b1.B0 ph7,
//            b1.A1/B1 ph8.
//  stages:  ph1:(2m+1).A1  ph2:(2m+1).B1  ph3:(2m+2).A0  ph4:(2m+2).B0
//           ph5:(2m+2).A1  ph6:(2m+2).B1  ph7:(2m+3).A0  ph8:(2m+3).B0
//  each stage targets a region dead >=1 trailing barrier earlier (WAR ok).
//  waits: vmcnt(4) at ph4/ph8 retires all but the 2 youngest half-tiles;
//  every half-tile is retired before its first read (RAW ok). Last iter:
//  ph4 uses vmcnt(0) (ph3/4 stages absent -> ph1/2 stages must land).
// Accumulation order per acc element: k ascending (ks0,ks1; tiles asc) ==
// v1's order -> bit-identical output (absmax canary 0.0005531311).
// ---------------------------------------------------------------------------
__global__ __launch_bounds__(512, 2) void gemm256_8ph(
    const unsigned short* __restrict__ A, const unsigned short* __restrict__ Bt,
    const float* __restrict__ bias, unsigned short* __restrict__ C,
    int M, int N, int K)
{
    __shared__ alignas(16) unsigned short lds[2][2][2][128 * 64];  // 128 KiB

    const int nbx = N >> 8;
    int wg = blockIdx.x;
    const int nwg = gridDim.x;
    if ((nwg & 7) == 0) { const int cpx = nwg >> 3; wg = (wg & 7) * cpx + (wg >> 3); }
    const int bx = wg % nbx, by = wg / nbx;
    const int row0 = by << 8, col0 = bx << 8;

    const int t = threadIdx.x;
    const int w = t >> 6, l = t & 63;
    const int wr = w >> 2, wc = w & 3;
    const int lr = l & 15, lk = l >> 4;

    f32x4 acc[8][4];
    #pragma unroll
    for (int i = 0; i < 8; ++i)
        #pragma unroll
        for (int j = 0; j < 4; ++j) acc[i][j] = (f32x4)(0.f);

    const int NT = K >> 6;     // K-tiles of 64 (even; >=2)
    const int NI = NT >> 1;

    // stage one half-tile: 2 loads, wave-uniform LDS dest (chunk c_=s_*8+w),
    // pre-swizzled global source (granule g ^ (row&7), involution).
    #define STG(mat_, kt_, h_) do {                                              \
        const unsigned short* gb_ = (mat_) ? Bt : A;                              \
        const int gr0_ = (mat_) ? col0 : row0;                                    \
        _Pragma("unroll")                                                         \
        for (int s_ = 0; s_ < 2; ++s_) {                                          \
            const int c_   = s_ * 8 + w;                                          \
            const int row_ = c_ * 8 + (l >> 3);                                   \
            const int g_   = (l & 7) ^ (row_ & 7);                                \
            __builtin_amdgcn_global_load_lds(                                     \
                TO_GLB(gb_ + (size_t)(gr0_ + (h_) * 128 + row_) * K + (kt_) * 64 + g_ * 8), \
                TO_LDS((char*)&lds[mat_][(kt_) & 1][h_][0] + c_ * 1024), 16, 0, 0);\
        } } while (0)

    #define RD_A(dst_, buf_, qi_) do {                                            \
        _Pragma("unroll")                                                         \
        for (int ks_ = 0; ks_ < 2; ++ks_)                                         \
        _Pragma("unroll")                                                         \
        for (int ii_ = 0; ii_ < 4; ++ii_) {                                       \
            const int rh_ = wr * 64 + ii_ * 16 + lr;                              \
            dst_[ks_][ii_] = *(const bf16x8*)                                     \
                &lds[0][buf_][qi_][rh_ * 64 + (((ks_ * 4 + lk) ^ (rh_ & 7)) << 3)]; \
        } } while (0)

    #define RD_B(dst_, buf_, qj_) do {                                            \
        _Pragma("unroll")                                                         \
        for (int ks_ = 0; ks_ < 2; ++ks_)                                         \
        _Pragma("unroll")                                                         \
        for (int jj_ = 0; jj_ < 2; ++jj_) {                                       \
            const int rh_ = wc * 32 + jj_ * 16 + lr;                              \
            dst_[ks_][jj_] = *(const bf16x8*)                                     \
                &lds[1][buf_][qj_][rh_ * 64 + (((ks_ * 4 + lk) ^ (rh_ & 7)) << 3)]; \
        } } while (0)

    #define SYNC_IN() do {                                                        \
        __builtin_amdgcn_sched_barrier(0);                                        \
        __builtin_amdgcn_s_barrier();                                             \
        asm volatile("s_waitcnt lgkmcnt(0)" ::: "memory");                        \
        __builtin_amdgcn_sched_barrier(0); } while (0)

    #define MFMA16(aa_, bb_, qi_, qj_) do {                                       \
        __builtin_amdgcn_s_setprio(1);                                            \
        _Pragma("unroll")                                                         \
        for (int ks_ = 0; ks_ < 2; ++ks_)                                         \
        _Pragma("unroll")                                                         \
        for (int jj_ = 0; jj_ < 2; ++jj_)                                         \
        _Pragma("unroll")                                                         \
        for (int ii_ = 0; ii_ < 4; ++ii_)                                         \
            acc[(qi_)*4+ii_][(qj_)*2+jj_] = __builtin_amdgcn_mfma_f32_16x16x32_bf16( \
                aa_[ks_][ii_], bb_[ks_][jj_], acc[(qi_)*4+ii_][(qj_)*2+jj_], 0, 0, 0); \
        __builtin_amdgcn_s_setprio(0); } while (0)

    #define PH_END() do {                                                         \
        __builtin_amdgcn_sched_barrier(0);                                        \
        __builtin_amdgcn_s_barrier(); } while (0)

    // prologue: t0 full + t1.A0/B0 (12 loads); allow t1's 4 outstanding
    STG(0, 0, 0); STG(0, 0, 1); STG(1, 0, 0); STG(1, 0, 1);
    STG(0, 1, 0); STG(1, 1, 0);
    asm volatile("s_waitcnt vmcnt(4)" ::: "memory");
    __builtin_amdgcn_sched_barrier(0);
    __builtin_amdgcn_s_barrier();
    __builtin_amdgcn_sched_barrier(0);

    for (int m = 0; m < NI; ++m) {
        const int t1 = 2 * m + 1, u0 = 2 * m + 2, u1 = 2 * m + 3;
        const bool last = (m == NI - 1);
        bf16x8 a_[2][4], b0_[2][2], b1_[2][2];

        // ph1: t0 q(0,0)
        RD_A(a_, 0, 0); RD_B(b0_, 0, 0);
        STG(0, t1, 1);
        SYNC_IN(); MFMA16(a_, b0_, 0, 0); PH_END();
        // ph2: t0 q(0,1)
        RD_B(b1_, 0, 1);
        STG(1, t1, 1);
        SYNC_IN(); MFMA16(a_, b1_, 0, 1); PH_END();
        // ph3: t0 q(1,0)
        RD_A(a_, 0, 1);
        if (u0 < NT) STG(0, u0, 0);
        SYNC_IN(); MFMA16(a_, b0_, 1, 0); PH_END();
        // ph4: t0 q(1,1) + K-tile wait
        if (u0 < NT) STG(1, u0, 0);
        SYNC_IN(); MFMA16(a_, b1_, 1, 1);
        if (last) asm volatile("s_waitcnt vmcnt(0)" ::: "memory");
        else      asm volatile("s_waitcnt vmcnt(4)" ::: "memory");
        PH_END();
        // ph5: t1 q(0,0)
        RD_A(a_, 1, 0); RD_B(b0_, 1, 0);
        if (u0 < NT) STG(0, u0, 1);
        SYNC_IN(); MFMA16(a_, b0_, 0, 0); PH_END();
        // ph6: t1 q(0,1)
        RD_B(b1_, 1, 1);
        if (u0 < NT) STG(1, u0, 1);
        SYNC_IN(); MFMA16(a_, b1_, 0, 1); PH_END();
        // ph7: t1 q(1,0)
        RD_A(a_, 1, 1);
        if (u1 < NT) STG(0, u1, 0);
        SYNC_IN(); MFMA16(a_, b0_, 1, 0); PH_END();
        // ph8: t1 q(1,1) + K-tile wait
        if (u1 < NT) STG(1, u1, 0);
        SYNC_IN(); MFMA16(a_, b1_, 1, 1);
        if (!last) asm volatile("s_waitcnt vmcnt(4)" ::: "memory");
        PH_END();
    }
    #undef STG
    #undef RD_A
    #undef RD_B
    #undef SYNC_IN
    #undef MFMA16
    #undef PH_END

    // epilogue: row = row0 + qi*128 + wr*64 + ii*16 + lk*4 + r
    //           col = col0 + qj*128 + wc*32 + jj*16 + lr
    const int colb = col0 + wc * 32 + lr;
    const int rowb = row0 + wr * 64 + lk * 4;
    float bj[4];
    #pragma unroll
    for (int j = 0; j < 4; ++j)
        bj[j] = bias[colb + (j >> 1) * 128 + (j & 1) * 16];

    #pragma unroll
    for (int i = 0; i < 8; ++i) {
        const int gri = rowb + (i >> 2) * 128 + (i & 3) * 16;
        #pragma unroll
        for (int r = 0; r < 4; ++r) {
            const size_t row = gri + r;
            #pragma unroll
            for (int j = 0; j < 4; ++j) {
                float x = fmaxf(acc[i][j][r] + bj[j], 0.f);
                C[row * (size_t)N + colb + (j >> 1) * 128 + (j & 1) * 16] = f2bf(x);
            }
        }
    }
}

// ---------------------------------------------------------------------------
// gemm128: proven pipeline at 128x128 / 4 waves / 48 KiB. Narrow-N GEMMs 6/7.
// ---------------------------------------------------------------------------
template<bool OUT_F32, int ACT>
__global__ __launch_bounds__(256, 2) void gemm128(
    const unsigned short* __restrict__ A, const unsigned short* __restrict__ Bt,
    const float* __restrict__ bias, void* __restrict__ Cp,
    int M, int N, int K, int ldc, int cc0,
    const int* __restrict__ dom, int biasStride)
{
    __shared__ alignas(16) unsigned short lds[3][2][128 * 32];  // 48 KiB

    const int nbx = N >> 7;
    int wg = blockIdx.x;
    const int nwg = gridDim.x;
    if ((nwg & 7) == 0) {
        const int cpx = nwg >> 3;
        wg = (wg & 7) * cpx + (wg >> 3);
    }
    const int bx = wg % nbx, by = wg / nbx;
    const int row0 = by << 7, col0 = bx << 7;

    const int t  = threadIdx.x;
    const int w  = t >> 6, l = t & 63;
    const int wr = w >> 1, wc = w & 1;
    const int lr = l & 15, lk = l >> 4;
    const int rsw = (lr >> 1) & 3;
    const int srow = l >> 2;
    const int skel = ((l & 3) ^ ((l >> 3) & 3)) * 8;

    f32x4 acc[4][4];
    #pragma unroll
    for (int i = 0; i < 4; ++i)
        #pragma unroll
        for (int j = 0; j < 4; ++j)
            acc[i][j] = (f32x4)(0.f);

    const int NT = K >> 5;

    #define STAGE128(tile_)  do {                                            \
        const int k0_  = (tile_) << 5;                                       \
        const int buf_ = (tile_) % 3;                                        \
        _Pragma("unroll")                                                    \
        for (int s_ = 0; s_ < 2; ++s_) {                                     \
            const int c_   = w * 2 + s_;                                     \
            const int row_ = c_ * 16 + srow;                                 \
            __builtin_amdgcn_global_load_lds(                                \
                TO_GLB(A + (size_t)(row0 + row_) * K + k0_ + skel),          \
                TO_LDS((char*)&lds[buf_][0][0] + c_ * 1024), 16, 0, 0);      \
            __builtin_amdgcn_global_load_lds(                                \
                TO_GLB(Bt + (size_t)(col0 + row_) * K + k0_ + skel),         \
                TO_LDS((char*)&lds[buf_][1][0] + c_ * 1024), 16, 0, 0);      \
        }                                                                    \
    } while (0)

    STAGE128(0);
    if (NT > 1) {
        STAGE128(1);
        asm volatile("s_waitcnt vmcnt(4)" ::: "memory");
    } else {
        asm volatile("s_waitcnt vmcnt(0)" ::: "memory");
    }
    __builtin_amdgcn_sched_barrier(0);
    __builtin_amdgcn_s_barrier();
    __builtin_amdgcn_sched_barrier(0);

    for (int tt = 0; tt < NT; ++tt) {
        const int buf = tt % 3;
        if (tt + 2 < NT) STAGE128(tt + 2);
        __builtin_amdgcn_sched_barrier(0);

        bf16x8 af[4], bfv[4];
        #pragma unroll
        for (int i = 0; i < 4; ++i)
            af[i]  = *(const bf16x8*)&lds[buf][0][(wr*64 + i*16 + lr) * 32 + (lk ^ rsw) * 8];
        #pragma unroll
        for (int j = 0; j < 4; ++j)
            bfv[j] = *(const bf16x8*)&lds[buf][1][(wc*64 + j*16 + lr) * 32 + (lk ^ rsw) * 8];

        #pragma unroll
        for (int j = 0; j < 4; ++j)
            #pragma unroll
            for (int i = 0; i < 4; ++i)
                acc[i][j] = __builtin_amdgcn_mfma_f32_16x16x32_bf16(
                    af[i], bfv[j], acc[i][j], 0, 0, 0);

        if (tt + 1 < NT) {
            if (tt + 2 < NT) asm volatile("s_waitcnt vmcnt(4)" ::: "memory");
            else             asm volatile("s_waitcnt vmcnt(0)" ::: "memory");
            __builtin_amdgcn_sched_barrier(0);
            __builtin_amdgcn_s_barrier();
            __builtin_amdgcn_sched_barrier(0);
        }
    }
    #undef STAGE128

    if (dom) bias += (*dom) * biasStride;
    const int colb = col0 + wc * 64 + lr;
    const int rowb = row0 + wr * 64 + lk * 4;
    float bj[4];
    #pragma unroll
    for (int j = 0; j < 4; ++j) bj[j] = bias[colb + j * 16];

    #pragma unroll
    for (int i = 0; i < 4; ++i) {
        #pragma unroll
        for (int r = 0; r < 4; ++r) {
            const size_t row = rowb + i * 16 + r;
            #pragma unroll
            for (int j = 0; j < 4; ++j) {
                float x = acc[i][j][r] + bj[j];
                if (ACT == 1)      x = fmaxf(x, 0.f);
                else if (ACT == 2) x = (x > 0.f) ? x : LEAKS * x;
                const size_t idx = row * (size_t)ldc + cc0 + colb + j * 16;
                if (OUT_F32) ((float*)Cp)[idx] = x;
                else         ((unsigned short*)Cp)[idx] = f2bf(x);
            }
        }
    }
}

// ---------------------------------------------------------------------------
// BatchNorm stats + heads — unchanged (proven).
// ---------------------------------------------------------------------------
__global__ __launch_bounds__(256) void bn_stats_a(
    const float* __restrict__ X, float* __restrict__ psum, float* __restrict__ pss)
{
    const int c  = blockIdx.x * 256 + threadIdx.x;
    const int rb = blockIdx.y;
    float s = 0.f, ss = 0.f;
    const int r0 = rb * 256;
    for (int r = r0; r < r0 + 256; ++r) {
        float v = X[(size_t)r * XW + c];
        s += v; ss = fmaf(v, v, ss);
    }
    psum[rb * XW + c] = s;
    pss [rb * XW + c] = ss;
}

__global__ __launch_bounds__(256) void bn_stats_b(
    const float* __restrict__ psum, const float* __restrict__ pss,
    const float* __restrict__ gamma, const float* __restrict__ beta,
    float* __restrict__ scale, float* __restrict__ shift)
{
    const int c = blockIdx.x * 256 + threadIdx.x;
    float s = 0.f, ss = 0.f;
    for (int rb = 0; rb < 32; ++rb) { s += psum[rb * XW + c]; ss += pss[rb * XW + c]; }
    const float inv = 1.f / (float)BQ;
    const float mean = s * inv;
    const float var  = ss * inv - mean * mean;
    const float sc = gamma[c] * rsqrtf(var + BN_EPS);
    scale[c] = sc;
    shift[c] = beta[c] - mean * sc;
}

__global__ __launch_bounds__(256) void head_kernel(
    const float* __restrict__ X, const float* __restrict__ scale,
    const float* __restrict__ shift, const int* __restrict__ tt,
    const float* __restrict__ Wh1, const float* __restrict__ bh1,
    const float* __restrict__ Wh2, const float* __restrict__ bh2,
    const float* __restrict__ Wh3, const float* __restrict__ bh3,
    float* __restrict__ out)
{
    __shared__ float xs[4][XW];
    __shared__ float y1[4][H1N];
    __shared__ float y2[4][H2N + 2];

    const int t = threadIdx.x;
    const int w = t >> 6;
    const int l = t & 63;
    const int s = blockIdx.x * 4 + w;
    const int d = tt[s];

    #pragma unroll 4
    for (int i = 0; i < XW / 64; ++i) {
        const int c = i * 64 + l;
        xs[w][c] = fmaf(X[(size_t)s * XW + c], scale[c], shift[c]);
    }
    __syncthreads();

    if (l < H1N) {
        const float* W1 = Wh1 + (size_t)d * XW * H1N;
        float acc = bh1[d * H1N + l];
        #pragma unroll 8
        for (int c = 0; c < XW; ++c)
            acc = fmaf(xs[w][c], W1[c * H1N + l], acc);
        y1[w][l] = fmaxf(acc, 0.f);
    }
    __syncthreads();

    if (l < H2N) {
        const float* W2 = Wh2 + (size_t)d * H1N * H2N;
        float acc = bh2[d * H2N + l];
        #pragma unroll
        for (int c = 0; c < H1N; ++c)
            acc = fmaf(y1[w][c], W2[c * H2N + l], acc);
        y2[w][l] = fmaxf(acc, 0.f);
    }
    __syncthreads();

    if (l < NWAY) {
        const float* W3 = Wh3 + (size_t)d * H2N * NWAY;
        float acc = bh3[d * NWAY + l];
        #pragma unroll
        for (int c = 0; c < H2N; ++c)
            acc = fmaf(y2[w][c], W3[c * NWAY + l], acc);
        out[(size_t)s * NWAY + l] = acc;
    }
}

// ---------------------------------------------------------------------------
extern "C" void kernel_launch(void* const* d_in, const int* in_sizes, int n_in,
                              void* d_out, int out_size, void* d_ws, size_t ws_size,
                              hipStream_t stream)
{
    const float* x_s   = (const float*)d_in[0];
    const float* x_p   = (const float*)d_in[1];
    const int*   tt    = (const int*)  d_in[2];
    const int*   dom   = (const int*)  d_in[3];
    const float* W_in  = (const float*)d_in[4];
    const float* b_in  = (const float*)d_in[5];
    const float* W_hid = (const float*)d_in[6];
    const float* b_hid = (const float*)d_in[7];
    const float* W_out = (const float*)d_in[8];
    const float* b_out = (const float*)d_in[9];
    const float* Wp    = (const float*)d_in[10];
    const float* bp    = (const float*)d_in[11];
    const float* gamma = (const float*)d_in[12];
    const float* beta  = (const float*)d_in[13];
    const float* Wh1   = (const float*)d_in[14];
    const float* bh1   = (const float*)d_in[15];
    const float* Wh2   = (const float*)d_in[16];
    const float* bh2   = (const float*)d_in[17];
    const float* Wh3   = (const float*)d_in[18];
    const float* bh3   = (const float*)d_in[19];
    float* out = (float*)d_out;

    const dim3 blk(256);
    char* w = (char*)d_ws;

    const size_t FAST_NEED = 470810624ull;

    if (ws_size >= FAST_NEED) {
        unsigned short* xb    = (unsigned short*)w;                    // 192M
        unsigned short* WinT  = (unsigned short*)(w + 201326592);      // 96M region
        unsigned short* WoutT = (unsigned short*)(w + 201326592);      //  8M
        unsigned short* WpT   = (unsigned short*)(w + 209715200);      // 24M
        unsigned short* actA  = (unsigned short*)(w + 301989888);      // 64M
        unsigned short* actB  = (unsigned short*)(w + 369098752);      // 64M
        float*          X     = (float*)(w + 369098752);               // aliases actB
        unsigned short* WhidT = (unsigned short*)(w + 436207616);      // 32M
        float*          psum  = (float*)(w + 469762048);
        float*          pss   = psum + 32 * XW;
        float*          scale = pss  + 32 * XW;
        float*          shift = scale + XW;

        cvt_bf16<<<dim3(2048), blk, 0, stream>>>(x_s, xb, (long long)BQ * FIN / 8);
        transpose_cvt<<<dim3(SUN/64,  FIN/64), blk, 0, stream>>>(W_in,  WinT,  FIN, SUN,  nullptr);
        transpose_cvt<<<dim3(SUN/64,  SUN/64), blk, 0, stream>>>(W_hid, WhidT, SUN, SUN,  nullptr);

        // GEMM1 — proven v1
        gemm256<<<dim3(512), dim3(512), 0, stream>>>(xb, WinT, b_in, actA, BQ, SUN, FIN);

        transpose_cvt<<<dim3(HIDN/64, SUN/64), blk, 0, stream>>>(W_out, WoutT, SUN, HIDN, nullptr);
        transpose_cvt<<<dim3(HIDN/64, FIN/64), blk, 0, stream>>>(Wp,    WpT,   FIN, HIDN, dom);
        cvt_bf16<<<dim3(2048), blk, 0, stream>>>(x_p, xb, (long long)BQ * FIN / 8);

        // hidden layers A/B: 8ph, v1, 8ph, v1
        gemm256_8ph<<<dim3(512), dim3(512), 0, stream>>>(actA, WhidT, b_hid, actB, BQ, SUN, SUN);
        gemm256    <<<dim3(512), dim3(512), 0, stream>>>(actB, WhidT, b_hid, actA, BQ, SUN, SUN);
        gemm256_8ph<<<dim3(512), dim3(512), 0, stream>>>(actA, WhidT, b_hid, actB, BQ, SUN, SUN);
        gemm256    <<<dim3(512), dim3(512), 0, stream>>>(actB, WhidT, b_hid, actA, BQ, SUN, SUN);

        gemm128<true,1><<<dim3(512), blk, 0, stream>>>(
            actA, WoutT, b_out, X, BQ, HIDN, SUN, XW, 0, nullptr, 0);
        gemm128<true,2><<<dim3(512), blk, 0, stream>>>(
            xb, WpT, bp, X, BQ, HIDN, FIN, XW, HIDN, dom, HIDN);

        bn_stats_a<<<dim3(XW/256, 32), blk, 0, stream>>>(X, psum, pss);
        bn_stats_b<<<dim3(XW/256),     blk, 0, stream>>>(psum, pss, gamma, beta, scale, shift);
        head_kernel<<<dim3(BQ/4), blk, 0, stream>>>(X, scale, shift, tt,
                                                    Wh1, bh1, Wh2, bh2, Wh3, bh3, out);
        return;
    }

    // ---------------- fallback: 256 MiB path ----------------
    unsigned short* actA  = (unsigned short*)w;
    unsigned short* actB  = (unsigned short*)(w + 67108864);
    float*          X     = (float*)(w + 67108864);
    unsigned short* WinT  = (unsigned short*)(w + 134217728);
    unsigned short* WoutT = (unsigned short*)(w + 134217728);
    unsigned short* WpT   = (unsigned short*)(w + 142606336);
    float*          psum  = (float*)(w + 167772160);
    float*          pss   = psum + 32 * XW;
    float*          scale = pss  + 32 * XW;
    float*          shift = scale + XW;
    unsigned short* WhidT = (unsigned short*)(w + 234881024);

    transpose_cvt<<<dim3(SUN/64,  FIN/64), blk, 0, stream>>>(W_in,  WinT,  FIN, SUN,  nullptr);
    transpose_cvt<<<dim3(SUN/64,  SUN/64), blk, 0, stream>>>(W_hid, WhidT, SUN, SUN,  nullptr);

    gemm_mfma<true,false,1><<<dim3(2048), blk, 0, stream>>>(
        x_s, WinT, b_in, actA, BQ, SUN, FIN, SUN, 0, nullptr, 0);

    transpose_cvt<<<dim3(HIDN/64, SUN/64), blk, 0, stream>>>(W_out, WoutT, SUN, HIDN, nullptr);
    transpose_cvt<<<dim3(HIDN/64, FIN/64), blk, 0, stream>>>(Wp,    WpT,   FIN, HIDN, dom);

    gemm256<<<dim3(512), dim3(512), 0, stream>>>(actA, WhidT, b_hid, actB, BQ, SUN, SUN);
    gemm256<<<dim3(512), dim3(512), 0, stream>>>(actB, WhidT, b_hid, actA, BQ, SUN, SUN);
    gemm256<<<dim3(512), dim3(512), 0, stream>>>(actA, WhidT, b_hid, actB, BQ, SUN, SUN);
    gemm256<<<dim3(512), dim3(512), 0, stream>>>(actB, WhidT, b_hid, actA, BQ, SUN, SUN);

    gemm128<true,1><<<dim3(512), blk, 0, stream>>>(
        actA, WoutT, b_out, X, BQ, HIDN, SUN, XW, 0, nullptr, 0);
    gemm_mfma<true,true,2><<<dim3(512), blk, 0, stream>>>(
        x_p, WpT, bp, X, BQ, HIDN, FIN, XW, HIDN, dom, HIDN);

    bn_stats_a<<<dim3(XW/256, 32), blk, 0, stream>>>(X, psum, pss);
    bn_stats_b<<<dim3(XW/256),     blk, 0, stream>>>(psum, pss, gamma, beta, scale, shift);
    head_kernel<<<dim3(BQ/4), blk, 0, stream>>>(X, scale, shift, tt,
                                                Wh1, bh1, Wh2, bh2, Wh3, bh3, out);
}

// Round 12
// 2387.820 us; speedup vs baseline: 1.2808x; 1.0414x over previous
//
#include <hip/hip_runtime.h>
#include <hip/hip_bf16.h>

// Problem constants
#define BQ    8192
#define FIN   12288
#define SUN   4096
#define HIDN  1024
#define XW    2048
#define H1N   28
#define H2N   14
#define NWAY  5
#define BN_EPS 1e-5f
#define LEAKS 0.001f

typedef __bf16 bf16x8 __attribute__((ext_vector_type(8)));
typedef float  f32x4  __attribute__((ext_vector_type(4)));
typedef unsigned short ushort8 __attribute__((ext_vector_type(8)));

__device__ __forceinline__ unsigned short f2bf(float f) {
    unsigned u = __float_as_uint(f);
    unsigned r = u + 0x7fffu + ((u >> 16) & 1u);   // RNE
    return (unsigned short)(r >> 16);
}

__device__ __forceinline__ ushort8 cvt8(const float4 a, const float4 b) {
    union { __bf16 h[8]; ushort8 u; } r;
    r.h[0] = (__bf16)a.x; r.h[1] = (__bf16)a.y;
    r.h[2] = (__bf16)a.z; r.h[3] = (__bf16)a.w;
    r.h[4] = (__bf16)b.x; r.h[5] = (__bf16)b.y;
    r.h[6] = (__bf16)b.z; r.h[7] = (__bf16)b.w;
    return r.u;
}

#define TO_LDS(p) ((__attribute__((address_space(3))) void*)(p))
#define TO_GLB(p) ((const __attribute__((address_space(1))) void*)(p))

// ---------------------------------------------------------------------------
__global__ __launch_bounds__(256) void cvt_bf16(
    const float* __restrict__ in, unsigned short* __restrict__ out, long long n8)
{
    const long long idx = (long long)blockIdx.x * 256 + threadIdx.x;
    const long long stride = (long long)gridDim.x * 256;
    for (long long i = idx; i < n8; i += stride) {
        const float4 a = ((const float4*)in)[2 * i];
        const float4 b = ((const float4*)in)[2 * i + 1];
        ((ushort8*)out)[i] = cvt8(a, b);
    }
}

// ---------------------------------------------------------------------------
__global__ __launch_bounds__(256) void transpose_cvt(
    const float* __restrict__ in, unsigned short* __restrict__ out,
    int R, int Cc, const int* __restrict__ dom)
{
    if (dom) in += (size_t)(*dom) * (size_t)R * (size_t)Cc;
    __shared__ float tile[64][65];
    const int t  = threadIdx.x;
    const int tr = t >> 4;
    const int tc = t & 15;
    const int c0 = blockIdx.x * 64;
    const int r0 = blockIdx.y * 64;

    #pragma unroll
    for (int q = 0; q < 4; ++q) {
        const int r = r0 + tr + q * 16;
        const float4 v = *(const float4*)&in[(size_t)r * Cc + c0 + tc * 4];
        tile[tc*4+0][tr + q*16] = v.x;
        tile[tc*4+1][tr + q*16] = v.y;
        tile[tc*4+2][tr + q*16] = v.z;
        tile[tc*4+3][tr + q*16] = v.w;
    }
    __syncthreads();
    #pragma unroll
    for (int q = 0; q < 4; ++q) {
        const int c = c0 + tr + q * 16;
        ushort4 o;
        o.x = f2bf(tile[tr + q*16][tc*4+0]);
        o.y = f2bf(tile[tr + q*16][tc*4+1]);
        o.z = f2bf(tile[tr + q*16][tc*4+2]);
        o.w = f2bf(tile[tr + q*16][tc*4+3]);
        *(ushort4*)&out[(size_t)c * R + r0 + tc * 4] = o;
    }
}

// ---------------------------------------------------------------------------
// m97-structure bf16 MFMA GEMM (128x128, 2-barrier) — fp32-A fallback only.
// ---------------------------------------------------------------------------
template<bool A_F32, bool OUT_F32, int ACT>
__global__ __launch_bounds__(256) void gemm_mfma(
    const void* __restrict__ Ap, const unsigned short* __restrict__ Bt,
    const float* __restrict__ bias, void* __restrict__ Cp,
    int M, int N, int K, int ldc, int cc0,
    const int* __restrict__ dom, int biasStride)
{
    __shared__ alignas(16) unsigned short As[128 * 32];
    __shared__ alignas(16) unsigned short Bs[128 * 32];

    const int nbx = N >> 7;
    int wg = blockIdx.x;
    const int nwg = gridDim.x;
    if ((nwg & 7) == 0) {
        const int cpx = nwg >> 3;
        wg = (wg & 7) * cpx + (wg >> 3);
    }
    const int bx = wg % nbx, by = wg / nbx;
    const int row0 = by << 7, col0 = bx << 7;

    const int t  = threadIdx.x;
    const int w  = t >> 6;
    const int l  = t & 63;
    const int wr = w >> 1, wc = w & 1;
    const int lr = l & 15, lk = l >> 4;
    const int rsw = (lr >> 1) & 3;

    f32x4 acc[4][4];
    #pragma unroll
    for (int i = 0; i < 4; ++i)
        #pragma unroll
        for (int j = 0; j < 4; ++j)
            acc[i][j] = (f32x4)(0.f);

    const int srow = l >> 2;
    const int skb  = (((l & 3) ^ ((l >> 3) & 3)) * 16);
    const float* Af = (const float*)Ap;
    const unsigned short* Ab = (const unsigned short*)Ap;

    for (int k0 = 0; k0 < K; k0 += 32) {
        __syncthreads();

        #pragma unroll
        for (int c = 0; c < 2; ++c) {
            const int inst = w * 2 + c;
            const int row  = inst * 16 + srow;
            const char* src = (const char*)Bt +
                (((size_t)(col0 + row) * K + k0) * 2 + skb);
            char* dst = (char*)Bs + inst * 1024;
            __builtin_amdgcn_global_load_lds(TO_GLB(src), TO_LDS(dst), 16, 0, 0);
        }
        if (!A_F32) {
            #pragma unroll
            for (int c = 0; c < 2; ++c) {
                const int inst = w * 2 + c;
                const int row  = inst * 16 + srow;
                const char* src = (const char*)Ab +
                    (((size_t)(row0 + row) * K + k0) * 2 + skb);
                char* dst = (char*)As + inst * 1024;
                __builtin_amdgcn_global_load_lds(TO_GLB(src), TO_LDS(dst), 16, 0, 0);
            }
        } else {
            #pragma unroll
            for (int c = 0; c < 2; ++c) {
                const int ci  = t + 256 * c;
                const int row = ci >> 2;
                const int ko  = (((ci & 3) ^ ((ci >> 3) & 3)) * 8);
                const float* s = Af + (size_t)(row0 + row) * K + k0 + ko;
                const float4 v0 = *(const float4*)s;
                const float4 v1 = *(const float4*)(s + 4);
                *(ushort8*)&As[ci * 8] = cvt8(v0, v1);
            }
        }
        __syncthreads();

        bf16x8 af[4], bfv[4];
        #pragma unroll
        for (int i = 0; i < 4; ++i)
            af[i]  = *(const bf16x8*)&As[(wr*64 + i*16 + lr) * 32 + (lk ^ rsw) * 8];
        #pragma unroll
        for (int j = 0; j < 4; ++j)
            bfv[j] = *(const bf16x8*)&Bs[(wc*64 + j*16 + lr) * 32 + (lk ^ rsw) * 8];
        #pragma unroll
        for (int i = 0; i < 4; ++i)
            #pragma unroll
            for (int j = 0; j < 4; ++j)
                acc[i][j] = __builtin_amdgcn_mfma_f32_16x16x32_bf16(
                    af[i], bfv[j], acc[i][j], 0, 0, 0);
    }

    if (dom) bias += (*dom) * biasStride;
    const int colb = col0 + wc * 64 + lr;
    const int rowb = row0 + wr * 64 + lk * 4;
    float bj[4];
    #pragma unroll
    for (int j = 0; j < 4; ++j) bj[j] = bias[colb + j * 16];

    #pragma unroll
    for (int i = 0; i < 4; ++i) {
        #pragma unroll
        for (int r = 0; r < 4; ++r) {
            const size_t row = rowb + i * 16 + r;
            #pragma unroll
            for (int j = 0; j < 4; ++j) {
                float x = acc[i][j][r] + bj[j];
                if (ACT == 1)      x = fmaxf(x, 0.f);
                else if (ACT == 2) x = (x > 0.f) ? x : LEAKS * x;
                const size_t idx = row * (size_t)ldc + cc0 + colb + j * 16;
                if (OUT_F32) ((float*)Cp)[idx] = x;
                else         ((unsigned short*)Cp)[idx] = f2bf(x);
            }
        }
    }
}

// ---------------------------------------------------------------------------
// gemm256 (v1): 256x256, BK=32, triple-buffered, counted vmcnt(4), T2, setprio.
// Kept for fallback path only.
// ---------------------------------------------------------------------------
__global__ __launch_bounds__(512, 2) void gemm256(
    const unsigned short* __restrict__ A, const unsigned short* __restrict__ Bt,
    const float* __restrict__ bias, unsigned short* __restrict__ C,
    int M, int N, int K)
{
    __shared__ alignas(16) unsigned short lds[3][2][256 * 32];  // 96 KiB

    const int nbx = N >> 8;
    int wg = blockIdx.x;
    const int nwg = gridDim.x;
    if ((nwg & 7) == 0) {
        const int cpx = nwg >> 3;
        wg = (wg & 7) * cpx + (wg >> 3);
    }
    const int bx = wg % nbx, by = wg / nbx;
    const int row0 = by << 8, col0 = bx << 8;

    const int t  = threadIdx.x;
    const int w  = t >> 6, l = t & 63;
    const int wr = w >> 2, wc = w & 3;
    const int lr = l & 15, lk = l >> 4;
    const int rsw = (lr >> 1) & 3;
    const int srow = l >> 2;
    const int skel = ((l & 3) ^ ((l >> 3) & 3)) * 8;

    f32x4 acc[8][4];
    #pragma unroll
    for (int i = 0; i < 8; ++i)
        #pragma unroll
        for (int j = 0; j < 4; ++j)
            acc[i][j] = (f32x4)(0.f);

    const int NT = K >> 5;

    #define STAGE256(tile_)  do {                                            \
        const int k0_  = (tile_) << 5;                                       \
        const int buf_ = (tile_) % 3;                                        \
        _Pragma("unroll")                                                    \
        for (int s_ = 0; s_ < 2; ++s_) {                                     \
            const int c_   = w * 2 + s_;                                     \
            const int row_ = c_ * 16 + srow;                                 \
            __builtin_amdgcn_global_load_lds(                                \
                TO_GLB(A + (size_t)(row0 + row_) * K + k0_ + skel),          \
                TO_LDS((char*)&lds[buf_][0][0] + c_ * 1024), 16, 0, 0);      \
            __builtin_amdgcn_global_load_lds(                                \
                TO_GLB(Bt + (size_t)(col0 + row_) * K + k0_ + skel),         \
                TO_LDS((char*)&lds[buf_][1][0] + c_ * 1024), 16, 0, 0);      \
        }                                                                    \
    } while (0)

    STAGE256(0);
    if (NT > 1) {
        STAGE256(1);
        asm volatile("s_waitcnt vmcnt(4)" ::: "memory");
    } else {
        asm volatile("s_waitcnt vmcnt(0)" ::: "memory");
    }
    __builtin_amdgcn_sched_barrier(0);
    __builtin_amdgcn_s_barrier();
    __builtin_amdgcn_sched_barrier(0);

    for (int tt = 0; tt < NT; ++tt) {
        const int buf = tt % 3;
        if (tt + 2 < NT) STAGE256(tt + 2);
        __builtin_amdgcn_sched_barrier(0);

        bf16x8 af[8], bfv[4];
        #pragma unroll
        for (int i = 0; i < 8; ++i)
            af[i]  = *(const bf16x8*)&lds[buf][0][(wr*128 + i*16 + lr) * 32 + (lk ^ rsw) * 8];
        #pragma unroll
        for (int j = 0; j < 4; ++j)
            bfv[j] = *(const bf16x8*)&lds[buf][1][(wc*64 + j*16 + lr) * 32 + (lk ^ rsw) * 8];

        __builtin_amdgcn_s_setprio(1);
        #pragma unroll
        for (int j = 0; j < 4; ++j)
            #pragma unroll
            for (int i = 0; i < 8; ++i)
                acc[i][j] = __builtin_amdgcn_mfma_f32_16x16x32_bf16(
                    af[i], bfv[j], acc[i][j], 0, 0, 0);
        __builtin_amdgcn_s_setprio(0);

        if (tt + 1 < NT) {
            if (tt + 2 < NT) asm volatile("s_waitcnt vmcnt(4)" ::: "memory");
            else             asm volatile("s_waitcnt vmcnt(0)" ::: "memory");
            __builtin_amdgcn_sched_barrier(0);
            __builtin_amdgcn_s_barrier();
            __builtin_amdgcn_sched_barrier(0);
        }
    }
    #undef STAGE256

    const int colb = col0 + wc * 64 + lr;
    const int rowb = row0 + wr * 128 + lk * 4;
    float bj[4];
    #pragma unroll
    for (int j = 0; j < 4; ++j) bj[j] = bias[colb + j * 16];

    #pragma unroll
    for (int i = 0; i < 8; ++i) {
        #pragma unroll
        for (int r = 0; r < 4; ++r) {
            const size_t row = rowb + i * 16 + r;
            #pragma unroll
            for (int j = 0; j < 4; ++j) {
                float x = fmaxf(acc[i][j][r] + bj[j], 0.f);
                C[row * (size_t)N + colb + j * 16] = f2bf(x);
            }
        }
    }
}

// ---------------------------------------------------------------------------
// gemm256_8ph — m201-style 8-phase schedule (R11-verified, +7-8% vs v1).
// BK=64, 2 K-tiles/iter, 8 waves, LDS 128 KiB = [mat][dbuf][half][128x64].
// Race ledger in R11 notes: per-phase stage targets region dead >=1 barrier
// earlier; vmcnt(4) only at ph4/ph8 (vmcnt(0) last iter ph4). Accumulation
// k-ascending == v1 -> bit-identical (absmax canary 0.0005531311).
// Requires: M,N % 256 == 0, K % 128 == 0.
// ---------------------------------------------------------------------------
__global__ __launch_bounds__(512, 2) void gemm256_8ph(
    const unsigned short* __restrict__ A, const unsigned short* __restrict__ Bt,
    const float* __restrict__ bias, unsigned short* __restrict__ C,
    int M, int N, int K)
{
    __shared__ alignas(16) unsigned short lds[2][2][2][128 * 64];  // 128 KiB

    const int nbx = N >> 8;
    int wg = blockIdx.x;
    const int nwg = gridDim.x;
    if ((nwg & 7) == 0) { const int cpx = nwg >> 3; wg = (wg & 7) * cpx + (wg >> 3); }
    const int bx = wg % nbx, by = wg / nbx;
    const int row0 = by << 8, col0 = bx << 8;

    const int t = threadIdx.x;
    const int w = t >> 6, l = t & 63;
    const int wr = w >> 2, wc = w & 3;
    const int lr = l & 15, lk = l >> 4;

    f32x4 acc[8][4];
    #pragma unroll
    for (int i = 0; i < 8; ++i)
        #pragma unroll
        for (int j = 0; j < 4; ++j) acc[i][j] = (f32x4)(0.f);

    const int NT = K >> 6;     // K-tiles of 64 (even; >=2)
    const int NI = NT >> 1;

    #define STG(mat_, kt_, h_) do {                                              \
        const unsigned short* gb_ = (mat_) ? Bt : A;                              \
        const int gr0_ = (mat_) ? col0 : row0;                                    \
        _Pragma("unroll")                                                         \
        for (int s_ = 0; s_ < 2; ++s_) {                                          \
            const int c_   = s_ * 8 + w;                                          \
            const int row_ = c_ * 8 + (l >> 3);                                   \
            const int g_   = (l & 7) ^ (row_ & 7);                                \
            __builtin_amdgcn_global_load_lds(                                     \
                TO_GLB(gb_ + (size_t)(gr0_ + (h_) * 128 + row_) * K + (kt_) * 64 + g_ * 8), \
                TO_LDS((char*)&lds[mat_][(kt_) & 1][h_][0] + c_ * 1024), 16, 0, 0);\
        } } while (0)

    #define RD_A(dst_, buf_, qi_) do {                                            \
        _Pragma("unroll")                                                         \
        for (int ks_ = 0; ks_ < 2; ++ks_)                                         \
        _Pragma("unroll")                                                         \
        for (int ii_ = 0; ii_ < 4; ++ii_) {                                       \
            const int rh_ = wr * 64 + ii_ * 16 + lr;                              \
            dst_[ks_][ii_] = *(const bf16x8*)                                     \
                &lds[0][buf_][qi_][rh_ * 64 + (((ks_ * 4 + lk) ^ (rh_ & 7)) << 3)]; \
        } } while (0)

    #define RD_B(dst_, buf_, qj_) do {                                            \
        _Pragma("unroll")                                                         \
        for (int ks_ = 0; ks_ < 2; ++ks_)                                         \
        _Pragma("unroll")                                                         \
        for (int jj_ = 0; jj_ < 2; ++jj_) {                                       \
            const int rh_ = wc * 32 + jj_ * 16 + lr;                              \
            dst_[ks_][jj_] = *(const bf16x8*)                                     \
                &lds[1][buf_][qj_][rh_ * 64 + (((ks_ * 4 + lk) ^ (rh_ & 7)) << 3)]; \
        } } while (0)

    #define SYNC_IN() do {                                                        \
        __builtin_amdgcn_sched_barrier(0);                                        \
        __builtin_amdgcn_s_barrier();                                             \
        asm volatile("s_waitcnt lgkmcnt(0)" ::: "memory");                        \
        __builtin_amdgcn_sched_barrier(0); } while (0)

    #define MFMA16(aa_, bb_, qi_, qj_) do {                                       \
        __builtin_amdgcn_s_setprio(1);                                            \
        _Pragma("unroll")                                                         \
        for (int ks_ = 0; ks_ < 2; ++ks_)                                         \
        _Pragma("unroll")                                                         \
        for (int jj_ = 0; jj_ < 2; ++jj_)                                         \
        _Pragma("unroll")                                                         \
        for (int ii_ = 0; ii_ < 4; ++ii_)                                         \
            acc[(qi_)*4+ii_][(qj_)*2+jj_] = __builtin_amdgcn_mfma_f32_16x16x32_bf16( \
                aa_[ks_][ii_], bb_[ks_][jj_], acc[(qi_)*4+ii_][(qj_)*2+jj_], 0, 0, 0); \
        __builtin_amdgcn_s_setprio(0); } while (0)

    #define PH_END() do {                                                         \
        __builtin_amdgcn_sched_barrier(0);                                        \
        __builtin_amdgcn_s_barrier(); } while (0)

    // prologue: t0 full + t1.A0/B0 (12 loads); allow t1's 4 outstanding
    STG(0, 0, 0); STG(0, 0, 1); STG(1, 0, 0); STG(1, 0, 1);
    STG(0, 1, 0); STG(1, 1, 0);
    asm volatile("s_waitcnt vmcnt(4)" ::: "memory");
    __builtin_amdgcn_sched_barrier(0);
    __builtin_amdgcn_s_barrier();
    __builtin_amdgcn_sched_barrier(0);

    for (int m = 0; m < NI; ++m) {
        const int t1 = 2 * m + 1, u0 = 2 * m + 2, u1 = 2 * m + 3;
        const bool last = (m == NI - 1);
        bf16x8 a_[2][4], b0_[2][2], b1_[2][2];

        // ph1: t0 q(0,0)
        RD_A(a_, 0, 0); RD_B(b0_, 0, 0);
        STG(0, t1, 1);
        SYNC_IN(); MFMA16(a_, b0_, 0, 0); PH_END();
        // ph2: t0 q(0,1)
        RD_B(b1_, 0, 1);
        STG(1, t1, 1);
        SYNC_IN(); MFMA16(a_, b1_, 0, 1); PH_END();
        // ph3: t0 q(1,0)
        RD_A(a_, 0, 1);
        if (u0 < NT) STG(0, u0, 0);
        SYNC_IN(); MFMA16(a_, b0_, 1, 0); PH_END();
        // ph4: t0 q(1,1) + K-tile wait
        if (u0 < NT) STG(1, u0, 0);
        SYNC_IN(); MFMA16(a_, b1_, 1, 1);
        if (last) asm volatile("s_waitcnt vmcnt(0)" ::: "memory");
        else      asm volatile("s_waitcnt vmcnt(4)" ::: "memory");
        PH_END();
        // ph5: t1 q(0,0)
        RD_A(a_, 1, 0); RD_B(b0_, 1, 0);
        if (u0 < NT) STG(0, u0, 1);
        SYNC_IN(); MFMA16(a_, b0_, 0, 0); PH_END();
        // ph6: t1 q(0,1)
        RD_B(b1_, 1, 1);
        if (u0 < NT) STG(1, u0, 1);
        SYNC_IN(); MFMA16(a_, b1_, 0, 1); PH_END();
        // ph7: t1 q(1,0)
        RD_A(a_, 1, 1);
        if (u1 < NT) STG(0, u1, 0);
        SYNC_IN(); MFMA16(a_, b0_, 1, 0); PH_END();
        // ph8: t1 q(1,1) + K-tile wait
        if (u1 < NT) STG(1, u1, 0);
        SYNC_IN(); MFMA16(a_, b1_, 1, 1);
        if (!last) asm volatile("s_waitcnt vmcnt(4)" ::: "memory");
        PH_END();
    }
    #undef STG
    #undef RD_A
    #undef RD_B
    #undef SYNC_IN
    #undef MFMA16
    #undef PH_END

    const int colb = col0 + wc * 32 + lr;
    const int rowb = row0 + wr * 64 + lk * 4;
    float bj[4];
    #pragma unroll
    for (int j = 0; j < 4; ++j)
        bj[j] = bias[colb + (j >> 1) * 128 + (j & 1) * 16];

    #pragma unroll
    for (int i = 0; i < 8; ++i) {
        const int gri = rowb + (i >> 2) * 128 + (i & 3) * 16;
        #pragma unroll
        for (int r = 0; r < 4; ++r) {
            const size_t row = gri + r;
            #pragma unroll
            for (int j = 0; j < 4; ++j) {
                float x = fmaxf(acc[i][j][r] + bj[j], 0.f);
                C[row * (size_t)N + colb + (j >> 1) * 128 + (j & 1) * 16] = f2bf(x);
            }
        }
    }
}

// ---------------------------------------------------------------------------
// gemm128: proven pipeline at 128x128 / 4 waves / 48 KiB. Narrow-N GEMMs 6/7.
// ---------------------------------------------------------------------------
template<bool OUT_F32, int ACT>
__global__ __launch_bounds__(256, 2) void gemm128(
    const unsigned short* __restrict__ A, const unsigned short* __restrict__ Bt,
    const float* __restrict__ bias, void* __restrict__ Cp,
    int M, int N, int K, int ldc, int cc0,
    const int* __restrict__ dom, int biasStride)
{
    __shared__ alignas(16) unsigned short lds[3][2][128 * 32];  // 48 KiB

    const int nbx = N >> 7;
    int wg = blockIdx.x;
    const int nwg = gridDim.x;
    if ((nwg & 7) == 0) {
        const int cpx = nwg >> 3;
        wg = (wg & 7) * cpx + (wg >> 3);
    }
    const int bx = wg % nbx, by = wg / nbx;
    const int row0 = by << 7, col0 = bx << 7;

    const int t  = threadIdx.x;
    const int w  = t >> 6, l = t & 63;
    const int wr = w >> 1, wc = w & 1;
    const int lr = l & 15, lk = l >> 4;
    const int rsw = (lr >> 1) & 3;
    const int srow = l >> 2;
    const int skel = ((l & 3) ^ ((l >> 3) & 3)) * 8;

    f32x4 acc[4][4];
    #pragma unroll
    for (int i = 0; i < 4; ++i)
        #pragma unroll
        for (int j = 0; j < 4; ++j)
            acc[i][j] = (f32x4)(0.f);

    const int NT = K >> 5;

    #define STAGE128(tile_)  do {                                            \
        const int k0_  = (tile_) << 5;                                       \
        const int buf_ = (tile_) % 3;                                        \
        _Pragma("unroll")                                                    \
        for (int s_ = 0; s_ < 2; ++s_) {                                     \
            const int c_   = w * 2 + s_;                                     \
            const int row_ = c_ * 16 + srow;                                 \
            __builtin_amdgcn_global_load_lds(                                \
                TO_GLB(A + (size_t)(row0 + row_) * K + k0_ + skel),          \
                TO_LDS((char*)&lds[buf_][0][0] + c_ * 1024), 16, 0, 0);      \
            __builtin_amdgcn_global_load_lds(                                \
                TO_GLB(Bt + (size_t)(col0 + row_) * K + k0_ + skel),         \
                TO_LDS((char*)&lds[buf_][1][0] + c_ * 1024), 16, 0, 0);      \
        }                                                                    \
    } while (0)

    STAGE128(0);
    if (NT > 1) {
        STAGE128(1);
        asm volatile("s_waitcnt vmcnt(4)" ::: "memory");
    } else {
        asm volatile("s_waitcnt vmcnt(0)" ::: "memory");
    }
    __builtin_amdgcn_sched_barrier(0);
    __builtin_amdgcn_s_barrier();
    __builtin_amdgcn_sched_barrier(0);

    for (int tt = 0; tt < NT; ++tt) {
        const int buf = tt % 3;
        if (tt + 2 < NT) STAGE128(tt + 2);
        __builtin_amdgcn_sched_barrier(0);

        bf16x8 af[4], bfv[4];
        #pragma unroll
        for (int i = 0; i < 4; ++i)
            af[i]  = *(const bf16x8*)&lds[buf][0][(wr*64 + i*16 + lr) * 32 + (lk ^ rsw) * 8];
        #pragma unroll
        for (int j = 0; j < 4; ++j)
            bfv[j] = *(const bf16x8*)&lds[buf][1][(wc*64 + j*16 + lr) * 32 + (lk ^ rsw) * 8];

        #pragma unroll
        for (int j = 0; j < 4; ++j)
            #pragma unroll
            for (int i = 0; i < 4; ++i)
                acc[i][j] = __builtin_amdgcn_mfma_f32_16x16x32_bf16(
                    af[i], bfv[j], acc[i][j], 0, 0, 0);

        if (tt + 1 < NT) {
            if (tt + 2 < NT) asm volatile("s_waitcnt vmcnt(4)" ::: "memory");
            else             asm volatile("s_waitcnt vmcnt(0)" ::: "memory");
            __builtin_amdgcn_sched_barrier(0);
            __builtin_amdgcn_s_barrier();
            __builtin_amdgcn_sched_barrier(0);
        }
    }
    #undef STAGE128

    if (dom) bias += (*dom) * biasStride;
    const int colb = col0 + wc * 64 + lr;
    const int rowb = row0 + wr * 64 + lk * 4;
    float bj[4];
    #pragma unroll
    for (int j = 0; j < 4; ++j) bj[j] = bias[colb + j * 16];

    #pragma unroll
    for (int i = 0; i < 4; ++i) {
        #pragma unroll
        for (int r = 0; r < 4; ++r) {
            const size_t row = rowb + i * 16 + r;
            #pragma unroll
            for (int j = 0; j < 4; ++j) {
                float x = acc[i][j][r] + bj[j];
                if (ACT == 1)      x = fmaxf(x, 0.f);
                else if (ACT == 2) x = (x > 0.f) ? x : LEAKS * x;
                const size_t idx = row * (size_t)ldc + cc0 + colb + j * 16;
                if (OUT_F32) ((float*)Cp)[idx] = x;
                else         ((unsigned short*)Cp)[idx] = f2bf(x);
            }
        }
    }
}

// ---------------------------------------------------------------------------
// BatchNorm stats + heads — unchanged (proven).
// ---------------------------------------------------------------------------
__global__ __launch_bounds__(256) void bn_stats_a(
    const float* __restrict__ X, float* __restrict__ psum, float* __restrict__ pss)
{
    const int c  = blockIdx.x * 256 + threadIdx.x;
    const int rb = blockIdx.y;
    float s = 0.f, ss = 0.f;
    const int r0 = rb * 256;
    for (int r = r0; r < r0 + 256; ++r) {
        float v = X[(size_t)r * XW + c];
        s += v; ss = fmaf(v, v, ss);
    }
    psum[rb * XW + c] = s;
    pss [rb * XW + c] = ss;
}

__global__ __launch_bounds__(256) void bn_stats_b(
    const float* __restrict__ psum, const float* __restrict__ pss,
    const float* __restrict__ gamma, const float* __restrict__ beta,
    float* __restrict__ scale, float* __restrict__ shift)
{
    const int c = blockIdx.x * 256 + threadIdx.x;
    float s = 0.f, ss = 0.f;
    for (int rb = 0; rb < 32; ++rb) { s += psum[rb * XW + c]; ss += pss[rb * XW + c]; }
    const float inv = 1.f / (float)BQ;
    const float mean = s * inv;
    const float var  = ss * inv - mean * mean;
    const float sc = gamma[c] * rsqrtf(var + BN_EPS);
    scale[c] = sc;
    shift[c] = beta[c] - mean * sc;
}

__global__ __launch_bounds__(256) void head_kernel(
    const float* __restrict__ X, const float* __restrict__ scale,
    const float* __restrict__ shift, const int* __restrict__ tt,
    const float* __restrict__ Wh1, const float* __restrict__ bh1,
    const float* __restrict__ Wh2, const float* __restrict__ bh2,
    const float* __restrict__ Wh3, const float* __restrict__ bh3,
    float* __restrict__ out)
{
    __shared__ float xs[4][XW];
    __shared__ float y1[4][H1N];
    __shared__ float y2[4][H2N + 2];

    const int t = threadIdx.x;
    const int w = t >> 6;
    const int l = t & 63;
    const int s = blockIdx.x * 4 + w;
    const int d = tt[s];

    #pragma unroll 4
    for (int i = 0; i < XW / 64; ++i) {
        const int c = i * 64 + l;
        xs[w][c] = fmaf(X[(size_t)s * XW + c], scale[c], shift[c]);
    }
    __syncthreads();

    if (l < H1N) {
        const float* W1 = Wh1 + (size_t)d * XW * H1N;
        float acc = bh1[d * H1N + l];
        #pragma unroll 8
        for (int c = 0; c < XW; ++c)
            acc = fmaf(xs[w][c], W1[c * H1N + l], acc);
        y1[w][l] = fmaxf(acc, 0.f);
    }
    __syncthreads();

    if (l < H2N) {
        const float* W2 = Wh2 + (size_t)d * H1N * H2N;
        float acc = bh2[d * H2N + l];
        #pragma unroll
        for (int c = 0; c < H1N; ++c)
            acc = fmaf(y1[w][c], W2[c * H2N + l], acc);
        y2[w][l] = fmaxf(acc, 0.f);
    }
    __syncthreads();

    if (l < NWAY) {
        const float* W3 = Wh3 + (size_t)d * H2N * NWAY;
        float acc = bh3[d * NWAY + l];
        #pragma unroll
        for (int c = 0; c < H2N; ++c)
            acc = fmaf(y2[w][c], W3[c * NWAY + l], acc);
        out[(size_t)s * NWAY + l] = acc;
    }
}

// ---------------------------------------------------------------------------
extern "C" void kernel_launch(void* const* d_in, const int* in_sizes, int n_in,
                              void* d_out, int out_size, void* d_ws, size_t ws_size,
                              hipStream_t stream)
{
    const float* x_s   = (const float*)d_in[0];
    const float* x_p   = (const float*)d_in[1];
    const int*   tt    = (const int*)  d_in[2];
    const int*   dom   = (const int*)  d_in[3];
    const float* W_in  = (const float*)d_in[4];
    const float* b_in  = (const float*)d_in[5];
    const float* W_hid = (const float*)d_in[6];
    const float* b_hid = (const float*)d_in[7];
    const float* W_out = (const float*)d_in[8];
    const float* b_out = (const float*)d_in[9];
    const float* Wp    = (const float*)d_in[10];
    const float* bp    = (const float*)d_in[11];
    const float* gamma = (const float*)d_in[12];
    const float* beta  = (const float*)d_in[13];
    const float* Wh1   = (const float*)d_in[14];
    const float* bh1   = (const float*)d_in[15];
    const float* Wh2   = (const float*)d_in[16];
    const float* bh2   = (const float*)d_in[17];
    const float* Wh3   = (const float*)d_in[18];
    const float* bh3   = (const float*)d_in[19];
    float* out = (float*)d_out;

    const dim3 blk(256);
    char* w = (char*)d_ws;

    const size_t FAST_NEED = 470810624ull;

    if (ws_size >= FAST_NEED) {
        unsigned short* xb    = (unsigned short*)w;                    // 192M
        unsigned short* WinT  = (unsigned short*)(w + 201326592);      // 96M region
        unsigned short* WoutT = (unsigned short*)(w + 201326592);      //  8M
        unsigned short* WpT   = (unsigned short*)(w + 209715200);      // 24M
        unsigned short* actA  = (unsigned short*)(w + 301989888);      // 64M
        unsigned short* actB  = (unsigned short*)(w + 369098752);      // 64M
        float*          X     = (float*)(w + 369098752);               // aliases actB
        unsigned short* WhidT = (unsigned short*)(w + 436207616);      // 32M
        float*          psum  = (float*)(w + 469762048);
        float*          pss   = psum + 32 * XW;
        float*          scale = pss  + 32 * XW;
        float*          shift = scale + XW;

        cvt_bf16<<<dim3(2048), blk, 0, stream>>>(x_s, xb, (long long)BQ * FIN / 8);
        transpose_cvt<<<dim3(SUN/64,  FIN/64), blk, 0, stream>>>(W_in,  WinT,  FIN, SUN,  nullptr);
        transpose_cvt<<<dim3(SUN/64,  SUN/64), blk, 0, stream>>>(W_hid, WhidT, SUN, SUN,  nullptr);

        // GEMM1 — 8-phase (K=12288 -> NT=192 even)
        gemm256_8ph<<<dim3(512), dim3(512), 0, stream>>>(xb, WinT, b_in, actA, BQ, SUN, FIN);

        transpose_cvt<<<dim3(HIDN/64, SUN/64), blk, 0, stream>>>(W_out, WoutT, SUN, HIDN, nullptr);
        transpose_cvt<<<dim3(HIDN/64, FIN/64), blk, 0, stream>>>(Wp,    WpT,   FIN, HIDN, dom);
        cvt_bf16<<<dim3(2048), blk, 0, stream>>>(x_p, xb, (long long)BQ * FIN / 8);

        // hidden layers — all 8-phase (R11-verified winner)
        gemm256_8ph<<<dim3(512), dim3(512), 0, stream>>>(actA, WhidT, b_hid, actB, BQ, SUN, SUN);
        gemm256_8ph<<<dim3(512), dim3(512), 0, stream>>>(actB, WhidT, b_hid, actA, BQ, SUN, SUN);
        gemm256_8ph<<<dim3(512), dim3(512), 0, stream>>>(actA, WhidT, b_hid, actB, BQ, SUN, SUN);
        gemm256_8ph<<<dim3(512), dim3(512), 0, stream>>>(actB, WhidT, b_hid, actA, BQ, SUN, SUN);

        gemm128<true,1><<<dim3(512), blk, 0, stream>>>(
            actA, WoutT, b_out, X, BQ, HIDN, SUN, XW, 0, nullptr, 0);
        gemm128<true,2><<<dim3(512), blk, 0, stream>>>(
            xb, WpT, bp, X, BQ, HIDN, FIN, XW, HIDN, dom, HIDN);

        bn_stats_a<<<dim3(XW/256, 32), blk, 0, stream>>>(X, psum, pss);
        bn_stats_b<<<dim3(XW/256),     blk, 0, stream>>>(psum, pss, gamma, beta, scale, shift);
        head_kernel<<<dim3(BQ/4), blk, 0, stream>>>(X, scale, shift, tt,
                                                    Wh1, bh1, Wh2, bh2, Wh3, bh3, out);
        return;
    }

    // ---------------- fallback: 256 MiB path ----------------
    unsigned short* actA  = (unsigned short*)w;
    unsigned short* actB  = (unsigned short*)(w + 67108864);
    float*          X     = (float*)(w + 67108864);
    unsigned short* WinT  = (unsigned short*)(w + 134217728);
    unsigned short* WoutT = (unsigned short*)(w + 134217728);
    unsigned short* WpT   = (unsigned short*)(w + 142606336);
    float*          psum  = (float*)(w + 167772160);
    float*          pss   = psum + 32 * XW;
    float*          scale = pss  + 32 * XW;
    float*          shift = scale + XW;
    unsigned short* WhidT = (unsigned short*)(w + 234881024);

    transpose_cvt<<<dim3(SUN/64,  FIN/64), blk, 0, stream>>>(W_in,  WinT,  FIN, SUN,  nullptr);
    transpose_cvt<<<dim3(SUN/64,  SUN/64), blk, 0, stream>>>(W_hid, WhidT, SUN, SUN,  nullptr);

    gemm_mfma<true,false,1><<<dim3(2048), blk, 0, stream>>>(
        x_s, WinT, b_in, actA, BQ, SUN, FIN, SUN, 0, nullptr, 0);

    transpose_cvt<<<dim3(HIDN/64, SUN/64), blk, 0, stream>>>(W_out, WoutT, SUN, HIDN, nullptr);
    transpose_cvt<<<dim3(HIDN/64, FIN/64), blk, 0, stream>>>(Wp,    WpT,   FIN, HIDN, dom);

    gemm256<<<dim3(512), dim3(512), 0, stream>>>(actA, WhidT, b_hid, actB, BQ, SUN, SUN);
    gemm256<<<dim3(512), dim3(512), 0, stream>>>(actB, WhidT, b_hid, actA, BQ, SUN, SUN);
    gemm256<<<dim3(512), dim3(512), 0, stream>>>(actA, WhidT, b_hid, actB, BQ, SUN, SUN);
    gemm256<<<dim3(512), dim3(512), 0, stream>>>(actB, WhidT, b_hid, actA, BQ, SUN, SUN);

    gemm128<true,1><<<dim3(512), blk, 0, stream>>>(
        actA, WoutT, b_out, X, BQ, HIDN, SUN, XW, 0, nullptr, 0);
    gemm_mfma<true,true,2><<<dim3(512), blk, 0, stream>>>(
        x_p, WpT, bp, X, BQ, HIDN, FIN, XW, HIDN, dom, HIDN);

    bn_stats_a<<<dim3(XW/256, 32), blk, 0, stream>>>(X, psum, pss);
    bn_stats_b<<<dim3(XW/256),     blk, 0, stream>>>(psum, pss, gamma, beta, scale, shift);
    head_kernel<<<dim3(BQ/4), blk, 0, stream>>>(X, scale, shift, tt,
                                                Wh1, bh1, Wh2, bh2, Wh3, bh3, out);
}

// Round 13
// 2383.070 us; speedup vs baseline: 1.2833x; 1.0020x over previous
//
#include <hip/hip_runtime.h>
#include <hip/hip_bf16.h>

// Problem constants
#define BQ    8192
#define FIN   12288
#define SUN   4096
#define HIDN  1024
#define XW    2048
#define H1N   28
#define H2N   14
#define NWAY  5
#define BN_EPS 1e-5f
#define LEAKS 0.001f

typedef __bf16 bf16x8 __attribute__((ext_vector_type(8)));
typedef float  f32x4  __attribute__((ext_vector_type(4)));
typedef unsigned short ushort8 __attribute__((ext_vector_type(8)));

__device__ __forceinline__ unsigned short f2bf(float f) {
    unsigned u = __float_as_uint(f);
    unsigned r = u + 0x7fffu + ((u >> 16) & 1u);   // RNE
    return (unsigned short)(r >> 16);
}

__device__ __forceinline__ ushort8 cvt8(const float4 a, const float4 b) {
    union { __bf16 h[8]; ushort8 u; } r;
    r.h[0] = (__bf16)a.x; r.h[1] = (__bf16)a.y;
    r.h[2] = (__bf16)a.z; r.h[3] = (__bf16)a.w;
    r.h[4] = (__bf16)b.x; r.h[5] = (__bf16)b.y;
    r.h[6] = (__bf16)b.z; r.h[7] = (__bf16)b.w;
    return r.u;
}

#define TO_LDS(p) ((__attribute__((address_space(3))) void*)(p))
#define TO_GLB(p) ((const __attribute__((address_space(1))) void*)(p))

// ---------------------------------------------------------------------------
__global__ __launch_bounds__(256) void cvt_bf16(
    const float* __restrict__ in, unsigned short* __restrict__ out, long long n8)
{
    const long long idx = (long long)blockIdx.x * 256 + threadIdx.x;
    const long long stride = (long long)gridDim.x * 256;
    for (long long i = idx; i < n8; i += stride) {
        const float4 a = ((const float4*)in)[2 * i];
        const float4 b = ((const float4*)in)[2 * i + 1];
        ((ushort8*)out)[i] = cvt8(a, b);
    }
}

// ---------------------------------------------------------------------------
__global__ __launch_bounds__(256) void transpose_cvt(
    const float* __restrict__ in, unsigned short* __restrict__ out,
    int R, int Cc, const int* __restrict__ dom)
{
    if (dom) in += (size_t)(*dom) * (size_t)R * (size_t)Cc;
    __shared__ float tile[64][65];
    const int t  = threadIdx.x;
    const int tr = t >> 4;
    const int tc = t & 15;
    const int c0 = blockIdx.x * 64;
    const int r0 = blockIdx.y * 64;

    #pragma unroll
    for (int q = 0; q < 4; ++q) {
        const int r = r0 + tr + q * 16;
        const float4 v = *(const float4*)&in[(size_t)r * Cc + c0 + tc * 4];
        tile[tc*4+0][tr + q*16] = v.x;
        tile[tc*4+1][tr + q*16] = v.y;
        tile[tc*4+2][tr + q*16] = v.z;
        tile[tc*4+3][tr + q*16] = v.w;
    }
    __syncthreads();
    #pragma unroll
    for (int q = 0; q < 4; ++q) {
        const int c = c0 + tr + q * 16;
        ushort4 o;
        o.x = f2bf(tile[tr + q*16][tc*4+0]);
        o.y = f2bf(tile[tr + q*16][tc*4+1]);
        o.z = f2bf(tile[tr + q*16][tc*4+2]);
        o.w = f2bf(tile[tr + q*16][tc*4+3]);
        *(ushort4*)&out[(size_t)c * R + r0 + tc * 4] = o;
    }
}

// ---------------------------------------------------------------------------
// m97-structure bf16 MFMA GEMM (128x128, 2-barrier) — fp32-A fallback only.
// ---------------------------------------------------------------------------
template<bool A_F32, bool OUT_F32, int ACT>
__global__ __launch_bounds__(256) void gemm_mfma(
    const void* __restrict__ Ap, const unsigned short* __restrict__ Bt,
    const float* __restrict__ bias, void* __restrict__ Cp,
    int M, int N, int K, int ldc, int cc0,
    const int* __restrict__ dom, int biasStride)
{
    __shared__ alignas(16) unsigned short As[128 * 32];
    __shared__ alignas(16) unsigned short Bs[128 * 32];

    const int nbx = N >> 7;
    int wg = blockIdx.x;
    const int nwg = gridDim.x;
    if ((nwg & 7) == 0) {
        const int cpx = nwg >> 3;
        wg = (wg & 7) * cpx + (wg >> 3);
    }
    const int bx = wg % nbx, by = wg / nbx;
    const int row0 = by << 7, col0 = bx << 7;

    const int t  = threadIdx.x;
    const int w  = t >> 6;
    const int l  = t & 63;
    const int wr = w >> 1, wc = w & 1;
    const int lr = l & 15, lk = l >> 4;
    const int rsw = (lr >> 1) & 3;

    f32x4 acc[4][4];
    #pragma unroll
    for (int i = 0; i < 4; ++i)
        #pragma unroll
        for (int j = 0; j < 4; ++j)
            acc[i][j] = (f32x4)(0.f);

    const int srow = l >> 2;
    const int skb  = (((l & 3) ^ ((l >> 3) & 3)) * 16);
    const float* Af = (const float*)Ap;
    const unsigned short* Ab = (const unsigned short*)Ap;

    for (int k0 = 0; k0 < K; k0 += 32) {
        __syncthreads();

        #pragma unroll
        for (int c = 0; c < 2; ++c) {
            const int inst = w * 2 + c;
            const int row  = inst * 16 + srow;
            const char* src = (const char*)Bt +
                (((size_t)(col0 + row) * K + k0) * 2 + skb);
            char* dst = (char*)Bs + inst * 1024;
            __builtin_amdgcn_global_load_lds(TO_GLB(src), TO_LDS(dst), 16, 0, 0);
        }
        if (!A_F32) {
            #pragma unroll
            for (int c = 0; c < 2; ++c) {
                const int inst = w * 2 + c;
                const int row  = inst * 16 + srow;
                const char* src = (const char*)Ab +
                    (((size_t)(row0 + row) * K + k0) * 2 + skb);
                char* dst = (char*)As + inst * 1024;
                __builtin_amdgcn_global_load_lds(TO_GLB(src), TO_LDS(dst), 16, 0, 0);
            }
        } else {
            #pragma unroll
            for (int c = 0; c < 2; ++c) {
                const int ci  = t + 256 * c;
                const int row = ci >> 2;
                const int ko  = (((ci & 3) ^ ((ci >> 3) & 3)) * 8);
                const float* s = Af + (size_t)(row0 + row) * K + k0 + ko;
                const float4 v0 = *(const float4*)s;
                const float4 v1 = *(const float4*)(s + 4);
                *(ushort8*)&As[ci * 8] = cvt8(v0, v1);
            }
        }
        __syncthreads();

        bf16x8 af[4], bfv[4];
        #pragma unroll
        for (int i = 0; i < 4; ++i)
            af[i]  = *(const bf16x8*)&As[(wr*64 + i*16 + lr) * 32 + (lk ^ rsw) * 8];
        #pragma unroll
        for (int j = 0; j < 4; ++j)
            bfv[j] = *(const bf16x8*)&Bs[(wc*64 + j*16 + lr) * 32 + (lk ^ rsw) * 8];
        #pragma unroll
        for (int i = 0; i < 4; ++i)
            #pragma unroll
            for (int j = 0; j < 4; ++j)
                acc[i][j] = __builtin_amdgcn_mfma_f32_16x16x32_bf16(
                    af[i], bfv[j], acc[i][j], 0, 0, 0);
    }

    if (dom) bias += (*dom) * biasStride;
    const int colb = col0 + wc * 64 + lr;
    const int rowb = row0 + wr * 64 + lk * 4;
    float bj[4];
    #pragma unroll
    for (int j = 0; j < 4; ++j) bj[j] = bias[colb + j * 16];

    #pragma unroll
    for (int i = 0; i < 4; ++i) {
        #pragma unroll
        for (int r = 0; r < 4; ++r) {
            const size_t row = rowb + i * 16 + r;
            #pragma unroll
            for (int j = 0; j < 4; ++j) {
                float x = acc[i][j][r] + bj[j];
                if (ACT == 1)      x = fmaxf(x, 0.f);
                else if (ACT == 2) x = (x > 0.f) ? x : LEAKS * x;
                const size_t idx = row * (size_t)ldc + cc0 + colb + j * 16;
                if (OUT_F32) ((float*)Cp)[idx] = x;
                else         ((unsigned short*)Cp)[idx] = f2bf(x);
            }
        }
    }
}

// ---------------------------------------------------------------------------
// gemm256 (v1): kept for fallback path only.
// ---------------------------------------------------------------------------
__global__ __launch_bounds__(512, 2) void gemm256(
    const unsigned short* __restrict__ A, const unsigned short* __restrict__ Bt,
    const float* __restrict__ bias, unsigned short* __restrict__ C,
    int M, int N, int K)
{
    __shared__ alignas(16) unsigned short lds[3][2][256 * 32];  // 96 KiB

    const int nbx = N >> 8;
    int wg = blockIdx.x;
    const int nwg = gridDim.x;
    if ((nwg & 7) == 0) {
        const int cpx = nwg >> 3;
        wg = (wg & 7) * cpx + (wg >> 3);
    }
    const int bx = wg % nbx, by = wg / nbx;
    const int row0 = by << 8, col0 = bx << 8;

    const int t  = threadIdx.x;
    const int w  = t >> 6, l = t & 63;
    const int wr = w >> 2, wc = w & 3;
    const int lr = l & 15, lk = l >> 4;
    const int rsw = (lr >> 1) & 3;
    const int srow = l >> 2;
    const int skel = ((l & 3) ^ ((l >> 3) & 3)) * 8;

    f32x4 acc[8][4];
    #pragma unroll
    for (int i = 0; i < 8; ++i)
        #pragma unroll
        for (int j = 0; j < 4; ++j)
            acc[i][j] = (f32x4)(0.f);

    const int NT = K >> 5;

    #define STAGE256(tile_)  do {                                            \
        const int k0_  = (tile_) << 5;                                       \
        const int buf_ = (tile_) % 3;                                        \
        _Pragma("unroll")                                                    \
        for (int s_ = 0; s_ < 2; ++s_) {                                     \
            const int c_   = w * 2 + s_;                                     \
            const int row_ = c_ * 16 + srow;                                 \
            __builtin_amdgcn_global_load_lds(                                \
                TO_GLB(A + (size_t)(row0 + row_) * K + k0_ + skel),          \
                TO_LDS((char*)&lds[buf_][0][0] + c_ * 1024), 16, 0, 0);      \
            __builtin_amdgcn_global_load_lds(                                \
                TO_GLB(Bt + (size_t)(col0 + row_) * K + k0_ + skel),         \
                TO_LDS((char*)&lds[buf_][1][0] + c_ * 1024), 16, 0, 0);      \
        }                                                                    \
    } while (0)

    STAGE256(0);
    if (NT > 1) {
        STAGE256(1);
        asm volatile("s_waitcnt vmcnt(4)" ::: "memory");
    } else {
        asm volatile("s_waitcnt vmcnt(0)" ::: "memory");
    }
    __builtin_amdgcn_sched_barrier(0);
    __builtin_amdgcn_s_barrier();
    __builtin_amdgcn_sched_barrier(0);

    for (int tt = 0; tt < NT; ++tt) {
        const int buf = tt % 3;
        if (tt + 2 < NT) STAGE256(tt + 2);
        __builtin_amdgcn_sched_barrier(0);

        bf16x8 af[8], bfv[4];
        #pragma unroll
        for (int i = 0; i < 8; ++i)
            af[i]  = *(const bf16x8*)&lds[buf][0][(wr*128 + i*16 + lr) * 32 + (lk ^ rsw) * 8];
        #pragma unroll
        for (int j = 0; j < 4; ++j)
            bfv[j] = *(const bf16x8*)&lds[buf][1][(wc*64 + j*16 + lr) * 32 + (lk ^ rsw) * 8];

        __builtin_amdgcn_s_setprio(1);
        #pragma unroll
        for (int j = 0; j < 4; ++j)
            #pragma unroll
            for (int i = 0; i < 8; ++i)
                acc[i][j] = __builtin_amdgcn_mfma_f32_16x16x32_bf16(
                    af[i], bfv[j], acc[i][j], 0, 0, 0);
        __builtin_amdgcn_s_setprio(0);

        if (tt + 1 < NT) {
            if (tt + 2 < NT) asm volatile("s_waitcnt vmcnt(4)" ::: "memory");
            else             asm volatile("s_waitcnt vmcnt(0)" ::: "memory");
            __builtin_amdgcn_sched_barrier(0);
            __builtin_amdgcn_s_barrier();
            __builtin_amdgcn_sched_barrier(0);
        }
    }
    #undef STAGE256

    const int colb = col0 + wc * 64 + lr;
    const int rowb = row0 + wr * 128 + lk * 4;
    float bj[4];
    #pragma unroll
    for (int j = 0; j < 4; ++j) bj[j] = bias[colb + j * 16];

    #pragma unroll
    for (int i = 0; i < 8; ++i) {
        #pragma unroll
        for (int r = 0; r < 4; ++r) {
            const size_t row = rowb + i * 16 + r;
            #pragma unroll
            for (int j = 0; j < 4; ++j) {
                float x = fmaxf(acc[i][j][r] + bj[j], 0.f);
                C[row * (size_t)N + colb + j * 16] = f2bf(x);
            }
        }
    }
}

// ---------------------------------------------------------------------------
// 8-phase schedule core, shared by DEPTH=2 (R11/R12-proven, vmcnt(4)) and
// DEPTH=3 (m201 steady-state, vmcnt(6), stages shifted one phase earlier).
// BK=64, 2 K-tiles/iter, 8 waves, LDS 128 KiB = [mat][dbuf][half][128x64].
// DEPTH=3 ledger: iter stages {ph1:B1(t1), ph2:A0(u0), ph3:B0(u0), ph4:A1(u0),
// ph5:B1(u0), ph6:A0(u1), ph7:B0(u1), ph8:A1(u1)}; vmcnt(6) at ph4 retires
// B1(t1)+older -> t1 complete before ph5 reads it; vmcnt(6) at ph8 retires
// B1(u0)+older -> u0 complete before next ph1. WAR: every stage's target was
// last ds_read >=1 barrier before the stage issues (checked half-by-half).
// Last iter: ph4 drains vmcnt(0) (only B1(t1) outstanding).
// Accumulation k-ascending, identical for both depths -> bit-identical output
// (absmax canary 0.0005531311). Requires M,N % 256 == 0, K % 128 == 0.
// ---------------------------------------------------------------------------
template<int DEPTH>
__global__ __launch_bounds__(512, 2) void gemm256_8ph(
    const unsigned short* __restrict__ A, const unsigned short* __restrict__ Bt,
    const float* __restrict__ bias, unsigned short* __restrict__ C,
    int M, int N, int K)
{
    __shared__ alignas(16) unsigned short lds[2][2][2][128 * 64];  // 128 KiB

    const int nbx = N >> 8;
    int wg = blockIdx.x;
    const int nwg = gridDim.x;
    if ((nwg & 7) == 0) { const int cpx = nwg >> 3; wg = (wg & 7) * cpx + (wg >> 3); }
    const int bx = wg % nbx, by = wg / nbx;
    const int row0 = by << 8, col0 = bx << 8;

    const int t = threadIdx.x;
    const int w = t >> 6, l = t & 63;
    const int wr = w >> 2, wc = w & 3;
    const int lr = l & 15, lk = l >> 4;

    f32x4 acc[8][4];
    #pragma unroll
    for (int i = 0; i < 8; ++i)
        #pragma unroll
        for (int j = 0; j < 4; ++j) acc[i][j] = (f32x4)(0.f);

    const int NT = K >> 6;     // K-tiles of 64 (even; >=2)
    const int NI = NT >> 1;

    #define STG(mat_, kt_, h_) do {                                              \
        const unsigned short* gb_ = (mat_) ? Bt : A;                              \
        const int gr0_ = (mat_) ? col0 : row0;                                    \
        _Pragma("unroll")                                                         \
        for (int s_ = 0; s_ < 2; ++s_) {                                          \
            const int c_   = s_ * 8 + w;                                          \
            const int row_ = c_ * 8 + (l >> 3);                                   \
            const int g_   = (l & 7) ^ (row_ & 7);                                \
            __builtin_amdgcn_global_load_lds(                                     \
                TO_GLB(gb_ + (size_t)(gr0_ + (h_) * 128 + row_) * K + (kt_) * 64 + g_ * 8), \
                TO_LDS((char*)&lds[mat_][(kt_) & 1][h_][0] + c_ * 1024), 16, 0, 0);\
        } } while (0)

    #define RD_A(dst_, buf_, qi_) do {                                            \
        _Pragma("unroll")                                                         \
        for (int ks_ = 0; ks_ < 2; ++ks_)                                         \
        _Pragma("unroll")                                                         \
        for (int ii_ = 0; ii_ < 4; ++ii_) {                                       \
            const int rh_ = wr * 64 + ii_ * 16 + lr;                              \
            dst_[ks_][ii_] = *(const bf16x8*)                                     \
                &lds[0][buf_][qi_][rh_ * 64 + (((ks_ * 4 + lk) ^ (rh_ & 7)) << 3)]; \
        } } while (0)

    #define RD_B(dst_, buf_, qj_) do {                                            \
        _Pragma("unroll")                                                         \
        for (int ks_ = 0; ks_ < 2; ++ks_)                                         \
        _Pragma("unroll")                                                         \
        for (int jj_ = 0; jj_ < 2; ++jj_) {                                       \
            const int rh_ = wc * 32 + jj_ * 16 + lr;                              \
            dst_[ks_][jj_] = *(const bf16x8*)                                     \
                &lds[1][buf_][qj_][rh_ * 64 + (((ks_ * 4 + lk) ^ (rh_ & 7)) << 3)]; \
        } } while (0)

    #define SYNC_IN() do {                                                        \
        __builtin_amdgcn_sched_barrier(0);                                        \
        __builtin_amdgcn_s_barrier();                                             \
        asm volatile("s_waitcnt lgkmcnt(0)" ::: "memory");                        \
        __builtin_amdgcn_sched_barrier(0); } while (0)

    #define MFMA16(aa_, bb_, qi_, qj_) do {                                       \
        __builtin_amdgcn_s_setprio(1);                                            \
        _Pragma("unroll")                                                         \
        for (int ks_ = 0; ks_ < 2; ++ks_)                                         \
        _Pragma("unroll")                                                         \
        for (int jj_ = 0; jj_ < 2; ++jj_)                                         \
        _Pragma("unroll")                                                         \
        for (int ii_ = 0; ii_ < 4; ++ii_)                                         \
            acc[(qi_)*4+ii_][(qj_)*2+jj_] = __builtin_amdgcn_mfma_f32_16x16x32_bf16( \
                aa_[ks_][ii_], bb_[ks_][jj_], acc[(qi_)*4+ii_][(qj_)*2+jj_], 0, 0, 0); \
        __builtin_amdgcn_s_setprio(0); } while (0)

    #define PH_END() do {                                                         \
        __builtin_amdgcn_sched_barrier(0);                                        \
        __builtin_amdgcn_s_barrier(); } while (0)

    if (DEPTH == 2) {
        // prologue: t0 full + t1.A0/B0 (6 halves); retire t0 (keep 4 loads)
        STG(0, 0, 0); STG(0, 0, 1); STG(1, 0, 0); STG(1, 0, 1);
        STG(0, 1, 0); STG(1, 1, 0);
        asm volatile("s_waitcnt vmcnt(4)" ::: "memory");
    } else {
        // prologue: t0 full + t1.A0,B0,A1 (7 halves); retire t0 (keep 6 loads)
        STG(0, 0, 0); STG(0, 0, 1); STG(1, 0, 0); STG(1, 0, 1);
        STG(0, 1, 0); STG(1, 1, 0); STG(0, 1, 1);
        asm volatile("s_waitcnt vmcnt(6)" ::: "memory");
    }
    __builtin_amdgcn_sched_barrier(0);
    __builtin_amdgcn_s_barrier();
    __builtin_amdgcn_sched_barrier(0);

    for (int m = 0; m < NI; ++m) {
        const int t1 = 2 * m + 1, u0 = 2 * m + 2, u1 = 2 * m + 3;
        const bool last = (m == NI - 1);
        bf16x8 a_[2][4], b0_[2][2], b1_[2][2];

        // ph1: t0 q(0,0)
        RD_A(a_, 0, 0); RD_B(b0_, 0, 0);
        if (DEPTH == 2) STG(0, t1, 1); else STG(1, t1, 1);
        SYNC_IN(); MFMA16(a_, b0_, 0, 0); PH_END();
        // ph2: t0 q(0,1)
        RD_B(b1_, 0, 1);
        if (DEPTH == 2) { STG(1, t1, 1); }
        else            { if (u0 < NT) STG(0, u0, 0); }
        SYNC_IN(); MFMA16(a_, b1_, 0, 1); PH_END();
        // ph3: t0 q(1,0)
        RD_A(a_, 0, 1);
        if (DEPTH == 2) { if (u0 < NT) STG(0, u0, 0); }
        else            { if (u0 < NT) STG(1, u0, 0); }
        SYNC_IN(); MFMA16(a_, b0_, 1, 0); PH_END();
        // ph4: t0 q(1,1) + K-tile wait
        if (DEPTH == 2) { if (u0 < NT) STG(1, u0, 0); }
        else            { if (u0 < NT) STG(0, u0, 1); }
        SYNC_IN(); MFMA16(a_, b1_, 1, 1);
        if (last) asm volatile("s_waitcnt vmcnt(0)" ::: "memory");
        else if (DEPTH == 2) asm volatile("s_waitcnt vmcnt(4)" ::: "memory");
        else                 asm volatile("s_waitcnt vmcnt(6)" ::: "memory");
        PH_END();
        // ph5: t1 q(0,0)
        RD_A(a_, 1, 0); RD_B(b0_, 1, 0);
        if (DEPTH == 2) { if (u0 < NT) STG(0, u0, 1); }
        else            { if (u0 < NT) STG(1, u0, 1); }
        SYNC_IN(); MFMA16(a_, b0_, 0, 0); PH_END();
        // ph6: t1 q(0,1)
        RD_B(b1_, 1, 1);
        if (DEPTH == 2) { if (u0 < NT) STG(1, u0, 1); }
        else            { if (u1 < NT) STG(0, u1, 0); }
        SYNC_IN(); MFMA16(a_, b1_, 0, 1); PH_END();
        // ph7: t1 q(1,0)
        RD_A(a_, 1, 1);
        if (DEPTH == 2) { if (u1 < NT) STG(0, u1, 0); }
        else            { if (u1 < NT) STG(1, u1, 0); }
        SYNC_IN(); MFMA16(a_, b0_, 1, 0); PH_END();
        // ph8: t1 q(1,1) + K-tile wait
        if (DEPTH == 2) { if (u1 < NT) STG(1, u1, 0); }
        else            { if (u1 < NT) STG(0, u1, 1); }
        SYNC_IN(); MFMA16(a_, b1_, 1, 1);
        if (!last) {
            if (DEPTH == 2) asm volatile("s_waitcnt vmcnt(4)" ::: "memory");
            else            asm volatile("s_waitcnt vmcnt(6)" ::: "memory");
        }
        PH_END();
    }
    #undef STG
    #undef RD_A
    #undef RD_B
    #undef SYNC_IN
    #undef MFMA16
    #undef PH_END

    const int colb = col0 + wc * 32 + lr;
    const int rowb = row0 + wr * 64 + lk * 4;
    float bj[4];
    #pragma unroll
    for (int j = 0; j < 4; ++j)
        bj[j] = bias[colb + (j >> 1) * 128 + (j & 1) * 16];

    #pragma unroll
    for (int i = 0; i < 8; ++i) {
        const int gri = rowb + (i >> 2) * 128 + (i & 3) * 16;
        #pragma unroll
        for (int r = 0; r < 4; ++r) {
            const size_t row = gri + r;
            #pragma unroll
            for (int j = 0; j < 4; ++j) {
                float x = fmaxf(acc[i][j][r] + bj[j], 0.f);
                C[row * (size_t)N + colb + (j >> 1) * 128 + (j & 1) * 16] = f2bf(x);
            }
        }
    }
}

// ---------------------------------------------------------------------------
// gemm128: proven pipeline at 128x128 / 4 waves / 48 KiB. Narrow-N GEMMs 6/7.
// ---------------------------------------------------------------------------
template<bool OUT_F32, int ACT>
__global__ __launch_bounds__(256, 2) void gemm128(
    const unsigned short* __restrict__ A, const unsigned short* __restrict__ Bt,
    const float* __restrict__ bias, void* __restrict__ Cp,
    int M, int N, int K, int ldc, int cc0,
    const int* __restrict__ dom, int biasStride)
{
    __shared__ alignas(16) unsigned short lds[3][2][128 * 32];  // 48 KiB

    const int nbx = N >> 7;
    int wg = blockIdx.x;
    const int nwg = gridDim.x;
    if ((nwg & 7) == 0) {
        const int cpx = nwg >> 3;
        wg = (wg & 7) * cpx + (wg >> 3);
    }
    const int bx = wg % nbx, by = wg / nbx;
    const int row0 = by << 7, col0 = bx << 7;

    const int t  = threadIdx.x;
    const int w  = t >> 6, l = t & 63;
    const int wr = w >> 1, wc = w & 1;
    const int lr = l & 15, lk = l >> 4;
    const int rsw = (lr >> 1) & 3;
    const int srow = l >> 2;
    const int skel = ((l & 3) ^ ((l >> 3) & 3)) * 8;

    f32x4 acc[4][4];
    #pragma unroll
    for (int i = 0; i < 4; ++i)
        #pragma unroll
        for (int j = 0; j < 4; ++j)
            acc[i][j] = (f32x4)(0.f);

    const int NT = K >> 5;

    #define STAGE128(tile_)  do {                                            \
        const int k0_  = (tile_) << 5;                                       \
        const int buf_ = (tile_) % 3;                                        \
        _Pragma("unroll")                                                    \
        for (int s_ = 0; s_ < 2; ++s_) {                                     \
            const int c_   = w * 2 + s_;                                     \
            const int row_ = c_ * 16 + srow;                                 \
            __builtin_amdgcn_global_load_lds(                                \
                TO_GLB(A + (size_t)(row0 + row_) * K + k0_ + skel),          \
                TO_LDS((char*)&lds[buf_][0][0] + c_ * 1024), 16, 0, 0);      \
            __builtin_amdgcn_global_load_lds(                                \
                TO_GLB(Bt + (size_t)(col0 + row_) * K + k0_ + skel),         \
                TO_LDS((char*)&lds[buf_][1][0] + c_ * 1024), 16, 0, 0);      \
        }                                                                    \
    } while (0)

    STAGE128(0);
    if (NT > 1) {
        STAGE128(1);
        asm volatile("s_waitcnt vmcnt(4)" ::: "memory");
    } else {
        asm volatile("s_waitcnt vmcnt(0)" ::: "memory");
    }
    __builtin_amdgcn_sched_barrier(0);
    __builtin_amdgcn_s_barrier();
    __builtin_amdgcn_sched_barrier(0);

    for (int tt = 0; tt < NT; ++tt) {
        const int buf = tt % 3;
        if (tt + 2 < NT) STAGE128(tt + 2);
        __builtin_amdgcn_sched_barrier(0);

        bf16x8 af[4], bfv[4];
        #pragma unroll
        for (int i = 0; i < 4; ++i)
            af[i]  = *(const bf16x8*)&lds[buf][0][(wr*64 + i*16 + lr) * 32 + (lk ^ rsw) * 8];
        #pragma unroll
        for (int j = 0; j < 4; ++j)
            bfv[j] = *(const bf16x8*)&lds[buf][1][(wc*64 + j*16 + lr) * 32 + (lk ^ rsw) * 8];

        #pragma unroll
        for (int j = 0; j < 4; ++j)
            #pragma unroll
            for (int i = 0; i < 4; ++i)
                acc[i][j] = __builtin_amdgcn_mfma_f32_16x16x32_bf16(
                    af[i], bfv[j], acc[i][j], 0, 0, 0);

        if (tt + 1 < NT) {
            if (tt + 2 < NT) asm volatile("s_waitcnt vmcnt(4)" ::: "memory");
            else             asm volatile("s_waitcnt vmcnt(0)" ::: "memory");
            __builtin_amdgcn_sched_barrier(0);
            __builtin_amdgcn_s_barrier();
            __builtin_amdgcn_sched_barrier(0);
        }
    }
    #undef STAGE128

    if (dom) bias += (*dom) * biasStride;
    const int colb = col0 + wc * 64 + lr;
    const int rowb = row0 + wr * 64 + lk * 4;
    float bj[4];
    #pragma unroll
    for (int j = 0; j < 4; ++j) bj[j] = bias[colb + j * 16];

    #pragma unroll
    for (int i = 0; i < 4; ++i) {
        #pragma unroll
        for (int r = 0; r < 4; ++r) {
            const size_t row = rowb + i * 16 + r;
            #pragma unroll
            for (int j = 0; j < 4; ++j) {
                float x = acc[i][j][r] + bj[j];
                if (ACT == 1)      x = fmaxf(x, 0.f);
                else if (ACT == 2) x = (x > 0.f) ? x : LEAKS * x;
                const size_t idx = row * (size_t)ldc + cc0 + colb + j * 16;
                if (OUT_F32) ((float*)Cp)[idx] = x;
                else         ((unsigned short*)Cp)[idx] = f2bf(x);
            }
        }
    }
}

// ---------------------------------------------------------------------------
// BatchNorm stats + heads — unchanged (proven).
// ---------------------------------------------------------------------------
__global__ __launch_bounds__(256) void bn_stats_a(
    const float* __restrict__ X, float* __restrict__ psum, float* __restrict__ pss)
{
    const int c  = blockIdx.x * 256 + threadIdx.x;
    const int rb = blockIdx.y;
    float s = 0.f, ss = 0.f;
    const int r0 = rb * 256;
    for (int r = r0; r < r0 + 256; ++r) {
        float v = X[(size_t)r * XW + c];
        s += v; ss = fmaf(v, v, ss);
    }
    psum[rb * XW + c] = s;
    pss [rb * XW + c] = ss;
}

__global__ __launch_bounds__(256) void bn_stats_b(
    const float* __restrict__ psum, const float* __restrict__ pss,
    const float* __restrict__ gamma, const float* __restrict__ beta,
    float* __restrict__ scale, float* __restrict__ shift)
{
    const int c = blockIdx.x * 256 + threadIdx.x;
    float s = 0.f, ss = 0.f;
    for (int rb = 0; rb < 32; ++rb) { s += psum[rb * XW + c]; ss += pss[rb * XW + c]; }
    const float inv = 1.f / (float)BQ;
    const float mean = s * inv;
    const float var  = ss * inv - mean * mean;
    const float sc = gamma[c] * rsqrtf(var + BN_EPS);
    scale[c] = sc;
    shift[c] = beta[c] - mean * sc;
}

__global__ __launch_bounds__(256) void head_kernel(
    const float* __restrict__ X, const float* __restrict__ scale,
    const float* __restrict__ shift, const int* __restrict__ tt,
    const float* __restrict__ Wh1, const float* __restrict__ bh1,
    const float* __restrict__ Wh2, const float* __restrict__ bh2,
    const float* __restrict__ Wh3, const float* __restrict__ bh3,
    float* __restrict__ out)
{
    __shared__ float xs[4][XW];
    __shared__ float y1[4][H1N];
    __shared__ float y2[4][H2N + 2];

    const int t = threadIdx.x;
    const int w = t >> 6;
    const int l = t & 63;
    const int s = blockIdx.x * 4 + w;
    const int d = tt[s];

    #pragma unroll 4
    for (int i = 0; i < XW / 64; ++i) {
        const int c = i * 64 + l;
        xs[w][c] = fmaf(X[(size_t)s * XW + c], scale[c], shift[c]);
    }
    __syncthreads();

    if (l < H1N) {
        const float* W1 = Wh1 + (size_t)d * XW * H1N;
        float acc = bh1[d * H1N + l];
        #pragma unroll 8
        for (int c = 0; c < XW; ++c)
            acc = fmaf(xs[w][c], W1[c * H1N + l], acc);
        y1[w][l] = fmaxf(acc, 0.f);
    }
    __syncthreads();

    if (l < H2N) {
        const float* W2 = Wh2 + (size_t)d * H1N * H2N;
        float acc = bh2[d * H2N + l];
        #pragma unroll
        for (int c = 0; c < H1N; ++c)
            acc = fmaf(y1[w][c], W2[c * H2N + l], acc);
        y2[w][l] = fmaxf(acc, 0.f);
    }
    __syncthreads();

    if (l < NWAY) {
        const float* W3 = Wh3 + (size_t)d * H2N * NWAY;
        float acc = bh3[d * NWAY + l];
        #pragma unroll
        for (int c = 0; c < H2N; ++c)
            acc = fmaf(y2[w][c], W3[c * NWAY + l], acc);
        out[(size_t)s * NWAY + l] = acc;
    }
}

// ---------------------------------------------------------------------------
extern "C" void kernel_launch(void* const* d_in, const int* in_sizes, int n_in,
                              void* d_out, int out_size, void* d_ws, size_t ws_size,
                              hipStream_t stream)
{
    const float* x_s   = (const float*)d_in[0];
    const float* x_p   = (const float*)d_in[1];
    const int*   tt    = (const int*)  d_in[2];
    const int*   dom   = (const int*)  d_in[3];
    const float* W_in  = (const float*)d_in[4];
    const float* b_in  = (const float*)d_in[5];
    const float* W_hid = (const float*)d_in[6];
    const float* b_hid = (const float*)d_in[7];
    const float* W_out = (const float*)d_in[8];
    const float* b_out = (const float*)d_in[9];
    const float* Wp    = (const float*)d_in[10];
    const float* bp    = (const float*)d_in[11];
    const float* gamma = (const float*)d_in[12];
    const float* beta  = (const float*)d_in[13];
    const float* Wh1   = (const float*)d_in[14];
    const float* bh1   = (const float*)d_in[15];
    const float* Wh2   = (const float*)d_in[16];
    const float* bh2   = (const float*)d_in[17];
    const float* Wh3   = (const float*)d_in[18];
    const float* bh3   = (const float*)d_in[19];
    float* out = (float*)d_out;

    const dim3 blk(256);
    char* w = (char*)d_ws;

    const size_t FAST_NEED = 470810624ull;

    if (ws_size >= FAST_NEED) {
        unsigned short* xb    = (unsigned short*)w;                    // 192M
        unsigned short* WinT  = (unsigned short*)(w + 201326592);      // 96M region
        unsigned short* WoutT = (unsigned short*)(w + 201326592);      //  8M
        unsigned short* WpT   = (unsigned short*)(w + 209715200);      // 24M
        unsigned short* actA  = (unsigned short*)(w + 301989888);      // 64M
        unsigned short* actB  = (unsigned short*)(w + 369098752);      // 64M
        float*          X     = (float*)(w + 369098752);               // aliases actB
        unsigned short* WhidT = (unsigned short*)(w + 436207616);      // 32M
        float*          psum  = (float*)(w + 469762048);
        float*          pss   = psum + 32 * XW;
        float*          scale = pss  + 32 * XW;
        float*          shift = scale + XW;

        cvt_bf16<<<dim3(2048), blk, 0, stream>>>(x_s, xb, (long long)BQ * FIN / 8);
        transpose_cvt<<<dim3(SUN/64,  FIN/64), blk, 0, stream>>>(W_in,  WinT,  FIN, SUN,  nullptr);
        transpose_cvt<<<dim3(SUN/64,  SUN/64), blk, 0, stream>>>(W_hid, WhidT, SUN, SUN,  nullptr);

        // GEMM1 — proven DEPTH=2 (K=12288 -> NT=192)
        gemm256_8ph<2><<<dim3(512), dim3(512), 0, stream>>>(xb, WinT, b_in, actA, BQ, SUN, FIN);

        transpose_cvt<<<dim3(HIDN/64, SUN/64), blk, 0, stream>>>(W_out, WoutT, SUN, HIDN, nullptr);
        transpose_cvt<<<dim3(HIDN/64, FIN/64), blk, 0, stream>>>(Wp,    WpT,   FIN, HIDN, dom);
        cvt_bf16<<<dim3(2048), blk, 0, stream>>>(x_p, xb, (long long)BQ * FIN / 8);

        // hidden layers A/B: DEPTH=3, DEPTH=2, DEPTH=3, DEPTH=2
        gemm256_8ph<3><<<dim3(512), dim3(512), 0, stream>>>(actA, WhidT, b_hid, actB, BQ, SUN, SUN);
        gemm256_8ph<2><<<dim3(512), dim3(512), 0, stream>>>(actB, WhidT, b_hid, actA, BQ, SUN, SUN);
        gemm256_8ph<3><<<dim3(512), dim3(512), 0, stream>>>(actA, WhidT, b_hid, actB, BQ, SUN, SUN);
        gemm256_8ph<2><<<dim3(512), dim3(512), 0, stream>>>(actB, WhidT, b_hid, actA, BQ, SUN, SUN);

        gemm128<true,1><<<dim3(512), blk, 0, stream>>>(
            actA, WoutT, b_out, X, BQ, HIDN, SUN, XW, 0, nullptr, 0);
        gemm128<true,2><<<dim3(512), blk, 0, stream>>>(
            xb, WpT, bp, X, BQ, HIDN, FIN, XW, HIDN, dom, HIDN);

        bn_stats_a<<<dim3(XW/256, 32), blk, 0, stream>>>(X, psum, pss);
        bn_stats_b<<<dim3(XW/256),     blk, 0, stream>>>(psum, pss, gamma, beta, scale, shift);
        head_kernel<<<dim3(BQ/4), blk, 0, stream>>>(X, scale, shift, tt,
                                                    Wh1, bh1, Wh2, bh2, Wh3, bh3, out);
        return;
    }

    // ---------------- fallback: 256 MiB path ----------------
    unsigned short* actA  = (unsigned short*)w;
    unsigned short* actB  = (unsigned short*)(w + 67108864);
    float*          X     = (float*)(w + 67108864);
    unsigned short* WinT  = (unsigned short*)(w + 134217728);
    unsigned short* WoutT = (unsigned short*)(w + 134217728);
    unsigned short* WpT   = (unsigned short*)(w + 142606336);
    float*          psum  = (float*)(w + 167772160);
    float*          pss   = psum + 32 * XW;
    float*          scale = pss  + 32 * XW;
    float*          shift = scale + XW;
    unsigned short* WhidT = (unsigned short*)(w + 234881024);

    transpose_cvt<<<dim3(SUN/64,  FIN/64), blk, 0, stream>>>(W_in,  WinT,  FIN, SUN,  nullptr);
    transpose_cvt<<<dim3(SUN/64,  SUN/64), blk, 0, stream>>>(W_hid, WhidT, SUN, SUN,  nullptr);

    gemm_mfma<true,false,1><<<dim3(2048), blk, 0, stream>>>(
        x_s, WinT, b_in, actA, BQ, SUN, FIN, SUN, 0, nullptr, 0);

    transpose_cvt<<<dim3(HIDN/64, SUN/64), blk, 0, stream>>>(W_out, WoutT, SUN, HIDN, nullptr);
    transpose_cvt<<<dim3(HIDN/64, FIN/64), blk, 0, stream>>>(Wp,    WpT,   FIN, HIDN, dom);

    gemm256<<<dim3(512), dim3(512), 0, stream>>>(actA, WhidT, b_hid, actB, BQ, SUN, SUN);
    gemm256<<<dim3(512), dim3(512), 0, stream>>>(actB, WhidT, b_hid, actA, BQ, SUN, SUN);
    gemm256<<<dim3(512), dim3(512), 0, stream>>>(actA, WhidT, b_hid, actB, BQ, SUN, SUN);
    gemm256<<<dim3(512), dim3(512), 0, stream>>>(actB, WhidT, b_hid, actA, BQ, SUN, SUN);

    gemm128<true,1><<<dim3(512), blk, 0, stream>>>(
        actA, WoutT, b_out, X, BQ, HIDN, SUN, XW, 0, nullptr, 0);
    gemm_mfma<true,true,2><<<dim3(512), blk, 0, stream>>>(
        x_p, WpT, bp, X, BQ, HIDN, FIN, XW, HIDN, dom, HIDN);

    bn_stats_a<<<dim3(XW/256, 32), blk, 0, stream>>>(X, psum, pss);
    bn_stats_b<<<dim3(XW/256),     blk, 0, stream>>>(psum, pss, gamma, beta, scale, shift);
    head_kernel<<<dim3(BQ/4), blk, 0, stream>>>(X, scale, shift, tt,
                                                Wh1, bh1, Wh2, bh2, Wh3, bh3, out);
}

// Round 14
// 2368.862 us; speedup vs baseline: 1.2910x; 1.0060x over previous
//
#include <hip/hip_runtime.h>
#include <hip/hip_bf16.h>

// Problem constants
#define BQ    8192
#define FIN   12288
#define SUN   4096
#define HIDN  1024
#define XW    2048
#define H1N   28
#define H2N   14
#define NWAY  5
#define BN_EPS 1e-5f
#define LEAKS 0.001f

typedef __bf16 bf16x8 __attribute__((ext_vector_type(8)));
typedef float  f32x4  __attribute__((ext_vector_type(4)));
typedef unsigned short ushort8 __attribute__((ext_vector_type(8)));

__device__ __forceinline__ unsigned short f2bf(float f) {
    unsigned u = __float_as_uint(f);
    unsigned r = u + 0x7fffu + ((u >> 16) & 1u);   // RNE
    return (unsigned short)(r >> 16);
}

__device__ __forceinline__ ushort8 cvt8(const float4 a, const float4 b) {
    union { __bf16 h[8]; ushort8 u; } r;
    r.h[0] = (__bf16)a.x; r.h[1] = (__bf16)a.y;
    r.h[2] = (__bf16)a.z; r.h[3] = (__bf16)a.w;
    r.h[4] = (__bf16)b.x; r.h[5] = (__bf16)b.y;
    r.h[6] = (__bf16)b.z; r.h[7] = (__bf16)b.w;
    return r.u;
}

#define TO_LDS(p) ((__attribute__((address_space(3))) void*)(p))
#define TO_GLB(p) ((const __attribute__((address_space(1))) void*)(p))

// ---------------------------------------------------------------------------
__global__ __launch_bounds__(256) void cvt_bf16(
    const float* __restrict__ in, unsigned short* __restrict__ out, long long n8)
{
    const long long idx = (long long)blockIdx.x * 256 + threadIdx.x;
    const long long stride = (long long)gridDim.x * 256;
    for (long long i = idx; i < n8; i += stride) {
        const float4 a = ((const float4*)in)[2 * i];
        const float4 b = ((const float4*)in)[2 * i + 1];
        ((ushort8*)out)[i] = cvt8(a, b);
    }
}

// ---------------------------------------------------------------------------
__global__ __launch_bounds__(256) void transpose_cvt(
    const float* __restrict__ in, unsigned short* __restrict__ out,
    int R, int Cc, const int* __restrict__ dom)
{
    if (dom) in += (size_t)(*dom) * (size_t)R * (size_t)Cc;
    __shared__ float tile[64][65];
    const int t  = threadIdx.x;
    const int tr = t >> 4;
    const int tc = t & 15;
    const int c0 = blockIdx.x * 64;
    const int r0 = blockIdx.y * 64;

    #pragma unroll
    for (int q = 0; q < 4; ++q) {
        const int r = r0 + tr + q * 16;
        const float4 v = *(const float4*)&in[(size_t)r * Cc + c0 + tc * 4];
        tile[tc*4+0][tr + q*16] = v.x;
        tile[tc*4+1][tr + q*16] = v.y;
        tile[tc*4+2][tr + q*16] = v.z;
        tile[tc*4+3][tr + q*16] = v.w;
    }
    __syncthreads();
    #pragma unroll
    for (int q = 0; q < 4; ++q) {
        const int c = c0 + tr + q * 16;
        ushort4 o;
        o.x = f2bf(tile[tr + q*16][tc*4+0]);
        o.y = f2bf(tile[tr + q*16][tc*4+1]);
        o.z = f2bf(tile[tr + q*16][tc*4+2]);
        o.w = f2bf(tile[tr + q*16][tc*4+3]);
        *(ushort4*)&out[(size_t)c * R + r0 + tc * 4] = o;
    }
}

// ---------------------------------------------------------------------------
// m97-structure bf16 MFMA GEMM (128x128, 2-barrier) — fp32-A fallback only.
// ---------------------------------------------------------------------------
template<bool A_F32, bool OUT_F32, int ACT>
__global__ __launch_bounds__(256) void gemm_mfma(
    const void* __restrict__ Ap, const unsigned short* __restrict__ Bt,
    const float* __restrict__ bias, void* __restrict__ Cp,
    int M, int N, int K, int ldc, int cc0,
    const int* __restrict__ dom, int biasStride)
{
    __shared__ alignas(16) unsigned short As[128 * 32];
    __shared__ alignas(16) unsigned short Bs[128 * 32];

    const int nbx = N >> 7;
    int wg = blockIdx.x;
    const int nwg = gridDim.x;
    if ((nwg & 7) == 0) {
        const int cpx = nwg >> 3;
        wg = (wg & 7) * cpx + (wg >> 3);
    }
    const int bx = wg % nbx, by = wg / nbx;
    const int row0 = by << 7, col0 = bx << 7;

    const int t  = threadIdx.x;
    const int w  = t >> 6;
    const int l  = t & 63;
    const int wr = w >> 1, wc = w & 1;
    const int lr = l & 15, lk = l >> 4;
    const int rsw = (lr >> 1) & 3;

    f32x4 acc[4][4];
    #pragma unroll
    for (int i = 0; i < 4; ++i)
        #pragma unroll
        for (int j = 0; j < 4; ++j)
            acc[i][j] = (f32x4)(0.f);

    const int srow = l >> 2;
    const int skb  = (((l & 3) ^ ((l >> 3) & 3)) * 16);
    const float* Af = (const float*)Ap;
    const unsigned short* Ab = (const unsigned short*)Ap;

    for (int k0 = 0; k0 < K; k0 += 32) {
        __syncthreads();

        #pragma unroll
        for (int c = 0; c < 2; ++c) {
            const int inst = w * 2 + c;
            const int row  = inst * 16 + srow;
            const char* src = (const char*)Bt +
                (((size_t)(col0 + row) * K + k0) * 2 + skb);
            char* dst = (char*)Bs + inst * 1024;
            __builtin_amdgcn_global_load_lds(TO_GLB(src), TO_LDS(dst), 16, 0, 0);
        }
        if (!A_F32) {
            #pragma unroll
            for (int c = 0; c < 2; ++c) {
                const int inst = w * 2 + c;
                const int row  = inst * 16 + srow;
                const char* src = (const char*)Ab +
                    (((size_t)(row0 + row) * K + k0) * 2 + skb);
                char* dst = (char*)As + inst * 1024;
                __builtin_amdgcn_global_load_lds(TO_GLB(src), TO_LDS(dst), 16, 0, 0);
            }
        } else {
            #pragma unroll
            for (int c = 0; c < 2; ++c) {
                const int ci  = t + 256 * c;
                const int row = ci >> 2;
                const int ko  = (((ci & 3) ^ ((ci >> 3) & 3)) * 8);
                const float* s = Af + (size_t)(row0 + row) * K + k0 + ko;
                const float4 v0 = *(const float4*)s;
                const float4 v1 = *(const float4*)(s + 4);
                *(ushort8*)&As[ci * 8] = cvt8(v0, v1);
            }
        }
        __syncthreads();

        bf16x8 af[4], bfv[4];
        #pragma unroll
        for (int i = 0; i < 4; ++i)
            af[i]  = *(const bf16x8*)&As[(wr*64 + i*16 + lr) * 32 + (lk ^ rsw) * 8];
        #pragma unroll
        for (int j = 0; j < 4; ++j)
            bfv[j] = *(const bf16x8*)&Bs[(wc*64 + j*16 + lr) * 32 + (lk ^ rsw) * 8];
        #pragma unroll
        for (int i = 0; i < 4; ++i)
            #pragma unroll
            for (int j = 0; j < 4; ++j)
                acc[i][j] = __builtin_amdgcn_mfma_f32_16x16x32_bf16(
                    af[i], bfv[j], acc[i][j], 0, 0, 0);
    }

    if (dom) bias += (*dom) * biasStride;
    const int colb = col0 + wc * 64 + lr;
    const int rowb = row0 + wr * 64 + lk * 4;
    float bj[4];
    #pragma unroll
    for (int j = 0; j < 4; ++j) bj[j] = bias[colb + j * 16];

    #pragma unroll
    for (int i = 0; i < 4; ++i) {
        #pragma unroll
        for (int r = 0; r < 4; ++r) {
            const size_t row = rowb + i * 16 + r;
            #pragma unroll
            for (int j = 0; j < 4; ++j) {
                float x = acc[i][j][r] + bj[j];
                if (ACT == 1)      x = fmaxf(x, 0.f);
                else if (ACT == 2) x = (x > 0.f) ? x : LEAKS * x;
                const size_t idx = row * (size_t)ldc + cc0 + colb + j * 16;
                if (OUT_F32) ((float*)Cp)[idx] = x;
                else         ((unsigned short*)Cp)[idx] = f2bf(x);
            }
        }
    }
}

// ---------------------------------------------------------------------------
// gemm256 (v1): kept for fallback path only.
// ---------------------------------------------------------------------------
__global__ __launch_bounds__(512, 2) void gemm256(
    const unsigned short* __restrict__ A, const unsigned short* __restrict__ Bt,
    const float* __restrict__ bias, unsigned short* __restrict__ C,
    int M, int N, int K)
{
    __shared__ alignas(16) unsigned short lds[3][2][256 * 32];  // 96 KiB

    const int nbx = N >> 8;
    int wg = blockIdx.x;
    const int nwg = gridDim.x;
    if ((nwg & 7) == 0) {
        const int cpx = nwg >> 3;
        wg = (wg & 7) * cpx + (wg >> 3);
    }
    const int bx = wg % nbx, by = wg / nbx;
    const int row0 = by << 8, col0 = bx << 8;

    const int t  = threadIdx.x;
    const int w  = t >> 6, l = t & 63;
    const int wr = w >> 2, wc = w & 3;
    const int lr = l & 15, lk = l >> 4;
    const int rsw = (lr >> 1) & 3;
    const int srow = l >> 2;
    const int skel = ((l & 3) ^ ((l >> 3) & 3)) * 8;

    f32x4 acc[8][4];
    #pragma unroll
    for (int i = 0; i < 8; ++i)
        #pragma unroll
        for (int j = 0; j < 4; ++j)
            acc[i][j] = (f32x4)(0.f);

    const int NT = K >> 5;

    #define STAGE256(tile_)  do {                                            \
        const int k0_  = (tile_) << 5;                                       \
        const int buf_ = (tile_) % 3;                                        \
        _Pragma("unroll")                                                    \
        for (int s_ = 0; s_ < 2; ++s_) {                                     \
            const int c_   = w * 2 + s_;                                     \
            const int row_ = c_ * 16 + srow;                                 \
            __builtin_amdgcn_global_load_lds(                                \
                TO_GLB(A + (size_t)(row0 + row_) * K + k0_ + skel),          \
                TO_LDS((char*)&lds[buf_][0][0] + c_ * 1024), 16, 0, 0);      \
            __builtin_amdgcn_global_load_lds(                                \
                TO_GLB(Bt + (size_t)(col0 + row_) * K + k0_ + skel),         \
                TO_LDS((char*)&lds[buf_][1][0] + c_ * 1024), 16, 0, 0);      \
        }                                                                    \
    } while (0)

    STAGE256(0);
    if (NT > 1) {
        STAGE256(1);
        asm volatile("s_waitcnt vmcnt(4)" ::: "memory");
    } else {
        asm volatile("s_waitcnt vmcnt(0)" ::: "memory");
    }
    __builtin_amdgcn_sched_barrier(0);
    __builtin_amdgcn_s_barrier();
    __builtin_amdgcn_sched_barrier(0);

    for (int tt = 0; tt < NT; ++tt) {
        const int buf = tt % 3;
        if (tt + 2 < NT) STAGE256(tt + 2);
        __builtin_amdgcn_sched_barrier(0);

        bf16x8 af[8], bfv[4];
        #pragma unroll
        for (int i = 0; i < 8; ++i)
            af[i]  = *(const bf16x8*)&lds[buf][0][(wr*128 + i*16 + lr) * 32 + (lk ^ rsw) * 8];
        #pragma unroll
        for (int j = 0; j < 4; ++j)
            bfv[j] = *(const bf16x8*)&lds[buf][1][(wc*64 + j*16 + lr) * 32 + (lk ^ rsw) * 8];

        __builtin_amdgcn_s_setprio(1);
        #pragma unroll
        for (int j = 0; j < 4; ++j)
            #pragma unroll
            for (int i = 0; i < 8; ++i)
                acc[i][j] = __builtin_amdgcn_mfma_f32_16x16x32_bf16(
                    af[i], bfv[j], acc[i][j], 0, 0, 0);
        __builtin_amdgcn_s_setprio(0);

        if (tt + 1 < NT) {
            if (tt + 2 < NT) asm volatile("s_waitcnt vmcnt(4)" ::: "memory");
            else             asm volatile("s_waitcnt vmcnt(0)" ::: "memory");
            __builtin_amdgcn_sched_barrier(0);
            __builtin_amdgcn_s_barrier();
            __builtin_amdgcn_sched_barrier(0);
        }
    }
    #undef STAGE256

    const int colb = col0 + wc * 64 + lr;
    const int rowb = row0 + wr * 128 + lk * 4;
    float bj[4];
    #pragma unroll
    for (int j = 0; j < 4; ++j) bj[j] = bias[colb + j * 16];

    #pragma unroll
    for (int i = 0; i < 8; ++i) {
        #pragma unroll
        for (int r = 0; r < 4; ++r) {
            const size_t row = rowb + i * 16 + r;
            #pragma unroll
            for (int j = 0; j < 4; ++j) {
                float x = fmaxf(acc[i][j][r] + bj[j], 0.f);
                C[row * (size_t)N + colb + j * 16] = f2bf(x);
            }
        }
    }
}

// ---------------------------------------------------------------------------
// gemm256_8ph — 8-phase schedule (DEPTH=2, R11/R12-proven).
// LEAN=false: 2 barriers/phase (SYNC_IN barrier + PH_END)  [proven]
// LEAN=true:  1 barrier/phase (PH_END only)                [experiment]
// LEAN ledger: PH_END bounds wave drift to 1 phase. Stage in phase p targets
// a region whose readers' ds_reads delivered before their MFMA in phase
// <= p-2, hence before PH_END(p-2) <= PH_END(p-1); the stage issues after
// PH_END(p-1) -> WAR safe. RAW: per-wave vmcnt at ph4/ph8 precedes PH_END
// there; all waves' loads landed before any wave proceeds. lgkmcnt(0) is a
// per-wave wait (no barrier needed). Accumulation k-ascending, identical for
// both variants -> bit-identical output (absmax canary 0.0005531311).
// Requires M,N % 256 == 0, K % 128 == 0.
// ---------------------------------------------------------------------------
template<bool LEAN>
__global__ __launch_bounds__(512, 2) void gemm256_8ph(
    const unsigned short* __restrict__ A, const unsigned short* __restrict__ Bt,
    const float* __restrict__ bias, unsigned short* __restrict__ C,
    int M, int N, int K)
{
    __shared__ alignas(16) unsigned short lds[2][2][2][128 * 64];  // 128 KiB

    const int nbx = N >> 8;
    int wg = blockIdx.x;
    const int nwg = gridDim.x;
    if ((nwg & 7) == 0) { const int cpx = nwg >> 3; wg = (wg & 7) * cpx + (wg >> 3); }
    const int bx = wg % nbx, by = wg / nbx;
    const int row0 = by << 8, col0 = bx << 8;

    const int t = threadIdx.x;
    const int w = t >> 6, l = t & 63;
    const int wr = w >> 2, wc = w & 3;
    const int lr = l & 15, lk = l >> 4;

    f32x4 acc[8][4];
    #pragma unroll
    for (int i = 0; i < 8; ++i)
        #pragma unroll
        for (int j = 0; j < 4; ++j) acc[i][j] = (f32x4)(0.f);

    const int NT = K >> 6;     // K-tiles of 64 (even; >=2)
    const int NI = NT >> 1;

    #define STG(mat_, kt_, h_) do {                                              \
        const unsigned short* gb_ = (mat_) ? Bt : A;                              \
        const int gr0_ = (mat_) ? col0 : row0;                                    \
        _Pragma("unroll")                                                         \
        for (int s_ = 0; s_ < 2; ++s_) {                                          \
            const int c_   = s_ * 8 + w;                                          \
            const int row_ = c_ * 8 + (l >> 3);                                   \
            const int g_   = (l & 7) ^ (row_ & 7);                                \
            __builtin_amdgcn_global_load_lds(                                     \
                TO_GLB(gb_ + (size_t)(gr0_ + (h_) * 128 + row_) * K + (kt_) * 64 + g_ * 8), \
                TO_LDS((char*)&lds[mat_][(kt_) & 1][h_][0] + c_ * 1024), 16, 0, 0);\
        } } while (0)

    #define RD_A(dst_, buf_, qi_) do {                                            \
        _Pragma("unroll")                                                         \
        for (int ks_ = 0; ks_ < 2; ++ks_)                                         \
        _Pragma("unroll")                                                         \
        for (int ii_ = 0; ii_ < 4; ++ii_) {                                       \
            const int rh_ = wr * 64 + ii_ * 16 + lr;                              \
            dst_[ks_][ii_] = *(const bf16x8*)                                     \
                &lds[0][buf_][qi_][rh_ * 64 + (((ks_ * 4 + lk) ^ (rh_ & 7)) << 3)]; \
        } } while (0)

    #define RD_B(dst_, buf_, qj_) do {                                            \
        _Pragma("unroll")                                                         \
        for (int ks_ = 0; ks_ < 2; ++ks_)                                         \
        _Pragma("unroll")                                                         \
        for (int jj_ = 0; jj_ < 2; ++jj_) {                                       \
            const int rh_ = wc * 32 + jj_ * 16 + lr;                              \
            dst_[ks_][jj_] = *(const bf16x8*)                                     \
                &lds[1][buf_][qj_][rh_ * 64 + (((ks_ * 4 + lk) ^ (rh_ & 7)) << 3)]; \
        } } while (0)

    #define SYNC_IN() do {                                                        \
        __builtin_amdgcn_sched_barrier(0);                                        \
        if (!LEAN) __builtin_amdgcn_s_barrier();                                  \
        asm volatile("s_waitcnt lgkmcnt(0)" ::: "memory");                        \
        __builtin_amdgcn_sched_barrier(0); } while (0)

    #define MFMA16(aa_, bb_, qi_, qj_) do {                                       \
        __builtin_amdgcn_s_setprio(1);                                            \
        _Pragma("unroll")                                                         \
        for (int ks_ = 0; ks_ < 2; ++ks_)                                         \
        _Pragma("unroll")                                                         \
        for (int jj_ = 0; jj_ < 2; ++jj_)                                         \
        _Pragma("unroll")                                                         \
        for (int ii_ = 0; ii_ < 4; ++ii_)                                         \
            acc[(qi_)*4+ii_][(qj_)*2+jj_] = __builtin_amdgcn_mfma_f32_16x16x32_bf16( \
                aa_[ks_][ii_], bb_[ks_][jj_], acc[(qi_)*4+ii_][(qj_)*2+jj_], 0, 0, 0); \
        __builtin_amdgcn_s_setprio(0); } while (0)

    #define PH_END() do {                                                         \
        __builtin_amdgcn_sched_barrier(0);                                        \
        __builtin_amdgcn_s_barrier(); } while (0)

    // prologue: t0 full + t1.A0/B0 (6 halves); retire t0 (keep 4 loads)
    STG(0, 0, 0); STG(0, 0, 1); STG(1, 0, 0); STG(1, 0, 1);
    STG(0, 1, 0); STG(1, 1, 0);
    asm volatile("s_waitcnt vmcnt(4)" ::: "memory");
    __builtin_amdgcn_sched_barrier(0);
    __builtin_amdgcn_s_barrier();
    __builtin_amdgcn_sched_barrier(0);

    for (int m = 0; m < NI; ++m) {
        const int t1 = 2 * m + 1, u0 = 2 * m + 2, u1 = 2 * m + 3;
        const bool last = (m == NI - 1);
        bf16x8 a_[2][4], b0_[2][2], b1_[2][2];

        // ph1: t0 q(0,0)
        RD_A(a_, 0, 0); RD_B(b0_, 0, 0);
        STG(0, t1, 1);
        SYNC_IN(); MFMA16(a_, b0_, 0, 0); PH_END();
        // ph2: t0 q(0,1)
        RD_B(b1_, 0, 1);
        STG(1, t1, 1);
        SYNC_IN(); MFMA16(a_, b1_, 0, 1); PH_END();
        // ph3: t0 q(1,0)
        RD_A(a_, 0, 1);
        if (u0 < NT) STG(0, u0, 0);
        SYNC_IN(); MFMA16(a_, b0_, 1, 0); PH_END();
        // ph4: t0 q(1,1) + K-tile wait
        if (u0 < NT) STG(1, u0, 0);
        SYNC_IN(); MFMA16(a_, b1_, 1, 1);
        if (last) asm volatile("s_waitcnt vmcnt(0)" ::: "memory");
        else      asm volatile("s_waitcnt vmcnt(4)" ::: "memory");
        PH_END();
        // ph5: t1 q(0,0)
        RD_A(a_, 1, 0); RD_B(b0_, 1, 0);
        if (u0 < NT) STG(0, u0, 1);
        SYNC_IN(); MFMA16(a_, b0_, 0, 0); PH_END();
        // ph6: t1 q(0,1)
        RD_B(b1_, 1, 1);
        if (u0 < NT) STG(1, u0, 1);
        SYNC_IN(); MFMA16(a_, b1_, 0, 1); PH_END();
        // ph7: t1 q(1,0)
        RD_A(a_, 1, 1);
        if (u1 < NT) STG(0, u1, 0);
        SYNC_IN(); MFMA16(a_, b0_, 1, 0); PH_END();
        // ph8: t1 q(1,1) + K-tile wait
        if (u1 < NT) STG(1, u1, 0);
        SYNC_IN(); MFMA16(a_, b1_, 1, 1);
        if (!last) asm volatile("s_waitcnt vmcnt(4)" ::: "memory");
        PH_END();
    }
    #undef STG
    #undef RD_A
    #undef RD_B
    #undef SYNC_IN
    #undef MFMA16
    #undef PH_END

    const int colb = col0 + wc * 32 + lr;
    const int rowb = row0 + wr * 64 + lk * 4;
    float bj[4];
    #pragma unroll
    for (int j = 0; j < 4; ++j)
        bj[j] = bias[colb + (j >> 1) * 128 + (j & 1) * 16];

    #pragma unroll
    for (int i = 0; i < 8; ++i) {
        const int gri = rowb + (i >> 2) * 128 + (i & 3) * 16;
        #pragma unroll
        for (int r = 0; r < 4; ++r) {
            const size_t row = gri + r;
            #pragma unroll
            for (int j = 0; j < 4; ++j) {
                float x = fmaxf(acc[i][j][r] + bj[j], 0.f);
                C[row * (size_t)N + colb + (j >> 1) * 128 + (j & 1) * 16] = f2bf(x);
            }
        }
    }
}

// ---------------------------------------------------------------------------
// gemm128: proven pipeline at 128x128 / 4 waves / 48 KiB. Narrow-N GEMMs 6/7.
// ---------------------------------------------------------------------------
template<bool OUT_F32, int ACT>
__global__ __launch_bounds__(256, 2) void gemm128(
    const unsigned short* __restrict__ A, const unsigned short* __restrict__ Bt,
    const float* __restrict__ bias, void* __restrict__ Cp,
    int M, int N, int K, int ldc, int cc0,
    const int* __restrict__ dom, int biasStride)
{
    __shared__ alignas(16) unsigned short lds[3][2][128 * 32];  // 48 KiB

    const int nbx = N >> 7;
    int wg = blockIdx.x;
    const int nwg = gridDim.x;
    if ((nwg & 7) == 0) {
        const int cpx = nwg >> 3;
        wg = (wg & 7) * cpx + (wg >> 3);
    }
    const int bx = wg % nbx, by = wg / nbx;
    const int row0 = by << 7, col0 = bx << 7;

    const int t  = threadIdx.x;
    const int w  = t >> 6, l = t & 63;
    const int wr = w >> 1, wc = w & 1;
    const int lr = l & 15, lk = l >> 4;
    const int rsw = (lr >> 1) & 3;
    const int srow = l >> 2;
    const int skel = ((l & 3) ^ ((l >> 3) & 3)) * 8;

    f32x4 acc[4][4];
    #pragma unroll
    for (int i = 0; i < 4; ++i)
        #pragma unroll
        for (int j = 0; j < 4; ++j)
            acc[i][j] = (f32x4)(0.f);

    const int NT = K >> 5;

    #define STAGE128(tile_)  do {                                            \
        const int k0_  = (tile_) << 5;                                       \
        const int buf_ = (tile_) % 3;                                        \
        _Pragma("unroll")                                                    \
        for (int s_ = 0; s_ < 2; ++s_) {                                     \
            const int c_   = w * 2 + s_;                                     \
            const int row_ = c_ * 16 + srow;                                 \
            __builtin_amdgcn_global_load_lds(                                \
                TO_GLB(A + (size_t)(row0 + row_) * K + k0_ + skel),          \
                TO_LDS((char*)&lds[buf_][0][0] + c_ * 1024), 16, 0, 0);      \
            __builtin_amdgcn_global_load_lds(                                \
                TO_GLB(Bt + (size_t)(col0 + row_) * K + k0_ + skel),         \
                TO_LDS((char*)&lds[buf_][1][0] + c_ * 1024), 16, 0, 0);      \
        }                                                                    \
    } while (0)

    STAGE128(0);
    if (NT > 1) {
        STAGE128(1);
        asm volatile("s_waitcnt vmcnt(4)" ::: "memory");
    } else {
        asm volatile("s_waitcnt vmcnt(0)" ::: "memory");
    }
    __builtin_amdgcn_sched_barrier(0);
    __builtin_amdgcn_s_barrier();
    __builtin_amdgcn_sched_barrier(0);

    for (int tt = 0; tt < NT; ++tt) {
        const int buf = tt % 3;
        if (tt + 2 < NT) STAGE128(tt + 2);
        __builtin_amdgcn_sched_barrier(0);

        bf16x8 af[4], bfv[4];
        #pragma unroll
        for (int i = 0; i < 4; ++i)
            af[i]  = *(const bf16x8*)&lds[buf][0][(wr*64 + i*16 + lr) * 32 + (lk ^ rsw) * 8];
        #pragma unroll
        for (int j = 0; j < 4; ++j)
            bfv[j] = *(const bf16x8*)&lds[buf][1][(wc*64 + j*16 + lr) * 32 + (lk ^ rsw) * 8];

        #pragma unroll
        for (int j = 0; j < 4; ++j)
            #pragma unroll
            for (int i = 0; i < 4; ++i)
                acc[i][j] = __builtin_amdgcn_mfma_f32_16x16x32_bf16(
                    af[i], bfv[j], acc[i][j], 0, 0, 0);

        if (tt + 1 < NT) {
            if (tt + 2 < NT) asm volatile("s_waitcnt vmcnt(4)" ::: "memory");
            else             asm volatile("s_waitcnt vmcnt(0)" ::: "memory");
            __builtin_amdgcn_sched_barrier(0);
            __builtin_amdgcn_s_barrier();
            __builtin_amdgcn_sched_barrier(0);
        }
    }
    #undef STAGE128

    if (dom) bias += (*dom) * biasStride;
    const int colb = col0 + wc * 64 + lr;
    const int rowb = row0 + wr * 64 + lk * 4;
    float bj[4];
    #pragma unroll
    for (int j = 0; j < 4; ++j) bj[j] = bias[colb + j * 16];

    #pragma unroll
    for (int i = 0; i < 4; ++i) {
        #pragma unroll
        for (int r = 0; r < 4; ++r) {
            const size_t row = rowb + i * 16 + r;
            #pragma unroll
            for (int j = 0; j < 4; ++j) {
                float x = acc[i][j][r] + bj[j];
                if (ACT == 1)      x = fmaxf(x, 0.f);
                else if (ACT == 2) x = (x > 0.f) ? x : LEAKS * x;
                const size_t idx = row * (size_t)ldc + cc0 + colb + j * 16;
                if (OUT_F32) ((float*)Cp)[idx] = x;
                else         ((unsigned short*)Cp)[idx] = f2bf(x);
            }
        }
    }
}

// ---------------------------------------------------------------------------
// BatchNorm stats + heads — unchanged (proven).
// ---------------------------------------------------------------------------
__global__ __launch_bounds__(256) void bn_stats_a(
    const float* __restrict__ X, float* __restrict__ psum, float* __restrict__ pss)
{
    const int c  = blockIdx.x * 256 + threadIdx.x;
    const int rb = blockIdx.y;
    float s = 0.f, ss = 0.f;
    const int r0 = rb * 256;
    for (int r = r0; r < r0 + 256; ++r) {
        float v = X[(size_t)r * XW + c];
        s += v; ss = fmaf(v, v, ss);
    }
    psum[rb * XW + c] = s;
    pss [rb * XW + c] = ss;
}

__global__ __launch_bounds__(256) void bn_stats_b(
    const float* __restrict__ psum, const float* __restrict__ pss,
    const float* __restrict__ gamma, const float* __restrict__ beta,
    float* __restrict__ scale, float* __restrict__ shift)
{
    const int c = blockIdx.x * 256 + threadIdx.x;
    float s = 0.f, ss = 0.f;
    for (int rb = 0; rb < 32; ++rb) { s += psum[rb * XW + c]; ss += pss[rb * XW + c]; }
    const float inv = 1.f / (float)BQ;
    const float mean = s * inv;
    const float var  = ss * inv - mean * mean;
    const float sc = gamma[c] * rsqrtf(var + BN_EPS);
    scale[c] = sc;
    shift[c] = beta[c] - mean * sc;
}

__global__ __launch_bounds__(256) void head_kernel(
    const float* __restrict__ X, const float* __restrict__ scale,
    const float* __restrict__ shift, const int* __restrict__ tt,
    const float* __restrict__ Wh1, const float* __restrict__ bh1,
    const float* __restrict__ Wh2, const float* __restrict__ bh2,
    const float* __restrict__ Wh3, const float* __restrict__ bh3,
    float* __restrict__ out)
{
    __shared__ float xs[4][XW];
    __shared__ float y1[4][H1N];
    __shared__ float y2[4][H2N + 2];

    const int t = threadIdx.x;
    const int w = t >> 6;
    const int l = t & 63;
    const int s = blockIdx.x * 4 + w;
    const int d = tt[s];

    #pragma unroll 4
    for (int i = 0; i < XW / 64; ++i) {
        const int c = i * 64 + l;
        xs[w][c] = fmaf(X[(size_t)s * XW + c], scale[c], shift[c]);
    }
    __syncthreads();

    if (l < H1N) {
        const float* W1 = Wh1 + (size_t)d * XW * H1N;
        float acc = bh1[d * H1N + l];
        #pragma unroll 8
        for (int c = 0; c < XW; ++c)
            acc = fmaf(xs[w][c], W1[c * H1N + l], acc);
        y1[w][l] = fmaxf(acc, 0.f);
    }
    __syncthreads();

    if (l < H2N) {
        const float* W2 = Wh2 + (size_t)d * H1N * H2N;
        float acc = bh2[d * H2N + l];
        #pragma unroll
        for (int c = 0; c < H1N; ++c)
            acc = fmaf(y1[w][c], W2[c * H2N + l], acc);
        y2[w][l] = fmaxf(acc, 0.f);
    }
    __syncthreads();

    if (l < NWAY) {
        const float* W3 = Wh3 + (size_t)d * H2N * NWAY;
        float acc = bh3[d * NWAY + l];
        #pragma unroll
        for (int c = 0; c < H2N; ++c)
            acc = fmaf(y2[w][c], W3[c * NWAY + l], acc);
        out[(size_t)s * NWAY + l] = acc;
    }
}

// ---------------------------------------------------------------------------
extern "C" void kernel_launch(void* const* d_in, const int* in_sizes, int n_in,
                              void* d_out, int out_size, void* d_ws, size_t ws_size,
                              hipStream_t stream)
{
    const float* x_s   = (const float*)d_in[0];
    const float* x_p   = (const float*)d_in[1];
    const int*   tt    = (const int*)  d_in[2];
    const int*   dom   = (const int*)  d_in[3];
    const float* W_in  = (const float*)d_in[4];
    const float* b_in  = (const float*)d_in[5];
    const float* W_hid = (const float*)d_in[6];
    const float* b_hid = (const float*)d_in[7];
    const float* W_out = (const float*)d_in[8];
    const float* b_out = (const float*)d_in[9];
    const float* Wp    = (const float*)d_in[10];
    const float* bp    = (const float*)d_in[11];
    const float* gamma = (const float*)d_in[12];
    const float* beta  = (const float*)d_in[13];
    const float* Wh1   = (const float*)d_in[14];
    const float* bh1   = (const float*)d_in[15];
    const float* Wh2   = (const float*)d_in[16];
    const float* bh2   = (const float*)d_in[17];
    const float* Wh3   = (const float*)d_in[18];
    const float* bh3   = (const float*)d_in[19];
    float* out = (float*)d_out;

    const dim3 blk(256);
    char* w = (char*)d_ws;

    const size_t FAST_NEED = 470810624ull;

    if (ws_size >= FAST_NEED) {
        unsigned short* xb    = (unsigned short*)w;                    // 192M
        unsigned short* WinT  = (unsigned short*)(w + 201326592);      // 96M region
        unsigned short* WoutT = (unsigned short*)(w + 201326592);      //  8M
        unsigned short* WpT   = (unsigned short*)(w + 209715200);      // 24M
        unsigned short* actA  = (unsigned short*)(w + 301989888);      // 64M
        unsigned short* actB  = (unsigned short*)(w + 369098752);      // 64M
        float*          X     = (float*)(w + 369098752);               // aliases actB
        unsigned short* WhidT = (unsigned short*)(w + 436207616);      // 32M
        float*          psum  = (float*)(w + 469762048);
        float*          pss   = psum + 32 * XW;
        float*          scale = pss  + 32 * XW;
        float*          shift = scale + XW;

        cvt_bf16<<<dim3(2048), blk, 0, stream>>>(x_s, xb, (long long)BQ * FIN / 8);
        transpose_cvt<<<dim3(SUN/64,  FIN/64), blk, 0, stream>>>(W_in,  WinT,  FIN, SUN,  nullptr);
        transpose_cvt<<<dim3(SUN/64,  SUN/64), blk, 0, stream>>>(W_hid, WhidT, SUN, SUN,  nullptr);

        // GEMM1 — proven 2-barrier variant
        gemm256_8ph<false><<<dim3(512), dim3(512), 0, stream>>>(xb, WinT, b_in, actA, BQ, SUN, FIN);

        transpose_cvt<<<dim3(HIDN/64, SUN/64), blk, 0, stream>>>(W_out, WoutT, SUN, HIDN, nullptr);
        transpose_cvt<<<dim3(HIDN/64, FIN/64), blk, 0, stream>>>(Wp,    WpT,   FIN, HIDN, dom);
        cvt_bf16<<<dim3(2048), blk, 0, stream>>>(x_p, xb, (long long)BQ * FIN / 8);

        // hidden layers A/B: lean(1-bar), full(2-bar), lean, full
        gemm256_8ph<true ><<<dim3(512), dim3(512), 0, stream>>>(actA, WhidT, b_hid, actB, BQ, SUN, SUN);
        gemm256_8ph<false><<<dim3(512), dim3(512), 0, stream>>>(actB, WhidT, b_hid, actA, BQ, SUN, SUN);
        gemm256_8ph<true ><<<dim3(512), dim3(512), 0, stream>>>(actA, WhidT, b_hid, actB, BQ, SUN, SUN);
        gemm256_8ph<false><<<dim3(512), dim3(512), 0, stream>>>(actB, WhidT, b_hid, actA, BQ, SUN, SUN);

        gemm128<true,1><<<dim3(512), blk, 0, stream>>>(
            actA, WoutT, b_out, X, BQ, HIDN, SUN, XW, 0, nullptr, 0);
        gemm128<true,2><<<dim3(512), blk, 0, stream>>>(
            xb, WpT, bp, X, BQ, HIDN, FIN, XW, HIDN, dom, HIDN);

        bn_stats_a<<<dim3(XW/256, 32), blk, 0, stream>>>(X, psum, pss);
        bn_stats_b<<<dim3(XW/256),     blk, 0, stream>>>(psum, pss, gamma, beta, scale, shift);
        head_kernel<<<dim3(BQ/4), blk, 0, stream>>>(X, scale, shift, tt,
                                                    Wh1, bh1, Wh2, bh2, Wh3, bh3, out);
        return;
    }

    // ---------------- fallback: 256 MiB path ----------------
    unsigned short* actA  = (unsigned short*)w;
    unsigned short* actB  = (unsigned short*)(w + 67108864);
    float*          X     = (float*)(w + 67108864);
    unsigned short* WinT  = (unsigned short*)(w + 134217728);
    unsigned short* WoutT = (unsigned short*)(w + 134217728);
    unsigned short* WpT   = (unsigned short*)(w + 142606336);
    float*          psum  = (float*)(w + 167772160);
    float*          pss   = psum + 32 * XW;
    float*          scale = pss  + 32 * XW;
    float*          shift = scale + XW;
    unsigned short* WhidT = (unsigned short*)(w + 234881024);

    transpose_cvt<<<dim3(SUN/64,  FIN/64), blk, 0, stream>>>(W_in,  WinT,  FIN, SUN,  nullptr);
    transpose_cvt<<<dim3(SUN/64,  SUN/64), blk, 0, stream>>>(W_hid, WhidT, SUN, SUN,  nullptr);

    gemm_mfma<true,false,1><<<dim3(2048), blk, 0, stream>>>(
        x_s, WinT, b_in, actA, BQ, SUN, FIN, SUN, 0, nullptr, 0);

    transpose_cvt<<<dim3(HIDN/64, SUN/64), blk, 0, stream>>>(W_out, WoutT, SUN, HIDN, nullptr);
    transpose_cvt<<<dim3(HIDN/64, FIN/64), blk, 0, stream>>>(Wp,    WpT,   FIN, HIDN, dom);

    gemm256<<<dim3(512), dim3(512), 0, stream>>>(actA, WhidT, b_hid, actB, BQ, SUN, SUN);
    gemm256<<<dim3(512), dim3(512), 0, stream>>>(actB, WhidT, b_hid, actA, BQ, SUN, SUN);
    gemm256<<<dim3(512), dim3(512), 0, stream>>>(actA, WhidT, b_hid, actB, BQ, SUN, SUN);
    gemm256<<<dim3(512), dim3(512), 0, stream>>>(actB, WhidT, b_hid, actA, BQ, SUN, SUN);

    gemm128<true,1><<<dim3(512), blk, 0, stream>>>(
        actA, WoutT, b_out, X, BQ, HIDN, SUN, XW, 0, nullptr, 0);
    gemm_mfma<true,true,2><<<dim3(512), blk, 0, stream>>>(
        x_p, WpT, bp, X, BQ, HIDN, FIN, XW, HIDN, dom, HIDN);

    bn_stats_a<<<dim3(XW/256, 32), blk, 0, stream>>>(X, psum, pss);
    bn_stats_b<<<dim3(XW/256),     blk, 0, stream>>>(psum, pss, gamma, beta, scale, shift);
    head_kernel<<<dim3(BQ/4), blk, 0, stream>>>(X, scale, shift, tt,
                                                Wh1, bh1, Wh2, bh2, Wh3, bh3, out);
}

// Round 15
// 2322.469 us; speedup vs baseline: 1.3168x; 1.0200x over previous
//
#include <hip/hip_runtime.h>
#include <hip/hip_bf16.h>

// Problem constants
#define BQ    8192
#define FIN   12288
#define SUN   4096
#define HIDN  1024
#define XW    2048
#define H1N   28
#define H2N   14
#define NWAY  5
#define BN_EPS 1e-5f
#define LEAKS 0.001f

typedef __bf16 bf16x8 __attribute__((ext_vector_type(8)));
typedef float  f32x4  __attribute__((ext_vector_type(4)));
typedef unsigned short ushort8 __attribute__((ext_vector_type(8)));

__device__ __forceinline__ unsigned short f2bf(float f) {
    unsigned u = __float_as_uint(f);
    unsigned r = u + 0x7fffu + ((u >> 16) & 1u);   // RNE
    return (unsigned short)(r >> 16);
}

__device__ __forceinline__ ushort8 cvt8(const float4 a, const float4 b) {
    union { __bf16 h[8]; ushort8 u; } r;
    r.h[0] = (__bf16)a.x; r.h[1] = (__bf16)a.y;
    r.h[2] = (__bf16)a.z; r.h[3] = (__bf16)a.w;
    r.h[4] = (__bf16)b.x; r.h[5] = (__bf16)b.y;
    r.h[6] = (__bf16)b.z; r.h[7] = (__bf16)b.w;
    return r.u;
}

#define TO_LDS(p) ((__attribute__((address_space(3))) void*)(p))
#define TO_GLB(p) ((const __attribute__((address_space(1))) void*)(p))

// ---------------------------------------------------------------------------
__global__ __launch_bounds__(256) void cvt_bf16(
    const float* __restrict__ in, unsigned short* __restrict__ out, long long n8)
{
    const long long idx = (long long)blockIdx.x * 256 + threadIdx.x;
    const long long stride = (long long)gridDim.x * 256;
    for (long long i = idx; i < n8; i += stride) {
        const float4 a = ((const float4*)in)[2 * i];
        const float4 b = ((const float4*)in)[2 * i + 1];
        ((ushort8*)out)[i] = cvt8(a, b);
    }
}

// ---------------------------------------------------------------------------
__global__ __launch_bounds__(256) void transpose_cvt(
    const float* __restrict__ in, unsigned short* __restrict__ out,
    int R, int Cc, const int* __restrict__ dom)
{
    if (dom) in += (size_t)(*dom) * (size_t)R * (size_t)Cc;
    __shared__ float tile[64][65];
    const int t  = threadIdx.x;
    const int tr = t >> 4;
    const int tc = t & 15;
    const int c0 = blockIdx.x * 64;
    const int r0 = blockIdx.y * 64;

    #pragma unroll
    for (int q = 0; q < 4; ++q) {
        const int r = r0 + tr + q * 16;
        const float4 v = *(const float4*)&in[(size_t)r * Cc + c0 + tc * 4];
        tile[tc*4+0][tr + q*16] = v.x;
        tile[tc*4+1][tr + q*16] = v.y;
        tile[tc*4+2][tr + q*16] = v.z;
        tile[tc*4+3][tr + q*16] = v.w;
    }
    __syncthreads();
    #pragma unroll
    for (int q = 0; q < 4; ++q) {
        const int c = c0 + tr + q * 16;
        ushort4 o;
        o.x = f2bf(tile[tr + q*16][tc*4+0]);
        o.y = f2bf(tile[tr + q*16][tc*4+1]);
        o.z = f2bf(tile[tr + q*16][tc*4+2]);
        o.w = f2bf(tile[tr + q*16][tc*4+3]);
        *(ushort4*)&out[(size_t)c * R + r0 + tc * 4] = o;
    }
}

// ---------------------------------------------------------------------------
// m97-structure bf16 MFMA GEMM (128x128, 2-barrier) — fp32-A fallback only.
// ---------------------------------------------------------------------------
template<bool A_F32, bool OUT_F32, int ACT>
__global__ __launch_bounds__(256) void gemm_mfma(
    const void* __restrict__ Ap, const unsigned short* __restrict__ Bt,
    const float* __restrict__ bias, void* __restrict__ Cp,
    int M, int N, int K, int ldc, int cc0,
    const int* __restrict__ dom, int biasStride)
{
    __shared__ alignas(16) unsigned short As[128 * 32];
    __shared__ alignas(16) unsigned short Bs[128 * 32];

    const int nbx = N >> 7;
    int wg = blockIdx.x;
    const int nwg = gridDim.x;
    if ((nwg & 7) == 0) {
        const int cpx = nwg >> 3;
        wg = (wg & 7) * cpx + (wg >> 3);
    }
    const int bx = wg % nbx, by = wg / nbx;
    const int row0 = by << 7, col0 = bx << 7;

    const int t  = threadIdx.x;
    const int w  = t >> 6;
    const int l  = t & 63;
    const int wr = w >> 1, wc = w & 1;
    const int lr = l & 15, lk = l >> 4;
    const int rsw = (lr >> 1) & 3;

    f32x4 acc[4][4];
    #pragma unroll
    for (int i = 0; i < 4; ++i)
        #pragma unroll
        for (int j = 0; j < 4; ++j)
            acc[i][j] = (f32x4)(0.f);

    const int srow = l >> 2;
    const int skb  = (((l & 3) ^ ((l >> 3) & 3)) * 16);
    const float* Af = (const float*)Ap;
    const unsigned short* Ab = (const unsigned short*)Ap;

    for (int k0 = 0; k0 < K; k0 += 32) {
        __syncthreads();

        #pragma unroll
        for (int c = 0; c < 2; ++c) {
            const int inst = w * 2 + c;
            const int row  = inst * 16 + srow;
            const char* src = (const char*)Bt +
                (((size_t)(col0 + row) * K + k0) * 2 + skb);
            char* dst = (char*)Bs + inst * 1024;
            __builtin_amdgcn_global_load_lds(TO_GLB(src), TO_LDS(dst), 16, 0, 0);
        }
        if (!A_F32) {
            #pragma unroll
            for (int c = 0; c < 2; ++c) {
                const int inst = w * 2 + c;
                const int row  = inst * 16 + srow;
                const char* src = (const char*)Ab +
                    (((size_t)(row0 + row) * K + k0) * 2 + skb);
                char* dst = (char*)As + inst * 1024;
                __builtin_amdgcn_global_load_lds(TO_GLB(src), TO_LDS(dst), 16, 0, 0);
            }
        } else {
            #pragma unroll
            for (int c = 0; c < 2; ++c) {
                const int ci  = t + 256 * c;
                const int row = ci >> 2;
                const int ko  = (((ci & 3) ^ ((ci >> 3) & 3)) * 8);
                const float* s = Af + (size_t)(row0 + row) * K + k0 + ko;
                const float4 v0 = *(const float4*)s;
                const float4 v1 = *(const float4*)(s + 4);
                *(ushort8*)&As[ci * 8] = cvt8(v0, v1);
            }
        }
        __syncthreads();

        bf16x8 af[4], bfv[4];
        #pragma unroll
        for (int i = 0; i < 4; ++i)
            af[i]  = *(const bf16x8*)&As[(wr*64 + i*16 + lr) * 32 + (lk ^ rsw) * 8];
        #pragma unroll
        for (int j = 0; j < 4; ++j)
            bfv[j] = *(const bf16x8*)&Bs[(wc*64 + j*16 + lr) * 32 + (lk ^ rsw) * 8];
        #pragma unroll
        for (int i = 0; i < 4; ++i)
            #pragma unroll
            for (int j = 0; j < 4; ++j)
                acc[i][j] = __builtin_amdgcn_mfma_f32_16x16x32_bf16(
                    af[i], bfv[j], acc[i][j], 0, 0, 0);
    }

    if (dom) bias += (*dom) * biasStride;
    const int colb = col0 + wc * 64 + lr;
    const int rowb = row0 + wr * 64 + lk * 4;
    float bj[4];
    #pragma unroll
    for (int j = 0; j < 4; ++j) bj[j] = bias[colb + j * 16];

    #pragma unroll
    for (int i = 0; i < 4; ++i) {
        #pragma unroll
        for (int r = 0; r < 4; ++r) {
            const size_t row = rowb + i * 16 + r;
            #pragma unroll
            for (int j = 0; j < 4; ++j) {
                float x = acc[i][j][r] + bj[j];
                if (ACT == 1)      x = fmaxf(x, 0.f);
                else if (ACT == 2) x = (x > 0.f) ? x : LEAKS * x;
                const size_t idx = row * (size_t)ldc + cc0 + colb + j * 16;
                if (OUT_F32) ((float*)Cp)[idx] = x;
                else         ((unsigned short*)Cp)[idx] = f2bf(x);
            }
        }
    }
}

// ---------------------------------------------------------------------------
// gemm256 (v1): kept for fallback path only.
// ---------------------------------------------------------------------------
__global__ __launch_bounds__(512, 2) void gemm256(
    const unsigned short* __restrict__ A, const unsigned short* __restrict__ Bt,
    const float* __restrict__ bias, unsigned short* __restrict__ C,
    int M, int N, int K)
{
    __shared__ alignas(16) unsigned short lds[3][2][256 * 32];  // 96 KiB

    const int nbx = N >> 8;
    int wg = blockIdx.x;
    const int nwg = gridDim.x;
    if ((nwg & 7) == 0) {
        const int cpx = nwg >> 3;
        wg = (wg & 7) * cpx + (wg >> 3);
    }
    const int bx = wg % nbx, by = wg / nbx;
    const int row0 = by << 8, col0 = bx << 8;

    const int t  = threadIdx.x;
    const int w  = t >> 6, l = t & 63;
    const int wr = w >> 2, wc = w & 3;
    const int lr = l & 15, lk = l >> 4;
    const int rsw = (lr >> 1) & 3;
    const int srow = l >> 2;
    const int skel = ((l & 3) ^ ((l >> 3) & 3)) * 8;

    f32x4 acc[8][4];
    #pragma unroll
    for (int i = 0; i < 8; ++i)
        #pragma unroll
        for (int j = 0; j < 4; ++j)
            acc[i][j] = (f32x4)(0.f);

    const int NT = K >> 5;

    #define STAGE256(tile_)  do {                                            \
        const int k0_  = (tile_) << 5;                                       \
        const int buf_ = (tile_) % 3;                                        \
        _Pragma("unroll")                                                    \
        for (int s_ = 0; s_ < 2; ++s_) {                                     \
            const int c_   = w * 2 + s_;                                     \
            const int row_ = c_ * 16 + srow;                                 \
            __builtin_amdgcn_global_load_lds(                                \
                TO_GLB(A + (size_t)(row0 + row_) * K + k0_ + skel),          \
                TO_LDS((char*)&lds[buf_][0][0] + c_ * 1024), 16, 0, 0);      \
            __builtin_amdgcn_global_load_lds(                                \
                TO_GLB(Bt + (size_t)(col0 + row_) * K + k0_ + skel),         \
                TO_LDS((char*)&lds[buf_][1][0] + c_ * 1024), 16, 0, 0);      \
        }                                                                    \
    } while (0)

    STAGE256(0);
    if (NT > 1) {
        STAGE256(1);
        asm volatile("s_waitcnt vmcnt(4)" ::: "memory");
    } else {
        asm volatile("s_waitcnt vmcnt(0)" ::: "memory");
    }
    __builtin_amdgcn_sched_barrier(0);
    __builtin_amdgcn_s_barrier();
    __builtin_amdgcn_sched_barrier(0);

    for (int tt = 0; tt < NT; ++tt) {
        const int buf = tt % 3;
        if (tt + 2 < NT) STAGE256(tt + 2);
        __builtin_amdgcn_sched_barrier(0);

        bf16x8 af[8], bfv[4];
        #pragma unroll
        for (int i = 0; i < 8; ++i)
            af[i]  = *(const bf16x8*)&lds[buf][0][(wr*128 + i*16 + lr) * 32 + (lk ^ rsw) * 8];
        #pragma unroll
        for (int j = 0; j < 4; ++j)
            bfv[j] = *(const bf16x8*)&lds[buf][1][(wc*64 + j*16 + lr) * 32 + (lk ^ rsw) * 8];

        __builtin_amdgcn_s_setprio(1);
        #pragma unroll
        for (int j = 0; j < 4; ++j)
            #pragma unroll
            for (int i = 0; i < 8; ++i)
                acc[i][j] = __builtin_amdgcn_mfma_f32_16x16x32_bf16(
                    af[i], bfv[j], acc[i][j], 0, 0, 0);
        __builtin_amdgcn_s_setprio(0);

        if (tt + 1 < NT) {
            if (tt + 2 < NT) asm volatile("s_waitcnt vmcnt(4)" ::: "memory");
            else             asm volatile("s_waitcnt vmcnt(0)" ::: "memory");
            __builtin_amdgcn_sched_barrier(0);
            __builtin_amdgcn_s_barrier();
            __builtin_amdgcn_sched_barrier(0);
        }
    }
    #undef STAGE256

    const int colb = col0 + wc * 64 + lr;
    const int rowb = row0 + wr * 128 + lk * 4;
    float bj[4];
    #pragma unroll
    for (int j = 0; j < 4; ++j) bj[j] = bias[colb + j * 16];

    #pragma unroll
    for (int i = 0; i < 8; ++i) {
        #pragma unroll
        for (int r = 0; r < 4; ++r) {
            const size_t row = rowb + i * 16 + r;
            #pragma unroll
            for (int j = 0; j < 4; ++j) {
                float x = fmaxf(acc[i][j][r] + bj[j], 0.f);
                C[row * (size_t)N + colb + j * 16] = f2bf(x);
            }
        }
    }
}

// ---------------------------------------------------------------------------
// gemm256_8ph — 8-phase schedule.
// MODE 0: 2 barriers/phase + lgkmcnt pin   [R11/R12-proven]
// MODE 1: 1 barrier/phase + lgkmcnt pin    [R14-proven, small win]
// MODE 2: 1 barrier/phase, NO explicit lgkmcnt/sched pins in SYNC_IN —
//         compiler emits fine-grained lgkmcnt(N), interleaving ds_reads with
//         MFMAs (m97 asm evidence; removes m141-style over-pinning).
// Race ledger identical for all modes (PH_END s_barrier placement unchanged;
// memory ops don't cross s_barrier; same-wave read->MFMA deps are
// compiler-tracked). Accumulation k-ascending -> bit-identical output
// (absmax canary 0.0005531311). Requires M,N % 256 == 0, K % 128 == 0.
// ---------------------------------------------------------------------------
template<int MODE>
__global__ __launch_bounds__(512, 2) void gemm256_8ph(
    const unsigned short* __restrict__ A, const unsigned short* __restrict__ Bt,
    const float* __restrict__ bias, unsigned short* __restrict__ C,
    int M, int N, int K)
{
    __shared__ alignas(16) unsigned short lds[2][2][2][128 * 64];  // 128 KiB

    const int nbx = N >> 8;
    int wg = blockIdx.x;
    const int nwg = gridDim.x;
    if ((nwg & 7) == 0) { const int cpx = nwg >> 3; wg = (wg & 7) * cpx + (wg >> 3); }
    const int bx = wg % nbx, by = wg / nbx;
    const int row0 = by << 8, col0 = bx << 8;

    const int t = threadIdx.x;
    const int w = t >> 6, l = t & 63;
    const int wr = w >> 2, wc = w & 3;
    const int lr = l & 15, lk = l >> 4;

    f32x4 acc[8][4];
    #pragma unroll
    for (int i = 0; i < 8; ++i)
        #pragma unroll
        for (int j = 0; j < 4; ++j) acc[i][j] = (f32x4)(0.f);

    const int NT = K >> 6;     // K-tiles of 64 (even; >=2)
    const int NI = NT >> 1;

    #define STG(mat_, kt_, h_) do {                                              \
        const unsigned short* gb_ = (mat_) ? Bt : A;                              \
        const int gr0_ = (mat_) ? col0 : row0;                                    \
        _Pragma("unroll")                                                         \
        for (int s_ = 0; s_ < 2; ++s_) {                                          \
            const int c_   = s_ * 8 + w;                                          \
            const int row_ = c_ * 8 + (l >> 3);                                   \
            const int g_   = (l & 7) ^ (row_ & 7);                                \
            __builtin_amdgcn_global_load_lds(                                     \
                TO_GLB(gb_ + (size_t)(gr0_ + (h_) * 128 + row_) * K + (kt_) * 64 + g_ * 8), \
                TO_LDS((char*)&lds[mat_][(kt_) & 1][h_][0] + c_ * 1024), 16, 0, 0);\
        } } while (0)

    #define RD_A(dst_, buf_, qi_) do {                                            \
        _Pragma("unroll")                                                         \
        for (int ks_ = 0; ks_ < 2; ++ks_)                                         \
        _Pragma("unroll")                                                         \
        for (int ii_ = 0; ii_ < 4; ++ii_) {                                       \
            const int rh_ = wr * 64 + ii_ * 16 + lr;                              \
            dst_[ks_][ii_] = *(const bf16x8*)                                     \
                &lds[0][buf_][qi_][rh_ * 64 + (((ks_ * 4 + lk) ^ (rh_ & 7)) << 3)]; \
        } } while (0)

    #define RD_B(dst_, buf_, qj_) do {                                            \
        _Pragma("unroll")                                                         \
        for (int ks_ = 0; ks_ < 2; ++ks_)                                         \
        _Pragma("unroll")                                                         \
        for (int jj_ = 0; jj_ < 2; ++jj_) {                                       \
            const int rh_ = wc * 32 + jj_ * 16 + lr;                              \
            dst_[ks_][jj_] = *(const bf16x8*)                                     \
                &lds[1][buf_][qj_][rh_ * 64 + (((ks_ * 4 + lk) ^ (rh_ & 7)) << 3)]; \
        } } while (0)

    #define SYNC_IN() do {                                                        \
        if (MODE == 0) {                                                          \
            __builtin_amdgcn_sched_barrier(0);                                    \
            __builtin_amdgcn_s_barrier();                                         \
        }                                                                         \
        if (MODE <= 1) {                                                          \
            asm volatile("s_waitcnt lgkmcnt(0)" ::: "memory");                    \
            __builtin_amdgcn_sched_barrier(0);                                    \
        } } while (0)

    #define MFMA16(aa_, bb_, qi_, qj_) do {                                       \
        __builtin_amdgcn_s_setprio(1);                                            \
        _Pragma("unroll")                                                         \
        for (int ks_ = 0; ks_ < 2; ++ks_)                                         \
        _Pragma("unroll")                                                         \
        for (int jj_ = 0; jj_ < 2; ++jj_)                                         \
        _Pragma("unroll")                                                         \
        for (int ii_ = 0; ii_ < 4; ++ii_)                                         \
            acc[(qi_)*4+ii_][(qj_)*2+jj_] = __builtin_amdgcn_mfma_f32_16x16x32_bf16( \
                aa_[ks_][ii_], bb_[ks_][jj_], acc[(qi_)*4+ii_][(qj_)*2+jj_], 0, 0, 0); \
        __builtin_amdgcn_s_setprio(0); } while (0)

    #define PH_END() do {                                                         \
        __builtin_amdgcn_sched_barrier(0);                                        \
        __builtin_amdgcn_s_barrier(); } while (0)

    // prologue: t0 full + t1.A0/B0 (6 halves); retire t0 (keep 4 loads)
    STG(0, 0, 0); STG(0, 0, 1); STG(1, 0, 0); STG(1, 0, 1);
    STG(0, 1, 0); STG(1, 1, 0);
    asm volatile("s_waitcnt vmcnt(4)" ::: "memory");
    __builtin_amdgcn_sched_barrier(0);
    __builtin_amdgcn_s_barrier();
    __builtin_amdgcn_sched_barrier(0);

    for (int m = 0; m < NI; ++m) {
        const int t1 = 2 * m + 1, u0 = 2 * m + 2, u1 = 2 * m + 3;
        const bool last = (m == NI - 1);
        bf16x8 a_[2][4], b0_[2][2], b1_[2][2];

        // ph1: t0 q(0,0)
        RD_A(a_, 0, 0); RD_B(b0_, 0, 0);
        STG(0, t1, 1);
        SYNC_IN(); MFMA16(a_, b0_, 0, 0); PH_END();
        // ph2: t0 q(0,1)
        RD_B(b1_, 0, 1);
        STG(1, t1, 1);
        SYNC_IN(); MFMA16(a_, b1_, 0, 1); PH_END();
        // ph3: t0 q(1,0)
        RD_A(a_, 0, 1);
        if (u0 < NT) STG(0, u0, 0);
        SYNC_IN(); MFMA16(a_, b0_, 1, 0); PH_END();
        // ph4: t0 q(1,1) + K-tile wait
        if (u0 < NT) STG(1, u0, 0);
        SYNC_IN(); MFMA16(a_, b1_, 1, 1);
        if (last) asm volatile("s_waitcnt vmcnt(0)" ::: "memory");
        else      asm volatile("s_waitcnt vmcnt(4)" ::: "memory");
        PH_END();
        // ph5: t1 q(0,0)
        RD_A(a_, 1, 0); RD_B(b0_, 1, 0);
        if (u0 < NT) STG(0, u0, 1);
        SYNC_IN(); MFMA16(a_, b0_, 0, 0); PH_END();
        // ph6: t1 q(0,1)
        RD_B(b1_, 1, 1);
        if (u0 < NT) STG(1, u0, 1);
        SYNC_IN(); MFMA16(a_, b1_, 0, 1); PH_END();
        // ph7: t1 q(1,0)
        RD_A(a_, 1, 1);
        if (u1 < NT) STG(0, u1, 0);
        SYNC_IN(); MFMA16(a_, b0_, 1, 0); PH_END();
        // ph8: t1 q(1,1) + K-tile wait
        if (u1 < NT) STG(1, u1, 0);
        SYNC_IN(); MFMA16(a_, b1_, 1, 1);
        if (!last) asm volatile("s_waitcnt vmcnt(4)" ::: "memory");
        PH_END();
    }
    #undef STG
    #undef RD_A
    #undef RD_B
    #undef SYNC_IN
    #undef MFMA16
    #undef PH_END

    const int colb = col0 + wc * 32 + lr;
    const int rowb = row0 + wr * 64 + lk * 4;
    float bj[4];
    #pragma unroll
    for (int j = 0; j < 4; ++j)
        bj[j] = bias[colb + (j >> 1) * 128 + (j & 1) * 16];

    #pragma unroll
    for (int i = 0; i < 8; ++i) {
        const int gri = rowb + (i >> 2) * 128 + (i & 3) * 16;
        #pragma unroll
        for (int r = 0; r < 4; ++r) {
            const size_t row = gri + r;
            #pragma unroll
            for (int j = 0; j < 4; ++j) {
                float x = fmaxf(acc[i][j][r] + bj[j], 0.f);
                C[row * (size_t)N + colb + (j >> 1) * 128 + (j & 1) * 16] = f2bf(x);
            }
        }
    }
}

// ---------------------------------------------------------------------------
// gemm128: proven pipeline at 128x128 / 4 waves / 48 KiB. Narrow-N GEMMs 6/7.
// ---------------------------------------------------------------------------
template<bool OUT_F32, int ACT>
__global__ __launch_bounds__(256, 2) void gemm128(
    const unsigned short* __restrict__ A, const unsigned short* __restrict__ Bt,
    const float* __restrict__ bias, void* __restrict__ Cp,
    int M, int N, int K, int ldc, int cc0,
    const int* __restrict__ dom, int biasStride)
{
    __shared__ alignas(16) unsigned short lds[3][2][128 * 32];  // 48 KiB

    const int nbx = N >> 7;
    int wg = blockIdx.x;
    const int nwg = gridDim.x;
    if ((nwg & 7) == 0) {
        const int cpx = nwg >> 3;
        wg = (wg & 7) * cpx + (wg >> 3);
    }
    const int bx = wg % nbx, by = wg / nbx;
    const int row0 = by << 7, col0 = bx << 7;

    const int t  = threadIdx.x;
    const int w  = t >> 6, l = t & 63;
    const int wr = w >> 1, wc = w & 1;
    const int lr = l & 15, lk = l >> 4;
    const int rsw = (lr >> 1) & 3;
    const int srow = l >> 2;
    const int skel = ((l & 3) ^ ((l >> 3) & 3)) * 8;

    f32x4 acc[4][4];
    #pragma unroll
    for (int i = 0; i < 4; ++i)
        #pragma unroll
        for (int j = 0; j < 4; ++j)
            acc[i][j] = (f32x4)(0.f);

    const int NT = K >> 5;

    #define STAGE128(tile_)  do {                                            \
        const int k0_  = (tile_) << 5;                                       \
        const int buf_ = (tile_) % 3;                                        \
        _Pragma("unroll")                                                    \
        for (int s_ = 0; s_ < 2; ++s_) {                                     \
            const int c_   = w * 2 + s_;                                     \
            const int row_ = c_ * 16 + srow;                                 \
            __builtin_amdgcn_global_load_lds(                                \
                TO_GLB(A + (size_t)(row0 + row_) * K + k0_ + skel),          \
                TO_LDS((char*)&lds[buf_][0][0] + c_ * 1024), 16, 0, 0);      \
            __builtin_amdgcn_global_load_lds(                                \
                TO_GLB(Bt + (size_t)(col0 + row_) * K + k0_ + skel),         \
                TO_LDS((char*)&lds[buf_][1][0] + c_ * 1024), 16, 0, 0);      \
        }                                                                    \
    } while (0)

    STAGE128(0);
    if (NT > 1) {
        STAGE128(1);
        asm volatile("s_waitcnt vmcnt(4)" ::: "memory");
    } else {
        asm volatile("s_waitcnt vmcnt(0)" ::: "memory");
    }
    __builtin_amdgcn_sched_barrier(0);
    __builtin_amdgcn_s_barrier();
    __builtin_amdgcn_sched_barrier(0);

    for (int tt = 0; tt < NT; ++tt) {
        const int buf = tt % 3;
        if (tt + 2 < NT) STAGE128(tt + 2);
        __builtin_amdgcn_sched_barrier(0);

        bf16x8 af[4], bfv[4];
        #pragma unroll
        for (int i = 0; i < 4; ++i)
            af[i]  = *(const bf16x8*)&lds[buf][0][(wr*64 + i*16 + lr) * 32 + (lk ^ rsw) * 8];
        #pragma unroll
        for (int j = 0; j < 4; ++j)
            bfv[j] = *(const bf16x8*)&lds[buf][1][(wc*64 + j*16 + lr) * 32 + (lk ^ rsw) * 8];

        #pragma unroll
        for (int j = 0; j < 4; ++j)
            #pragma unroll
            for (int i = 0; i < 4; ++i)
                acc[i][j] = __builtin_amdgcn_mfma_f32_16x16x32_bf16(
                    af[i], bfv[j], acc[i][j], 0, 0, 0);

        if (tt + 1 < NT) {
            if (tt + 2 < NT) asm volatile("s_waitcnt vmcnt(4)" ::: "memory");
            else             asm volatile("s_waitcnt vmcnt(0)" ::: "memory");
            __builtin_amdgcn_sched_barrier(0);
            __builtin_amdgcn_s_barrier();
            __builtin_amdgcn_sched_barrier(0);
        }
    }
    #undef STAGE128

    if (dom) bias += (*dom) * biasStride;
    const int colb = col0 + wc * 64 + lr;
    const int rowb = row0 + wr * 64 + lk * 4;
    float bj[4];
    #pragma unroll
    for (int j = 0; j < 4; ++j) bj[j] = bias[colb + j * 16];

    #pragma unroll
    for (int i = 0; i < 4; ++i) {
        #pragma unroll
        for (int r = 0; r < 4; ++r) {
            const size_t row = rowb + i * 16 + r;
            #pragma unroll
            for (int j = 0; j < 4; ++j) {
                float x = acc[i][j][r] + bj[j];
                if (ACT == 1)      x = fmaxf(x, 0.f);
                else if (ACT == 2) x = (x > 0.f) ? x : LEAKS * x;
                const size_t idx = row * (size_t)ldc + cc0 + colb + j * 16;
                if (OUT_F32) ((float*)Cp)[idx] = x;
                else         ((unsigned short*)Cp)[idx] = f2bf(x);
            }
        }
    }
}

// ---------------------------------------------------------------------------
// BatchNorm stats + heads — unchanged (proven).
// ---------------------------------------------------------------------------
__global__ __launch_bounds__(256) void bn_stats_a(
    const float* __restrict__ X, float* __restrict__ psum, float* __restrict__ pss)
{
    const int c  = blockIdx.x * 256 + threadIdx.x;
    const int rb = blockIdx.y;
    float s = 0.f, ss = 0.f;
    const int r0 = rb * 256;
    for (int r = r0; r < r0 + 256; ++r) {
        float v = X[(size_t)r * XW + c];
        s += v; ss = fmaf(v, v, ss);
    }
    psum[rb * XW + c] = s;
    pss [rb * XW + c] = ss;
}

__global__ __launch_bounds__(256) void bn_stats_b(
    const float* __restrict__ psum, const float* __restrict__ pss,
    const float* __restrict__ gamma, const float* __restrict__ beta,
    float* __restrict__ scale, float* __restrict__ shift)
{
    const int c = blockIdx.x * 256 + threadIdx.x;
    float s = 0.f, ss = 0.f;
    for (int rb = 0; rb < 32; ++rb) { s += psum[rb * XW + c]; ss += pss[rb * XW + c]; }
    const float inv = 1.f / (float)BQ;
    const float mean = s * inv;
    const float var  = ss * inv - mean * mean;
    const float sc = gamma[c] * rsqrtf(var + BN_EPS);
    scale[c] = sc;
    shift[c] = beta[c] - mean * sc;
}

__global__ __launch_bounds__(256) void head_kernel(
    const float* __restrict__ X, const float* __restrict__ scale,
    const float* __restrict__ shift, const int* __restrict__ tt,
    const float* __restrict__ Wh1, const float* __restrict__ bh1,
    const float* __restrict__ Wh2, const float* __restrict__ bh2,
    const float* __restrict__ Wh3, const float* __restrict__ bh3,
    float* __restrict__ out)
{
    __shared__ float xs[4][XW];
    __shared__ float y1[4][H1N];
    __shared__ float y2[4][H2N + 2];

    const int t = threadIdx.x;
    const int w = t >> 6;
    const int l = t & 63;
    const int s = blockIdx.x * 4 + w;
    const int d = tt[s];

    #pragma unroll 4
    for (int i = 0; i < XW / 64; ++i) {
        const int c = i * 64 + l;
        xs[w][c] = fmaf(X[(size_t)s * XW + c], scale[c], shift[c]);
    }
    __syncthreads();

    if (l < H1N) {
        const float* W1 = Wh1 + (size_t)d * XW * H1N;
        float acc = bh1[d * H1N + l];
        #pragma unroll 8
        for (int c = 0; c < XW; ++c)
            acc = fmaf(xs[w][c], W1[c * H1N + l], acc);
        y1[w][l] = fmaxf(acc, 0.f);
    }
    __syncthreads();

    if (l < H2N) {
        const float* W2 = Wh2 + (size_t)d * H1N * H2N;
        float acc = bh2[d * H2N + l];
        #pragma unroll
        for (int c = 0; c < H1N; ++c)
            acc = fmaf(y1[w][c], W2[c * H2N + l], acc);
        y2[w][l] = fmaxf(acc, 0.f);
    }
    __syncthreads();

    if (l < NWAY) {
        const float* W3 = Wh3 + (size_t)d * H2N * NWAY;
        float acc = bh3[d * NWAY + l];
        #pragma unroll
        for (int c = 0; c < H2N; ++c)
            acc = fmaf(y2[w][c], W3[c * NWAY + l], acc);
        out[(size_t)s * NWAY + l] = acc;
    }
}

// ---------------------------------------------------------------------------
extern "C" void kernel_launch(void* const* d_in, const int* in_sizes, int n_in,
                              void* d_out, int out_size, void* d_ws, size_t ws_size,
                              hipStream_t stream)
{
    const float* x_s   = (const float*)d_in[0];
    const float* x_p   = (const float*)d_in[1];
    const int*   tt    = (const int*)  d_in[2];
    const int*   dom   = (const int*)  d_in[3];
    const float* W_in  = (const float*)d_in[4];
    const float* b_in  = (const float*)d_in[5];
    const float* W_hid = (const float*)d_in[6];
    const float* b_hid = (const float*)d_in[7];
    const float* W_out = (const float*)d_in[8];
    const float* b_out = (const float*)d_in[9];
    const float* Wp    = (const float*)d_in[10];
    const float* bp    = (const float*)d_in[11];
    const float* gamma = (const float*)d_in[12];
    const float* beta  = (const float*)d_in[13];
    const float* Wh1   = (const float*)d_in[14];
    const float* bh1   = (const float*)d_in[15];
    const float* Wh2   = (const float*)d_in[16];
    const float* bh2   = (const float*)d_in[17];
    const float* Wh3   = (const float*)d_in[18];
    const float* bh3   = (const float*)d_in[19];
    float* out = (float*)d_out;

    const dim3 blk(256);
    char* w = (char*)d_ws;

    const size_t FAST_NEED = 470810624ull;

    if (ws_size >= FAST_NEED) {
        unsigned short* xb    = (unsigned short*)w;                    // 192M
        unsigned short* WinT  = (unsigned short*)(w + 201326592);      // 96M region
        unsigned short* WoutT = (unsigned short*)(w + 201326592);      //  8M
        unsigned short* WpT   = (unsigned short*)(w + 209715200);      // 24M
        unsigned short* actA  = (unsigned short*)(w + 301989888);      // 64M
        unsigned short* actB  = (unsigned short*)(w + 369098752);      // 64M
        float*          X     = (float*)(w + 369098752);               // aliases actB
        unsigned short* WhidT = (unsigned short*)(w + 436207616);      // 32M
        float*          psum  = (float*)(w + 469762048);
        float*          pss   = psum + 32 * XW;
        float*          scale = pss  + 32 * XW;
        float*          shift = scale + XW;

        cvt_bf16<<<dim3(2048), blk, 0, stream>>>(x_s, xb, (long long)BQ * FIN / 8);
        transpose_cvt<<<dim3(SUN/64,  FIN/64), blk, 0, stream>>>(W_in,  WinT,  FIN, SUN,  nullptr);
        transpose_cvt<<<dim3(SUN/64,  SUN/64), blk, 0, stream>>>(W_hid, WhidT, SUN, SUN,  nullptr);

        // GEMM1 — lean (MODE 1, R14-proven)
        gemm256_8ph<1><<<dim3(512), dim3(512), 0, stream>>>(xb, WinT, b_in, actA, BQ, SUN, FIN);

        transpose_cvt<<<dim3(HIDN/64, SUN/64), blk, 0, stream>>>(W_out, WoutT, SUN, HIDN, nullptr);
        transpose_cvt<<<dim3(HIDN/64, FIN/64), blk, 0, stream>>>(Wp,    WpT,   FIN, HIDN, dom);
        cvt_bf16<<<dim3(2048), blk, 0, stream>>>(x_p, xb, (long long)BQ * FIN / 8);

        // hidden layers A/B: relaxed(MODE 2), lean(MODE 1), relaxed, lean
        gemm256_8ph<2><<<dim3(512), dim3(512), 0, stream>>>(actA, WhidT, b_hid, actB, BQ, SUN, SUN);
        gemm256_8ph<1><<<dim3(512), dim3(512), 0, stream>>>(actB, WhidT, b_hid, actA, BQ, SUN, SUN);
        gemm256_8ph<2><<<dim3(512), dim3(512), 0, stream>>>(actA, WhidT, b_hid, actB, BQ, SUN, SUN);
        gemm256_8ph<1><<<dim3(512), dim3(512), 0, stream>>>(actB, WhidT, b_hid, actA, BQ, SUN, SUN);

        gemm128<true,1><<<dim3(512), blk, 0, stream>>>(
            actA, WoutT, b_out, X, BQ, HIDN, SUN, XW, 0, nullptr, 0);
        gemm128<true,2><<<dim3(512), blk, 0, stream>>>(
            xb, WpT, bp, X, BQ, HIDN, FIN, XW, HIDN, dom, HIDN);

        bn_stats_a<<<dim3(XW/256, 32), blk, 0, stream>>>(X, psum, pss);
        bn_stats_b<<<dim3(XW/256),     blk, 0, stream>>>(psum, pss, gamma, beta, scale, shift);
        head_kernel<<<dim3(BQ/4), blk, 0, stream>>>(X, scale, shift, tt,
                                                    Wh1, bh1, Wh2, bh2, Wh3, bh3, out);
        return;
    }

    // ---------------- fallback: 256 MiB path ----------------
    unsigned short* actA  = (unsigned short*)w;
    unsigned short* actB  = (unsigned short*)(w + 67108864);
    float*          X     = (float*)(w + 67108864);
    unsigned short* WinT  = (unsigned short*)(w + 134217728);
    unsigned short* WoutT = (unsigned short*)(w + 134217728);
    unsigned short* WpT   = (unsigned short*)(w + 142606336);
    float*          psum  = (float*)(w + 167772160);
    float*          pss   = psum + 32 * XW;
    float*          scale = pss  + 32 * XW;
    float*          shift = scale + XW;
    unsigned short* WhidT = (unsigned short*)(w + 234881024);

    transpose_cvt<<<dim3(SUN/64,  FIN/64), blk, 0, stream>>>(W_in,  WinT,  FIN, SUN,  nullptr);
    transpose_cvt<<<dim3(SUN/64,  SUN/64), blk, 0, stream>>>(W_hid, WhidT, SUN, SUN,  nullptr);

    gemm_mfma<true,false,1><<<dim3(2048), blk, 0, stream>>>(
        x_s, WinT, b_in, actA, BQ, SUN, FIN, SUN, 0, nullptr, 0);

    transpose_cvt<<<dim3(HIDN/64, SUN/64), blk, 0, stream>>>(W_out, WoutT, SUN, HIDN, nullptr);
    transpose_cvt<<<dim3(HIDN/64, FIN/64), blk, 0, stream>>>(Wp,    WpT,   FIN, HIDN, dom);

    gemm256<<<dim3(512), dim3(512), 0, stream>>>(actA, WhidT, b_hid, actB, BQ, SUN, SUN);
    gemm256<<<dim3(512), dim3(512), 0, stream>>>(actB, WhidT, b_hid, actA, BQ, SUN, SUN);
    gemm256<<<dim3(512), dim3(512), 0, stream>>>(actA, WhidT, b_hid, actB, BQ, SUN, SUN);
    gemm256<<<dim3(512), dim3(512), 0, stream>>>(actB, WhidT, b_hid, actA, BQ, SUN, SUN);

    gemm128<true,1><<<dim3(512), blk, 0, stream>>>(
        actA, WoutT, b_out, X, BQ, HIDN, SUN, XW, 0, nullptr, 0);
    gemm_mfma<true,true,2><<<dim3(512), blk, 0, stream>>>(
        x_p, WpT, bp, X, BQ, HIDN, FIN, XW, HIDN, dom, HIDN);

    bn_stats_a<<<dim3(XW/256, 32), blk, 0, stream>>>(X, psum, pss);
    bn_stats_b<<<dim3(XW/256),     blk, 0, stream>>>(psum, pss, gamma, beta, scale, shift);
    head_kernel<<<dim3(BQ/4), blk, 0, stream>>>(X, scale, shift, tt,
                                                Wh1, bh1, Wh2, bh2, Wh3, bh3, out);
}